// Round 1
// 231.742 us; speedup vs baseline: 1.0520x; 1.0520x over previous
//
#include <hip/hip_runtime.h>
#include <math.h>

#define NN   128
#define SS   129          // LDS row stride in float2 (ODD -> conflict-free lane stride)
#define TT   512          // PROVEN: TT=512 allocates ~112-128 VGPR no-spill (R4/R6-R13);
                          // TT=1024 ALWAYS gets 64 VGPR + spill (R2/R3/R10). Never 1024.
#define NPIX 16384        // 128*128
#define EPT  32           // NPIX / TT
#define SG   65           // 64-grid row stride (float2 or float4 units)
#define SG32 33           // 32-grid row stride

// R12 lesson: NO __threadfence() tail / in-kernel MLP fold (cost ~115 us).
// R14 (this round): (j1=0,j2=1) second order moved from full 128-grid (4 IFFTs)
// to OFF-CENTER 64x64 frequency windows + 64-grid IFFT. |IFFT| is invariant to
// the frequency shift; window centered near filter peak (biased 3 bins to DC).
// Mapping reduces exactly to the proven central-window H-staging when o=0.

__device__ __forceinline__ float2 cmul(float2 a, float2 w) {
    return make_float2(a.x * w.x - a.y * w.y, a.x * w.y + a.y * w.x);
}
__device__ __forceinline__ float2 cmulc(float2 a, float2 w) {   // a * conj(w)
    return make_float2(a.x * w.x + a.y * w.y, a.y * w.x - a.x * w.y);
}

// ---------- register FFT codelets (fft8/fft16 verified R2-R13) ----------
template<int SGN>
__device__ __forceinline__ void fft4(float2* f) {
    float2 t0 = make_float2(f[0].x + f[2].x, f[0].y + f[2].y);
    float2 t1 = make_float2(f[0].x - f[2].x, f[0].y - f[2].y);
    float2 t2 = make_float2(f[1].x + f[3].x, f[1].y + f[3].y);
    float2 t3 = make_float2(f[1].x - f[3].x, f[1].y - f[3].y);
    float2 t3i = (SGN > 0) ? make_float2(-t3.y, t3.x) : make_float2(t3.y, -t3.x);
    f[0] = make_float2(t0.x + t2.x, t0.y + t2.y);
    f[1] = make_float2(t1.x + t3i.x, t1.y + t3i.y);
    f[2] = make_float2(t0.x - t2.x, t0.y - t2.y);
    f[3] = make_float2(t1.x - t3i.x, t1.y - t3i.y);
}

template<int SGN>
__device__ __forceinline__ void fft8(float2* f) {
    const float R = 0.70710678118654752f;
    const float WC[4] = {1.f, R, 0.f, -R};
    const float WS[4] = {0.f, R, 1.f, R};
    #pragma unroll
    for (int stage = 0; stage < 3; ++stage) {
        const int L = 8 >> stage, half = L >> 1, step = 1 << stage;
        #pragma unroll
        for (int base = 0; base < 8; base += L) {
            #pragma unroll
            for (int j = 0; j < half; ++j) {
                float2 u = f[base + j], v = f[base + half + j];
                f[base + j] = make_float2(u.x + v.x, u.y + v.y);
                float dx = u.x - v.x, dy = u.y - v.y;
                const int t = j * step;
                const float wr = WC[t];
                const float wi = (SGN > 0) ? WS[t] : -WS[t];
                f[base + half + j] = make_float2(dx * wr - dy * wi, dx * wi + dy * wr);
            }
        }
    }
    float2 tmp;
    tmp = f[1]; f[1] = f[4]; f[4] = tmp;
    tmp = f[3]; f[3] = f[6]; f[6] = tmp;
}

template<int SGN>
__device__ __forceinline__ void fft16(float2* f) {
    const float WC[8] = {1.f, 0.92387953251f, 0.70710678119f, 0.38268343236f,
                         0.f, -0.38268343236f, -0.70710678119f, -0.92387953251f};
    const float WS[8] = {0.f, 0.38268343236f, 0.70710678119f, 0.92387953251f,
                         1.f, 0.92387953251f, 0.70710678119f, 0.38268343236f};
    #pragma unroll
    for (int stage = 0; stage < 4; ++stage) {
        const int L = 16 >> stage, half = L >> 1, step = 1 << stage;
        #pragma unroll
        for (int base = 0; base < 16; base += L) {
            #pragma unroll
            for (int j = 0; j < half; ++j) {
                float2 u = f[base + j], v = f[base + half + j];
                f[base + j] = make_float2(u.x + v.x, u.y + v.y);
                float dx = u.x - v.x, dy = u.y - v.y;
                const int t = j * step;
                const float wr = WC[t];
                const float wi = (SGN > 0) ? WS[t] : -WS[t];
                f[base + half + j] = make_float2(dx * wr - dy * wi, dx * wi + dy * wr);
            }
        }
    }
    float2 tmp;
    tmp = f[1];  f[1]  = f[8];  f[8]  = tmp;
    tmp = f[2];  f[2]  = f[4];  f[4]  = tmp;
    tmp = f[3];  f[3]  = f[12]; f[12] = tmp;
    tmp = f[5];  f[5]  = f[10]; f[10] = tmp;
    tmp = f[7];  f[7]  = f[14]; f[14] = tmp;
    tmp = f[11]; f[11] = f[13]; f[13] = tmp;
}

__device__ __forceinline__ float waveReduceSum(float v) {
    #pragma unroll
    for (int off = 32; off > 0; off >>= 1) v += __shfl_down(v, off, 64);
    return v;
}

__device__ __forceinline__ void buildTw(float2* tw, int tid) {
    if (tid < 128) {
        float s, c;
        __sincosf((float)tid * 0.04908738521234052f, &s, &c);   // 2*pi/128
        tw[tid] = make_float2(c, s);
    }
}

// ======== 128-grid sweep phases (R6-R13 proven, TT=512) ========
template<int ES, int LS>
__device__ __forceinline__ void fwdA(float2* __restrict__ F,
                                     const float2* __restrict__ tw, int tid) {
    #pragma unroll
    for (int i = 0; i < 4; ++i) {
        int u = i * TT + tid;
        int t = u >> 7, x = u & 127;
        float2* M = F + x * LS;
        float2 f[8];
        #pragma unroll
        for (int n1 = 0; n1 < 8; ++n1) f[n1] = M[(t + 16 * n1) * ES];
        fft8<-1>(f);
        #pragma unroll
        for (int ka = 0; ka < 8; ++ka)
            M[(t + 16 * ka) * ES] = cmulc(f[ka], tw[t * ka]);
    }
}

template<int ES, int LS>
__device__ __forceinline__ void fwdB(float2* __restrict__ F, int tid) {
    #pragma unroll
    for (int i = 0; i < 2; ++i) {
        int u = i * TT + tid;
        int ka = u >> 7, x = u & 127;
        float2* M = F + x * LS;
        float2 g[16];
        #pragma unroll
        for (int t = 0; t < 16; ++t) g[t] = M[(16 * ka + t) * ES];
        fft16<-1>(g);
        #pragma unroll
        for (int kb = 0; kb < 16; ++kb) M[(16 * ka + kb) * ES] = g[kb];
    }
}

__device__ __forceinline__ void fwdB_col_capture(const float2* __restrict__ F, int tid,
                                                 float2* __restrict__ uh) {
    #pragma unroll
    for (int i = 0; i < 2; ++i) {
        int u = i * TT + tid;
        int ka = u >> 7, c = u & 127;
        float2 g[16];
        #pragma unroll
        for (int t = 0; t < 16; ++t) g[t] = F[(16 * ka + t) * SS + c];
        fft16<-1>(g);
        #pragma unroll
        for (int kb = 0; kb < 16; ++kb) uh[i * 16 + kb] = g[kb];
    }
}

template<int ES, int LS>
__device__ __forceinline__ void invA(float2* __restrict__ F,
                                     const float2* __restrict__ tw, int tid) {
    #pragma unroll
    for (int i = 0; i < 2; ++i) {
        int u = i * TT + tid;
        int ka = u >> 7, x = u & 127;
        float2* M = F + x * LS;
        float2 g[16];
        #pragma unroll
        for (int kb = 0; kb < 16; ++kb) g[kb] = M[(16 * ka + kb) * ES];
        fft16<1>(g);
        #pragma unroll
        for (int t = 0; t < 16; ++t)
            M[(16 * ka + t) * ES] = cmul(g[t], tw[t * ka]);
    }
}

template<int ES, int LS>
__device__ __forceinline__ void invB(float2* __restrict__ F, int tid) {
    #pragma unroll
    for (int i = 0; i < 4; ++i) {
        int u = i * TT + tid;
        int t = u >> 7, x = u & 127;
        float2* M = F + x * LS;
        float2 f[8];
        #pragma unroll
        for (int ka = 0; ka < 8; ++ka) f[ka] = M[(16 * ka + t) * ES];
        fft8<1>(f);
        #pragma unroll
        for (int nh = 0; nh < 8; ++nh) M[(t + 16 * nh) * ES] = f[nh];
    }
}

// FUSED: inverse row stepB -> |.| (raw, acc) -> forward row stepA (same cells).
__device__ __forceinline__ void invBmag_fwdA_row(float2* __restrict__ F,
                                                 const float2* __restrict__ tw,
                                                 int tid, float& acc) {
    #pragma unroll
    for (int i = 0; i < 4; ++i) {
        int u = i * TT + tid;
        int t = u >> 7, x = u & 127;
        float2* M = F + x * SS;
        float2 f[8];
        #pragma unroll
        for (int ka = 0; ka < 8; ++ka) f[ka] = M[16 * ka + t];
        fft8<1>(f);
        #pragma unroll
        for (int nh = 0; nh < 8; ++nh) {
            float m = sqrtf(f[nh].x * f[nh].x + f[nh].y * f[nh].y);
            acc += m;
            f[nh] = make_float2(m, 0.f);
        }
        fft8<-1>(f);
        #pragma unroll
        for (int ka = 0; ka < 8; ++ka)
            M[t + 16 * ka] = cmulc(f[ka], tw[t * ka]);
    }
}

// ---------- K_pre: fused filter bank + coeff zero + i_hat FFT ----------
__global__ __attribute__((amdgpu_flat_work_group_size(TT, TT), amdgpu_waves_per_eu(2, 2)))
void k_pre(const float* __restrict__ img,
           float* __restrict__ psi,
           float2* __restrict__ ihat,
           float* __restrict__ coeffs) {
    __shared__ float2 F[NN * SS];
    __shared__ float2 tw[128];
    __shared__ float red[TT / 64];
    int blk = blockIdx.x, tid = threadIdx.x;
    if (blk >= 64) {
        if (blk == 80) {
            for (int i = tid; i < 64 * 11; i += TT)
                if (i % 11 != 0) coeffs[i] = 0.f;
            return;
        }
        int f = blk - 64;
        int j = f >> 2, l = f & 3;
        float k0    = 2.35619449019234493f / (float)(1 << j);
        float sigma = 0.8f * (float)(1 << j);
        float s2    = sigma * sigma;
        float theta = 0.78539816339744831f * (float)l;
        float k0x = k0 * cosf(theta);
        float k0y = k0 * sinf(theta);
        float beta = expf(-0.5f * s2 * k0 * k0);
        const float FSTEP = 0.04908738521234052f;
        float* dst = psi + (size_t)f * NPIX;
        for (int i = tid; i < NPIX; i += TT) {
            int pr = i >> 7, pc = i & 127;
            int kr = (pr >> 4) + 8 * (pr & 15);
            int kc = (pc >> 4) + 8 * (pc & 15);
            float fr = (float)(kr < 64 ? kr : kr - 128) * FSTEP;
            float fc = (float)(kc < 64 ? kc : kc - 128) * FSTEP;
            float dx = fr - k0x, dy = fc - k0y;
            float g1 = expf(-0.5f * s2 * (dx * dx + dy * dy));
            float g0 = expf(-0.5f * s2 * (fr * fr + fc * fc));
            dst[i] = g1 - beta * g0;
        }
        return;
    }
    int b = blk;
    buildTw(tw, tid);
    const float* im = img + (size_t)b * NPIX;
    float acc = 0.f;
    #pragma unroll
    for (int k = 0; k < EPT; ++k) {
        int e = k * TT + tid;
        float v = im[e];
        acc += v;
        F[(e >> 7) * SS + (e & 127)] = make_float2(v, 0.f);
    }
    float ws = waveReduceSum(acc);
    if ((tid & 63) == 0) red[tid >> 6] = ws;
    __syncthreads();
    if (tid == 0) {
        float t = 0.f;
        #pragma unroll
        for (int w = 0; w < TT / 64; ++w) t += red[w];
        coeffs[b * 11 + 0] = t * (1.f / 16384.f);
    }
    fwdA<1, SS>(F, tw, tid);  __syncthreads();
    fwdB<1, SS>(F, tid);      __syncthreads();
    fwdA<SS, 1>(F, tw, tid);  __syncthreads();
    float2 uh[32];
    fwdB_col_capture(F, tid, uh);
    float2* dst = ihat + (size_t)b * NPIX;
    #pragma unroll
    for (int i = 0; i < 2; ++i) {
        int u = i * TT + tid;
        int ka = u >> 7, c = u & 127;
        #pragma unroll
        for (int kb = 0; kb < 16; ++kb)
            dst[(16 * ka + kb) * NN + c] = uh[i * 16 + kb];
    }
}

// ---------- K_scat_big: j1 in {0,1} ----------
__global__ __attribute__((amdgpu_flat_work_group_size(TT, TT), amdgpu_waves_per_eu(2, 2)))
void k_scat_big(const float2* __restrict__ ihat,
                const float* __restrict__ psi,
                float* __restrict__ coeffs) {
    __shared__ __align__(16) float2 F[NN * SS];
    __shared__ float2 tw[128];
    float4* G4  = (float4*)F;
    float2* H   = F + 8320;        // 64x64 central-window spectrum (freq-perm layout)
    float2* G2a = F;               // 64x65 float2 grid A  [0,4160)
    float2* G2b = F + 4160;        // 64x65 float2 grid B  [4160,8320)  (below H)
    int tid = threadIdx.x;
    int x = blockIdx.x;
    int b = x & 63, l1 = (x >> 6) & 3, j1 = x >> 8;    // j1 in {0,1}
    const float2* ih = ihat + (size_t)b * NPIX;
    const float*  p1 = psi + (size_t)(j1 * 4 + l1) * NPIX;
    buildTw(tw, tid);

    const float S1_128 = 9.3132257461547852e-10f;   // 2^-30
    const float S2TR   = 5.6843418860808015e-14f;   // 2^-44

    int kalo = tid >> 7, c = tid & 127;
    {
        #pragma unroll
        for (int i = 0; i < 2; ++i) {
            int ka = kalo + 4 * i;
            float2 g[16];
            #pragma unroll
            for (int kb = 0; kb < 16; ++kb) {
                int e = (16 * ka + kb) * NN + c;
                float2 z = ih[e];
                float  p = p1[e];
                g[kb] = make_float2(z.x * p, z.y * p);
            }
            fft16<1>(g);
            #pragma unroll
            for (int t = 0; t < 16; ++t)
                F[(16 * ka + t) * SS + c] = cmul(g[t], tw[t * ka]);
        }
    }
    __syncthreads();
    invB<SS, 1>(F, tid);      __syncthreads();
    invA<1, SS>(F, tw, tid);  __syncthreads();
    float acc = 0.f;
    invBmag_fwdA_row(F, tw, tid, acc);
    float ws1 = waveReduceSum(acc);
    if ((tid & 63) == 0) atomicAdd(&coeffs[b * 11 + 1 + j1], ws1 * S1_128);
    __syncthreads();
    fwdB<1, SS>(F, tid);      __syncthreads();
    fwdA<SS, 1>(F, tw, tid);  __syncthreads();
    float2 uh[32];
    fwdB_col_capture(F, tid, uh);
    __syncthreads();   // capture done -> F reusable (H / G2a / G2b alias it)

    // ---- H staging (central +-32 window of U1hat), for truncated j2 in {2,3} ----
    int m = c & 15;
    bool colKeep = (m < 4) || (m >= 12);
    int pc64 = 8 * (c >> 4) + ((m < 4) ? m : (m - 8));
    if (colKeep) {
        #pragma unroll
        for (int i = 0; i < 2; ++i) {
            int ka = kalo + 4 * i;
            #pragma unroll
            for (int kb = 0; kb < 16; ++kb) {
                if (kb < 4 || kb >= 12) {
                    int pr64 = 8 * ka + ((kb < 4) ? kb : (kb - 8));
                    H[pr64 * 64 + pc64] = uh[i * 16 + kb];
                }
            }
        }
    }

    if (j1 == 0) {
        // ===== (j1=0, j2=1) on OFF-CENTER 64x64 windows (R14) =====
        // window center o = filter peak (bin 24 along theta) biased 3 bins to DC:
        //   l2=0:(21,0)  l2=1:(15,15)  l2=2:(0,21)  l2=3:(-15,15)
        // storage s -> freq f=(s>>4)+8*(s&15); d=(f-o)&127; keep d<32||d>=96;
        // u = d<32 ? d : d-64; dest64 = 8*(u&7)+(u>>3).  (o=0 reduces to H staging.)
        const int ORA[2] = {21, 0},  OCA[2] = {0, 21};
        const int ORB[2] = {15, -15}, OCB[2] = {15, 15};
        int fc = (c >> 4) + 8 * (c & 15);
        for (int p = 0; p < 2; ++p) {
            const float* pa = psi + (size_t)(4 + 2 * p) * NPIX;
            const float* pb = pa + NPIX;
            int dca = (fc - OCA[p]) & 127;
            bool cka = (dca < 32) || (dca >= 96);
            int uca = (dca < 32) ? dca : (dca - 64);
            int pca = 8 * (uca & 7) + (uca >> 3);
            int dcb = (fc - OCB[p]) & 127;
            bool ckb = (dcb < 32) || (dcb >= 96);
            int ucb = (dcb < 32) ? dcb : (dcb - 64);
            int pcb = 8 * (ucb & 7) + (ucb >> 3);
            #pragma unroll
            for (int i = 0; i < 2; ++i) {
                int ka = kalo + 4 * i;
                #pragma unroll
                for (int kb = 0; kb < 16; ++kb) {
                    int fr = ka + 8 * kb;
                    float2 z = uh[i * 16 + kb];
                    int e = (16 * ka + kb) * NN + c;
                    if (cka) {
                        int dr = (fr - ORA[p]) & 127;
                        if (dr < 32 || dr >= 96) {
                            int ur = (dr < 32) ? dr : (dr - 64);
                            int pr = 8 * (ur & 7) + (ur >> 3);
                            float pv = pa[e];
                            G2a[pr * SG + pca] = make_float2(z.x * pv, z.y * pv);
                        }
                    }
                    if (ckb) {
                        int dr = (fr - ORB[p]) & 127;
                        if (dr < 32 || dr >= 96) {
                            int ur = (dr < 32) ? dr : (dr - 64);
                            int pr = 8 * (ur & 7) + (ur >> 3);
                            float pv = pb[e];
                            G2b[pr * SG + pcb] = make_float2(z.x * pv, z.y * pv);
                        }
                    }
                }
            }
            __syncthreads();
            {   // col stepA (two independent 64-grids)
                int col = tid & 63, k8 = tid >> 6;
                float2 f0[8], f1[8];
                #pragma unroll
                for (int kb = 0; kb < 8; ++kb) {
                    f0[kb] = G2a[(8 * k8 + kb) * SG + col];
                    f1[kb] = G2b[(8 * k8 + kb) * SG + col];
                }
                fft8<1>(f0); fft8<1>(f1);
                #pragma unroll
                for (int q = 0; q < 8; ++q) {
                    float2 w = tw[2 * q * k8];
                    G2a[(8 * k8 + q) * SG + col] = cmul(f0[q], w);
                    G2b[(8 * k8 + q) * SG + col] = cmul(f1[q], w);
                }
            }
            __syncthreads();
            {   // col stepB
                int col = tid & 63, q = tid >> 6;
                float2 f0[8], f1[8];
                #pragma unroll
                for (int k8 = 0; k8 < 8; ++k8) {
                    f0[k8] = G2a[(8 * k8 + q) * SG + col];
                    f1[k8] = G2b[(8 * k8 + q) * SG + col];
                }
                fft8<1>(f0); fft8<1>(f1);
                #pragma unroll
                for (int n1 = 0; n1 < 8; ++n1) {
                    G2a[(8 * n1 + q) * SG + col] = f0[n1];
                    G2b[(8 * n1 + q) * SG + col] = f1[n1];
                }
            }
            __syncthreads();
            {   // row stepA
                int row = tid & 63, k8 = tid >> 6;
                float2* Ra = G2a + row * SG + 8 * k8;
                float2* Rb = G2b + row * SG + 8 * k8;
                float2 f0[8], f1[8];
                #pragma unroll
                for (int kb = 0; kb < 8; ++kb) { f0[kb] = Ra[kb]; f1[kb] = Rb[kb]; }
                fft8<1>(f0); fft8<1>(f1);
                #pragma unroll
                for (int q = 0; q < 8; ++q) {
                    float2 w = tw[2 * q * k8];
                    Ra[q] = cmul(f0[q], w);
                    Rb[q] = cmul(f1[q], w);
                }
            }
            __syncthreads();
            float a2 = 0.f;
            {   // row stepB + mag
                int row = tid & 63, q = tid >> 6;
                float2* Ra = G2a + row * SG + q;
                float2* Rb = G2b + row * SG + q;
                float2 f0[8], f1[8];
                #pragma unroll
                for (int k8 = 0; k8 < 8; ++k8) { f0[k8] = Ra[8 * k8]; f1[k8] = Rb[8 * k8]; }
                fft8<1>(f0); fft8<1>(f1);
                #pragma unroll
                for (int n1 = 0; n1 < 8; ++n1) {
                    a2 += sqrtf(f0[n1].x * f0[n1].x + f0[n1].y * f0[n1].y);
                    a2 += sqrtf(f1[n1].x * f1[n1].x + f1[n1].y * f1[n1].y);
                }
            }
            float ws2 = waveReduceSum(a2);
            if ((tid & 63) == 0) atomicAdd(&coeffs[b * 11 + 5 + 0], ws2 * S2TR);
            __syncthreads();
        }
    } else {
        __syncthreads();   // H visible before trunc loop
    }

    // ===== truncated second order j2 in {2,3} on the 64-grid (unchanged) =====
    for (int j2 = 2; j2 <= 3; ++j2) {
        int pair = (j1 == 0) ? (j2 - 1) : (j2 + 1);
        for (int half = 0; half < 2; ++half) {
            const float* p2a = psi + (size_t)(j2 * 4 + 2 * half) * NPIX;
            const float* p2b = p2a + NPIX;
            if (colKeep) {
                #pragma unroll
                for (int i = 0; i < 2; ++i) {
                    int ka = kalo + 4 * i;
                    #pragma unroll
                    for (int kb = 0; kb < 16; ++kb) {
                        if (kb < 4 || kb >= 12) {
                            int pr64 = 8 * ka + ((kb < 4) ? kb : (kb - 8));
                            float2 z = H[pr64 * 64 + pc64];
                            int e = (16 * ka + kb) * NN + c;
                            float pa = p2a[e], pb = p2b[e];
                            G4[pr64 * SG + pc64] =
                                make_float4(z.x * pa, z.y * pa, z.x * pb, z.y * pb);
                        }
                    }
                }
            }
            __syncthreads();
            {   // col stepA
                int col = tid & 63, k8 = tid >> 6;
                float2 f0[8], f1[8];
                #pragma unroll
                for (int kb = 0; kb < 8; ++kb) {
                    float4 v = G4[(8 * k8 + kb) * SG + col];
                    f0[kb] = make_float2(v.x, v.y); f1[kb] = make_float2(v.z, v.w);
                }
                fft8<1>(f0); fft8<1>(f1);
                #pragma unroll
                for (int q = 0; q < 8; ++q) {
                    float2 w = tw[2 * q * k8];
                    float2 a = cmul(f0[q], w), d = cmul(f1[q], w);
                    G4[(8 * k8 + q) * SG + col] = make_float4(a.x, a.y, d.x, d.y);
                }
            }
            __syncthreads();
            {   // col stepB
                int col = tid & 63, q = tid >> 6;
                float2 f0[8], f1[8];
                #pragma unroll
                for (int k8 = 0; k8 < 8; ++k8) {
                    float4 v = G4[(8 * k8 + q) * SG + col];
                    f0[k8] = make_float2(v.x, v.y); f1[k8] = make_float2(v.z, v.w);
                }
                fft8<1>(f0); fft8<1>(f1);
                #pragma unroll
                for (int n1 = 0; n1 < 8; ++n1)
                    G4[(8 * n1 + q) * SG + col] =
                        make_float4(f0[n1].x, f0[n1].y, f1[n1].x, f1[n1].y);
            }
            __syncthreads();
            {   // row stepA
                int row = tid & 63, k8 = tid >> 6;
                float4* R = G4 + row * SG + 8 * k8;
                float2 f0[8], f1[8];
                #pragma unroll
                for (int kb = 0; kb < 8; ++kb) {
                    float4 v = R[kb];
                    f0[kb] = make_float2(v.x, v.y); f1[kb] = make_float2(v.z, v.w);
                }
                fft8<1>(f0); fft8<1>(f1);
                #pragma unroll
                for (int q = 0; q < 8; ++q) {
                    float2 w = tw[2 * q * k8];
                    float2 a = cmul(f0[q], w), d = cmul(f1[q], w);
                    R[q] = make_float4(a.x, a.y, d.x, d.y);
                }
            }
            __syncthreads();
            float a2 = 0.f;
            {   // row stepB + mag
                int row = tid & 63, q = tid >> 6;
                float4* R = G4 + row * SG + q;
                float2 f0[8], f1[8];
                #pragma unroll
                for (int k8 = 0; k8 < 8; ++k8) {
                    float4 v = R[8 * k8];
                    f0[k8] = make_float2(v.x, v.y); f1[k8] = make_float2(v.z, v.w);
                }
                fft8<1>(f0); fft8<1>(f1);
                #pragma unroll
                for (int n1 = 0; n1 < 8; ++n1) {
                    a2 += sqrtf(f0[n1].x * f0[n1].x + f0[n1].y * f0[n1].y);
                    a2 += sqrtf(f1[n1].x * f1[n1].x + f1[n1].y * f1[n1].y);
                }
            }
            float ws2 = waveReduceSum(a2);
            if ((tid & 63) == 0) atomicAdd(&coeffs[b * 11 + 5 + pair], ws2 * S2TR);
            __syncthreads();
        }
    }
}

// ---------- K_scat_small: j1 in {2,3} -- 43 KB LDS => 2+ blocks/CU ----------
__global__ __attribute__((amdgpu_flat_work_group_size(TT, TT), amdgpu_waves_per_eu(4, 4)))
void k_scat_small(const float2* __restrict__ ihat,
                  const float* __restrict__ psi,
                  float* __restrict__ coeffs) {
    // S layout: G2 = S[0..4160) (64x65); H32 = S[4160..5184) (32x32, perm32 freq);
    // G32 (single 32-grid, 32x33) and G32p (packed float4 32x33) alias S[0..).
    __shared__ __align__(16) float2 S[5184];
    __shared__ float2 tw[128];
    float2* G2  = S;
    float2* G32 = S;
    float4* G32p = (float4*)S;
    float2* H32 = S + 4160;
    int tid = threadIdx.x;
    int x = blockIdx.x;
    int b = x & 63, l1 = (x >> 6) & 3, j1 = 2 + (x >> 8);
    const float2* ih = ihat + (size_t)b * NPIX;
    const float*  p1 = psi + (size_t)(j1 * 4 + l1) * NPIX;
    buildTw(tw, tid);

    const float S1_64 = 3.7252902984619141e-9f;    // 2^-28
    const float S1_32 = 1.4901161193847656e-8f;    // 2^-26
    const float S2_32 = 9.0949470177292824e-13f;   // 2^-40

    int kalo = tid >> 7, c = tid & 127;

    if (j1 == 3) {
        // ===== 32-grid first order: psi_{j1=3} support +-16 (3.07 sigma margin) =====
        int m = c & 15;
        bool ck32 = (m < 2) || (m >= 14);
        int pc32 = 4 * (c >> 4) + ((m < 2) ? m : (m - 12));
        if (ck32) {
            #pragma unroll
            for (int i = 0; i < 2; ++i) {
                int ka = kalo + 4 * i;
                #pragma unroll
                for (int kb = 0; kb < 16; ++kb) {
                    if (kb < 2 || kb >= 14) {
                        int e = (16 * ka + kb) * NN + c;
                        float2 z = ih[e];
                        float  p = p1[e];
                        int pr32 = 4 * ka + ((kb < 2) ? kb : (kb - 12));
                        G32[pr32 * SG32 + pc32] = make_float2(z.x * p, z.y * p);
                    }
                }
            }
        }
        __syncthreads();
        if (tid < 256) {   // col stepA: fft4 over b per a (32 lines x 8 a)
            int line = tid & 31, a = tid >> 5;
            float2 f[4];
            #pragma unroll
            for (int kb = 0; kb < 4; ++kb) f[kb] = G32[(4 * a + kb) * SG32 + line];
            fft4<1>(f);
            #pragma unroll
            for (int t = 0; t < 4; ++t)
                G32[(4 * a + t) * SG32 + line] = cmul(f[t], tw[4 * t * a]);
        }
        __syncthreads();
        if (tid < 128) {   // col stepB: fft8 over a per t (32 lines x 4 t)
            int line = tid & 31, t = tid >> 5;
            float2 f[8];
            #pragma unroll
            for (int a = 0; a < 8; ++a) f[a] = G32[(4 * a + t) * SG32 + line];
            fft8<1>(f);
            #pragma unroll
            for (int n1 = 0; n1 < 8; ++n1) G32[(4 * n1 + t) * SG32 + line] = f[n1];
        }
        __syncthreads();
        if (tid < 256) {   // row stepA
            int row = tid & 31, a = tid >> 5;
            float2* R = G32 + row * SG32 + 4 * a;
            float2 f[4];
            #pragma unroll
            for (int kb = 0; kb < 4; ++kb) f[kb] = R[kb];
            fft4<1>(f);
            #pragma unroll
            for (int t = 0; t < 4; ++t) R[t] = cmul(f[t], tw[4 * t * a]);
        }
        __syncthreads();
        float acc = 0.f;
        if (tid < 128) {   // row stepB + mag
            int row = tid & 31, t = tid >> 5;
            float2* R = G32 + row * SG32 + t;
            float2 f[8];
            #pragma unroll
            for (int a = 0; a < 8; ++a) f[a] = R[4 * a];
            fft8<1>(f);
            #pragma unroll
            for (int n1 = 0; n1 < 8; ++n1)
                acc += sqrtf(f[n1].x * f[n1].x + f[n1].y * f[n1].y);
        }
        float ws1 = waveReduceSum(acc);
        if ((tid & 63) == 0 && tid < 128) atomicAdd(&coeffs[b * 11 + 4], ws1 * S1_32);
        return;
    }

    // ===================== j1 == 2: 64-grid first order (R13-proven) ==============
    int m = c & 15;
    bool colKeep = (m < 4) || (m >= 12);
    if (colKeep) {
        #pragma unroll
        for (int i = 0; i < 2; ++i) {
            int ka = kalo + 4 * i;
            #pragma unroll
            for (int kb = 0; kb < 16; ++kb) {
                if (kb < 4 || kb >= 12) {
                    int e = (16 * ka + kb) * NN + c;
                    float2 z = ih[e];
                    float  p = p1[e];
                    int pr64 = 8 * ka + ((kb < 4) ? kb : (kb - 8));
                    int pc64 = 8 * (c >> 4) + ((m < 4) ? m : (m - 8));
                    G2[pr64 * SG + pc64] = make_float2(z.x * p, z.y * p);
                }
            }
        }
    }
    __syncthreads();
    {   // col stepA (inverse)
        int col = tid & 63, k8 = tid >> 6;
        float2 f[8];
        #pragma unroll
        for (int kb = 0; kb < 8; ++kb) f[kb] = G2[(8 * k8 + kb) * SG + col];
        fft8<1>(f);
        #pragma unroll
        for (int q = 0; q < 8; ++q)
            G2[(8 * k8 + q) * SG + col] = cmul(f[q], tw[2 * q * k8]);
    }
    __syncthreads();
    {   // col stepB
        int col = tid & 63, q = tid >> 6;
        float2 f[8];
        #pragma unroll
        for (int k8 = 0; k8 < 8; ++k8) f[k8] = G2[(8 * k8 + q) * SG + col];
        fft8<1>(f);
        #pragma unroll
        for (int n1 = 0; n1 < 8; ++n1) G2[(8 * n1 + q) * SG + col] = f[n1];
    }
    __syncthreads();
    {   // row stepA (inverse)
        int row = tid & 63, k8 = tid >> 6;
        float2* R = G2 + row * SG + 8 * k8;
        float2 f[8];
        #pragma unroll
        for (int kb = 0; kb < 8; ++kb) f[kb] = R[kb];
        fft8<1>(f);
        #pragma unroll
        for (int q = 0; q < 8; ++q) R[q] = cmul(f[q], tw[2 * q * k8]);
    }
    __syncthreads();
    float acc = 0.f;
    {   // FUSED64: row stepB inv -> |.| (raw) -> row stepA fwd (same cells)
        int row = tid & 63, q = tid >> 6;
        float2* R = G2 + row * SG + q;
        float2 f[8];
        #pragma unroll
        for (int k8 = 0; k8 < 8; ++k8) f[k8] = R[8 * k8];
        fft8<1>(f);
        #pragma unroll
        for (int n1 = 0; n1 < 8; ++n1) {
            float mg = sqrtf(f[n1].x * f[n1].x + f[n1].y * f[n1].y);
            acc += mg;
            f[n1] = make_float2(mg, 0.f);
        }
        fft8<-1>(f);
        #pragma unroll
        for (int ka = 0; ka < 8; ++ka)
            R[8 * ka] = cmulc(f[ka], tw[2 * q * ka]);
    }
    float ws1 = waveReduceSum(acc);
    if ((tid & 63) == 0) atomicAdd(&coeffs[b * 11 + 3], ws1 * S1_64);
    __syncthreads();
    {   // row stepB (forward)
        int row2 = tid & 63, ka = tid >> 6;
        float2* R2 = G2 + row2 * SG + 8 * ka;
        float2 g[8];
        #pragma unroll
        for (int t = 0; t < 8; ++t) g[t] = R2[t];
        fft8<-1>(g);
        #pragma unroll
        for (int kb = 0; kb < 8; ++kb) R2[kb] = g[kb];
    }
    __syncthreads();
    {   // col stepA (forward)
        int col = tid & 63, t = tid >> 6;
        float2 g[8];
        #pragma unroll
        for (int n1 = 0; n1 < 8; ++n1) g[n1] = G2[(t + 8 * n1) * SG + col];
        fft8<-1>(g);
        #pragma unroll
        for (int ka = 0; ka < 8; ++ka)
            G2[(t + 8 * ka) * SG + col] = cmulc(g[ka], tw[2 * t * ka]);
    }
    __syncthreads();
    {   // col stepB (forward) -> H32: central +-16 of V only (perm32 layout)
        int col = tid & 63, ka = tid >> 6;
        float2 g[8];
        #pragma unroll
        for (int t = 0; t < 8; ++t) g[t] = G2[(8 * ka + t) * SG + col];
        fft8<-1>(g);
        int br = col & 7, ar = col >> 3;
        if (br < 2 || br >= 6) {
            int p32row = 4 * ar + (br & 3);
            #pragma unroll
            for (int kb = 0; kb < 8; ++kb) {
                if (kb < 2 || kb >= 6)
                    H32[(4 * ka + (kb & 3)) * 32 + p32row] = g[kb];
            }
        }
    }
    __syncthreads();

    // ===== truncated second order j2 = 3 on the 32-grid, 2 filters packed =====
    bool ck32 = (m < 2) || (m >= 14);
    int pc32 = 4 * (c >> 4) + ((m < 2) ? m : (m - 12));
    for (int half = 0; half < 2; ++half) {
        const float* p2a = psi + (size_t)(12 + 2 * half) * NPIX;
        const float* p2b = p2a + NPIX;
        if (ck32) {
            #pragma unroll
            for (int i = 0; i < 2; ++i) {
                int ka = kalo + 4 * i;
                #pragma unroll
                for (int kb = 0; kb < 16; ++kb) {
                    if (kb < 2 || kb >= 14) {
                        int pr32 = 4 * ka + ((kb < 2) ? kb : (kb - 12));
                        float2 z = H32[pr32 * 32 + pc32];
                        int e = (16 * ka + kb) * NN + c;
                        float pa = p2a[e], pb = p2b[e];
                        G32p[pr32 * SG32 + pc32] =
                            make_float4(z.x * pa, z.y * pa, z.x * pb, z.y * pb);
                    }
                }
            }
        }
        __syncthreads();
        if (tid < 256) {   // col stepA (packed)
            int line = tid & 31, a = tid >> 5;
            float2 f0[4], f1[4];
            #pragma unroll
            for (int kb = 0; kb < 4; ++kb) {
                float4 v = G32p[(4 * a + kb) * SG32 + line];
                f0[kb] = make_float2(v.x, v.y); f1[kb] = make_float2(v.z, v.w);
            }
            fft4<1>(f0); fft4<1>(f1);
            #pragma unroll
            for (int t = 0; t < 4; ++t) {
                float2 w = tw[4 * t * a];
                float2 aa = cmul(f0[t], w), d = cmul(f1[t], w);
                G32p[(4 * a + t) * SG32 + line] = make_float4(aa.x, aa.y, d.x, d.y);
            }
        }
        __syncthreads();
        if (tid < 128) {   // col stepB (packed)
            int line = tid & 31, t = tid >> 5;
            float2 f0[8], f1[8];
            #pragma unroll
            for (int a = 0; a < 8; ++a) {
                float4 v = G32p[(4 * a + t) * SG32 + line];
                f0[a] = make_float2(v.x, v.y); f1[a] = make_float2(v.z, v.w);
            }
            fft8<1>(f0); fft8<1>(f1);
            #pragma unroll
            for (int n1 = 0; n1 < 8; ++n1)
                G32p[(4 * n1 + t) * SG32 + line] =
                    make_float4(f0[n1].x, f0[n1].y, f1[n1].x, f1[n1].y);
        }
        __syncthreads();
        if (tid < 256) {   // row stepA (packed)
            int row = tid & 31, a = tid >> 5;
            float4* R = G32p + row * SG32 + 4 * a;
            float2 f0[4], f1[4];
            #pragma unroll
            for (int kb = 0; kb < 4; ++kb) {
                float4 v = R[kb];
                f0[kb] = make_float2(v.x, v.y); f1[kb] = make_float2(v.z, v.w);
            }
            fft4<1>(f0); fft4<1>(f1);
            #pragma unroll
            for (int t = 0; t < 4; ++t) {
                float2 w = tw[4 * t * a];
                float2 aa = cmul(f0[t], w), d = cmul(f1[t], w);
                R[t] = make_float4(aa.x, aa.y, d.x, d.y);
            }
        }
        __syncthreads();
        float a2 = 0.f;
        if (tid < 128) {   // row stepB + mag (packed)
            int row = tid & 31, t = tid >> 5;
            float4* R = G32p + row * SG32 + t;
            float2 f0[8], f1[8];
            #pragma unroll
            for (int a = 0; a < 8; ++a) {
                float4 v = R[4 * a];
                f0[a] = make_float2(v.x, v.y); f1[a] = make_float2(v.z, v.w);
            }
            fft8<1>(f0); fft8<1>(f1);
            #pragma unroll
            for (int n1 = 0; n1 < 8; ++n1) {
                a2 += sqrtf(f0[n1].x * f0[n1].x + f0[n1].y * f0[n1].y);
                a2 += sqrtf(f1[n1].x * f1[n1].x + f1[n1].y * f1[n1].y);
            }
        }
        float ws2 = waveReduceSum(a2);
        if ((tid & 63) == 0 && tid < 128)
            atomicAdd(&coeffs[b * 11 + 5 + 5], ws2 * S2_32);
        __syncthreads();
    }
}

// ---------- K_mlp: tiny MLP head (separate launch -- R12 lesson) ----------
__global__ void k_mlp(const float* __restrict__ coeffs,
                      const float* __restrict__ w1, const float* __restrict__ b1,
                      const float* __restrict__ w2, const float* __restrict__ b2,
                      float* __restrict__ out) {
    int b = threadIdx.x;
    if (b >= 64) return;
    float c[11];
    #pragma unroll
    for (int i = 0; i < 11; ++i) c[i] = coeffs[b * 11 + i];
    float h[4];
    #pragma unroll
    for (int k = 0; k < 4; ++k) {
        float s = b1[k];
        #pragma unroll
        for (int i = 0; i < 11; ++i) s += w1[k * 11 + i] * c[i];
        h[k] = fmaxf(s, 0.f);
    }
    #pragma unroll
    for (int o = 0; o < 10; ++o) {
        float s = b2[o];
        #pragma unroll
        for (int k = 0; k < 4; ++k) s += w2[o * 4 + k] * h[k];
        out[b * 10 + o] = 1.f / (1.f + expf(-s));
    }
}

extern "C" void kernel_launch(void* const* d_in, const int* in_sizes, int n_in,
                              void* d_out, int out_size, void* d_ws, size_t ws_size,
                              hipStream_t stream) {
    const float* img = (const float*)d_in[0];
    const float* w1  = (const float*)d_in[1];
    const float* b1  = (const float*)d_in[2];
    const float* w2  = (const float*)d_in[3];
    const float* b2  = (const float*)d_in[4];
    float* out = (float*)d_out;

    float*  ws     = (float*)d_ws;
    float*  psi    = ws;
    float2* ihat   = (float2*)(ws + 16 * NPIX);
    float*  coeffs = ws + 16 * NPIX + 2 * 64 * NPIX;

    hipLaunchKernelGGL(k_pre,        dim3(81),  dim3(TT), 0, stream, img, psi, ihat, coeffs);
    hipLaunchKernelGGL(k_scat_big,   dim3(512), dim3(TT), 0, stream, ihat, psi, coeffs);
    hipLaunchKernelGGL(k_scat_small, dim3(512), dim3(TT), 0, stream, ihat, psi, coeffs);
    hipLaunchKernelGGL(k_mlp,        dim3(1),   dim3(64), 0, stream, coeffs, w1, b1, w2, b2, out);
}

// Round 2
// 221.313 us; speedup vs baseline: 1.1016x; 1.0471x over previous
//
#include <hip/hip_runtime.h>
#include <math.h>

#define NN   128
#define SS   129          // LDS row stride in float2 (ODD -> conflict-free lane stride)
#define TT   512          // PROVEN: TT=512 allocates ~112-128 VGPR no-spill (R4/R6-R13);
                          // TT=1024 ALWAYS gets 64 VGPR + spill (R2/R3/R10). Never 1024.
#define NPIX 16384        // 128*128
#define EPT  32           // NPIX / TT
#define SG   65           // 64-grid row stride (float2 or float4 units)
#define SG32 33           // 32-grid row stride

// R12 lesson: NO __threadfence() tail / in-kernel MLP fold (cost ~115 us).
// R14: (j1=0,j2=1) on OFF-CENTER 64x64 frequency windows (|IFFT| invariant
//      to freq shift). Verified passing, absmax 0.0.
// R15 (this round): H buffer eliminated -- trunc staging read H[pr64*64+pc64]
//      written by the SAME thread at the SAME index == uh[i*16+kb] (pure
//      register round-trip). Freed 32 KB LDS buys FULL-WIDTH packing:
//      j2=1 in ONE pass over 4 float2 grids (G2a..G2d, 5 barriers, 32 pts/thr),
//      trunc j2 in ONE pass per j2 over two float4 grids (4 filters, 10 barriers).

__device__ __forceinline__ float2 cmul(float2 a, float2 w) {
    return make_float2(a.x * w.x - a.y * w.y, a.x * w.y + a.y * w.x);
}
__device__ __forceinline__ float2 cmulc(float2 a, float2 w) {   // a * conj(w)
    return make_float2(a.x * w.x + a.y * w.y, a.y * w.x - a.x * w.y);
}

// ---------- register FFT codelets (fft8/fft16 verified R2-R13) ----------
template<int SGN>
__device__ __forceinline__ void fft4(float2* f) {
    float2 t0 = make_float2(f[0].x + f[2].x, f[0].y + f[2].y);
    float2 t1 = make_float2(f[0].x - f[2].x, f[0].y - f[2].y);
    float2 t2 = make_float2(f[1].x + f[3].x, f[1].y + f[3].y);
    float2 t3 = make_float2(f[1].x - f[3].x, f[1].y - f[3].y);
    float2 t3i = (SGN > 0) ? make_float2(-t3.y, t3.x) : make_float2(t3.y, -t3.x);
    f[0] = make_float2(t0.x + t2.x, t0.y + t2.y);
    f[1] = make_float2(t1.x + t3i.x, t1.y + t3i.y);
    f[2] = make_float2(t0.x - t2.x, t0.y - t2.y);
    f[3] = make_float2(t1.x - t3i.x, t1.y - t3i.y);
}

template<int SGN>
__device__ __forceinline__ void fft8(float2* f) {
    const float R = 0.70710678118654752f;
    const float WC[4] = {1.f, R, 0.f, -R};
    const float WS[4] = {0.f, R, 1.f, R};
    #pragma unroll
    for (int stage = 0; stage < 3; ++stage) {
        const int L = 8 >> stage, half = L >> 1, step = 1 << stage;
        #pragma unroll
        for (int base = 0; base < 8; base += L) {
            #pragma unroll
            for (int j = 0; j < half; ++j) {
                float2 u = f[base + j], v = f[base + half + j];
                f[base + j] = make_float2(u.x + v.x, u.y + v.y);
                float dx = u.x - v.x, dy = u.y - v.y;
                const int t = j * step;
                const float wr = WC[t];
                const float wi = (SGN > 0) ? WS[t] : -WS[t];
                f[base + half + j] = make_float2(dx * wr - dy * wi, dx * wi + dy * wr);
            }
        }
    }
    float2 tmp;
    tmp = f[1]; f[1] = f[4]; f[4] = tmp;
    tmp = f[3]; f[3] = f[6]; f[6] = tmp;
}

template<int SGN>
__device__ __forceinline__ void fft16(float2* f) {
    const float WC[8] = {1.f, 0.92387953251f, 0.70710678119f, 0.38268343236f,
                         0.f, -0.38268343236f, -0.70710678119f, -0.92387953251f};
    const float WS[8] = {0.f, 0.38268343236f, 0.70710678119f, 0.92387953251f,
                         1.f, 0.92387953251f, 0.70710678119f, 0.38268343236f};
    #pragma unroll
    for (int stage = 0; stage < 4; ++stage) {
        const int L = 16 >> stage, half = L >> 1, step = 1 << stage;
        #pragma unroll
        for (int base = 0; base < 16; base += L) {
            #pragma unroll
            for (int j = 0; j < half; ++j) {
                float2 u = f[base + j], v = f[base + half + j];
                f[base + j] = make_float2(u.x + v.x, u.y + v.y);
                float dx = u.x - v.x, dy = u.y - v.y;
                const int t = j * step;
                const float wr = WC[t];
                const float wi = (SGN > 0) ? WS[t] : -WS[t];
                f[base + half + j] = make_float2(dx * wr - dy * wi, dx * wi + dy * wr);
            }
        }
    }
    float2 tmp;
    tmp = f[1];  f[1]  = f[8];  f[8]  = tmp;
    tmp = f[2];  f[2]  = f[4];  f[4]  = tmp;
    tmp = f[3];  f[3]  = f[12]; f[12] = tmp;
    tmp = f[5];  f[5]  = f[10]; f[10] = tmp;
    tmp = f[7];  f[7]  = f[14]; f[14] = tmp;
    tmp = f[11]; f[11] = f[13]; f[13] = tmp;
}

__device__ __forceinline__ float waveReduceSum(float v) {
    #pragma unroll
    for (int off = 32; off > 0; off >>= 1) v += __shfl_down(v, off, 64);
    return v;
}

__device__ __forceinline__ void buildTw(float2* tw, int tid) {
    if (tid < 128) {
        float s, c;
        __sincosf((float)tid * 0.04908738521234052f, &s, &c);   // 2*pi/128
        tw[tid] = make_float2(c, s);
    }
}

// ======== 128-grid sweep phases (R6-R13 proven, TT=512) ========
template<int ES, int LS>
__device__ __forceinline__ void fwdA(float2* __restrict__ F,
                                     const float2* __restrict__ tw, int tid) {
    #pragma unroll
    for (int i = 0; i < 4; ++i) {
        int u = i * TT + tid;
        int t = u >> 7, x = u & 127;
        float2* M = F + x * LS;
        float2 f[8];
        #pragma unroll
        for (int n1 = 0; n1 < 8; ++n1) f[n1] = M[(t + 16 * n1) * ES];
        fft8<-1>(f);
        #pragma unroll
        for (int ka = 0; ka < 8; ++ka)
            M[(t + 16 * ka) * ES] = cmulc(f[ka], tw[t * ka]);
    }
}

template<int ES, int LS>
__device__ __forceinline__ void fwdB(float2* __restrict__ F, int tid) {
    #pragma unroll
    for (int i = 0; i < 2; ++i) {
        int u = i * TT + tid;
        int ka = u >> 7, x = u & 127;
        float2* M = F + x * LS;
        float2 g[16];
        #pragma unroll
        for (int t = 0; t < 16; ++t) g[t] = M[(16 * ka + t) * ES];
        fft16<-1>(g);
        #pragma unroll
        for (int kb = 0; kb < 16; ++kb) M[(16 * ka + kb) * ES] = g[kb];
    }
}

__device__ __forceinline__ void fwdB_col_capture(const float2* __restrict__ F, int tid,
                                                 float2* __restrict__ uh) {
    #pragma unroll
    for (int i = 0; i < 2; ++i) {
        int u = i * TT + tid;
        int ka = u >> 7, c = u & 127;
        float2 g[16];
        #pragma unroll
        for (int t = 0; t < 16; ++t) g[t] = F[(16 * ka + t) * SS + c];
        fft16<-1>(g);
        #pragma unroll
        for (int kb = 0; kb < 16; ++kb) uh[i * 16 + kb] = g[kb];
    }
}

template<int ES, int LS>
__device__ __forceinline__ void invA(float2* __restrict__ F,
                                     const float2* __restrict__ tw, int tid) {
    #pragma unroll
    for (int i = 0; i < 2; ++i) {
        int u = i * TT + tid;
        int ka = u >> 7, x = u & 127;
        float2* M = F + x * LS;
        float2 g[16];
        #pragma unroll
        for (int kb = 0; kb < 16; ++kb) g[kb] = M[(16 * ka + kb) * ES];
        fft16<1>(g);
        #pragma unroll
        for (int t = 0; t < 16; ++t)
            M[(16 * ka + t) * ES] = cmul(g[t], tw[t * ka]);
    }
}

template<int ES, int LS>
__device__ __forceinline__ void invB(float2* __restrict__ F, int tid) {
    #pragma unroll
    for (int i = 0; i < 4; ++i) {
        int u = i * TT + tid;
        int t = u >> 7, x = u & 127;
        float2* M = F + x * LS;
        float2 f[8];
        #pragma unroll
        for (int ka = 0; ka < 8; ++ka) f[ka] = M[(16 * ka + t) * ES];
        fft8<1>(f);
        #pragma unroll
        for (int nh = 0; nh < 8; ++nh) M[(t + 16 * nh) * ES] = f[nh];
    }
}

// FUSED: inverse row stepB -> |.| (raw, acc) -> forward row stepA (same cells).
__device__ __forceinline__ void invBmag_fwdA_row(float2* __restrict__ F,
                                                 const float2* __restrict__ tw,
                                                 int tid, float& acc) {
    #pragma unroll
    for (int i = 0; i < 4; ++i) {
        int u = i * TT + tid;
        int t = u >> 7, x = u & 127;
        float2* M = F + x * SS;
        float2 f[8];
        #pragma unroll
        for (int ka = 0; ka < 8; ++ka) f[ka] = M[16 * ka + t];
        fft8<1>(f);
        #pragma unroll
        for (int nh = 0; nh < 8; ++nh) {
            float m = sqrtf(f[nh].x * f[nh].x + f[nh].y * f[nh].y);
            acc += m;
            f[nh] = make_float2(m, 0.f);
        }
        fft8<-1>(f);
        #pragma unroll
        for (int ka = 0; ka < 8; ++ka)
            M[t + 16 * ka] = cmulc(f[ka], tw[t * ka]);
    }
}

// ---------- K_pre: fused filter bank + coeff zero + i_hat FFT ----------
__global__ __attribute__((amdgpu_flat_work_group_size(TT, TT), amdgpu_waves_per_eu(2, 2)))
void k_pre(const float* __restrict__ img,
           float* __restrict__ psi,
           float2* __restrict__ ihat,
           float* __restrict__ coeffs) {
    __shared__ float2 F[NN * SS];
    __shared__ float2 tw[128];
    __shared__ float red[TT / 64];
    int blk = blockIdx.x, tid = threadIdx.x;
    if (blk >= 64) {
        if (blk == 80) {
            for (int i = tid; i < 64 * 11; i += TT)
                if (i % 11 != 0) coeffs[i] = 0.f;
            return;
        }
        int f = blk - 64;
        int j = f >> 2, l = f & 3;
        float k0    = 2.35619449019234493f / (float)(1 << j);
        float sigma = 0.8f * (float)(1 << j);
        float s2    = sigma * sigma;
        float theta = 0.78539816339744831f * (float)l;
        float k0x = k0 * cosf(theta);
        float k0y = k0 * sinf(theta);
        float beta = expf(-0.5f * s2 * k0 * k0);
        const float FSTEP = 0.04908738521234052f;
        float* dst = psi + (size_t)f * NPIX;
        for (int i = tid; i < NPIX; i += TT) {
            int pr = i >> 7, pc = i & 127;
            int kr = (pr >> 4) + 8 * (pr & 15);
            int kc = (pc >> 4) + 8 * (pc & 15);
            float fr = (float)(kr < 64 ? kr : kr - 128) * FSTEP;
            float fc = (float)(kc < 64 ? kc : kc - 128) * FSTEP;
            float dx = fr - k0x, dy = fc - k0y;
            float g1 = expf(-0.5f * s2 * (dx * dx + dy * dy));
            float g0 = expf(-0.5f * s2 * (fr * fr + fc * fc));
            dst[i] = g1 - beta * g0;
        }
        return;
    }
    int b = blk;
    buildTw(tw, tid);
    const float* im = img + (size_t)b * NPIX;
    float acc = 0.f;
    #pragma unroll
    for (int k = 0; k < EPT; ++k) {
        int e = k * TT + tid;
        float v = im[e];
        acc += v;
        F[(e >> 7) * SS + (e & 127)] = make_float2(v, 0.f);
    }
    float ws = waveReduceSum(acc);
    if ((tid & 63) == 0) red[tid >> 6] = ws;
    __syncthreads();
    if (tid == 0) {
        float t = 0.f;
        #pragma unroll
        for (int w = 0; w < TT / 64; ++w) t += red[w];
        coeffs[b * 11 + 0] = t * (1.f / 16384.f);
    }
    fwdA<1, SS>(F, tw, tid);  __syncthreads();
    fwdB<1, SS>(F, tid);      __syncthreads();
    fwdA<SS, 1>(F, tw, tid);  __syncthreads();
    float2 uh[32];
    fwdB_col_capture(F, tid, uh);
    float2* dst = ihat + (size_t)b * NPIX;
    #pragma unroll
    for (int i = 0; i < 2; ++i) {
        int u = i * TT + tid;
        int ka = u >> 7, c = u & 127;
        #pragma unroll
        for (int kb = 0; kb < 16; ++kb)
            dst[(16 * ka + kb) * NN + c] = uh[i * 16 + kb];
    }
}

// ---------- K_scat_big: j1 in {0,1} ----------
__global__ __attribute__((amdgpu_flat_work_group_size(TT, TT), amdgpu_waves_per_eu(2, 2)))
void k_scat_big(const float2* __restrict__ ihat,
                const float* __restrict__ psi,
                float* __restrict__ coeffs) {
    // F: 16640 float2 = 133,120 B.
    //   128-grid phases use F[0..16512) with stride SS.
    //   j2=1 one-pass: G2a..G2d = F + {0,4160,8320,12480}  (4x 64x65 float2)
    //   trunc passes:  G4a = (float4*)F, G4b = (float4*)(F+8320)  (2x 64x65 float4)
    __shared__ __align__(16) float2 F[16640];
    __shared__ float2 tw[128];
    float4* G4a = (float4*)F;
    float4* G4b = (float4*)(F + 8320);
    float2* G2a = F;
    float2* G2b = F + 4160;
    float2* G2c = F + 8320;
    float2* G2d = F + 12480;
    int tid = threadIdx.x;
    int x = blockIdx.x;
    int b = x & 63, l1 = (x >> 6) & 3, j1 = x >> 8;    // j1 in {0,1}
    const float2* ih = ihat + (size_t)b * NPIX;
    const float*  p1 = psi + (size_t)(j1 * 4 + l1) * NPIX;
    buildTw(tw, tid);

    const float S1_128 = 9.3132257461547852e-10f;   // 2^-30
    const float S2TR   = 5.6843418860808015e-14f;   // 2^-44

    int kalo = tid >> 7, c = tid & 127;
    {
        #pragma unroll
        for (int i = 0; i < 2; ++i) {
            int ka = kalo + 4 * i;
            float2 g[16];
            #pragma unroll
            for (int kb = 0; kb < 16; ++kb) {
                int e = (16 * ka + kb) * NN + c;
                float2 z = ih[e];
                float  p = p1[e];
                g[kb] = make_float2(z.x * p, z.y * p);
            }
            fft16<1>(g);
            #pragma unroll
            for (int t = 0; t < 16; ++t)
                F[(16 * ka + t) * SS + c] = cmul(g[t], tw[t * ka]);
        }
    }
    __syncthreads();
    invB<SS, 1>(F, tid);      __syncthreads();
    invA<1, SS>(F, tw, tid);  __syncthreads();
    float acc = 0.f;
    invBmag_fwdA_row(F, tw, tid, acc);
    float ws1 = waveReduceSum(acc);
    if ((tid & 63) == 0) atomicAdd(&coeffs[b * 11 + 1 + j1], ws1 * S1_128);
    __syncthreads();
    fwdB<1, SS>(F, tid);      __syncthreads();
    fwdA<SS, 1>(F, tw, tid);  __syncthreads();
    float2 uh[32];
    fwdB_col_capture(F, tid, uh);
    __syncthreads();   // capture done -> F reusable (grids alias it)

    // trunc-staging column perm (central +-32 window), shared by j2 in {2,3}
    int m = c & 15;
    bool colKeep = (m < 4) || (m >= 12);
    int pc64 = 8 * (c >> 4) + ((m < 4) ? m : (m - 8));

    if (j1 == 0) {
        // ===== (j1=0, j2=1): ONE pass, 4 off-center 64-windows (R14 mapping) =====
        // o per l2 (biased 3 bins to DC): l2=0:(21,0) 1:(15,15) 2:(0,21) 3:(-15,15)
        const int ORW[4] = {21, 15, 0, -15};
        const int OCW[4] = { 0, 15, 21,  15};
        int fc = (c >> 4) + 8 * (c & 15);
        bool ckw[4]; int pcw[4];
        #pragma unroll
        for (int w = 0; w < 4; ++w) {
            int dc = (fc - OCW[w]) & 127;
            ckw[w] = (dc < 32) || (dc >= 96);
            int uc = (dc < 32) ? dc : (dc - 64);
            pcw[w] = 8 * (uc & 7) + (uc >> 3);
        }
        #pragma unroll
        for (int i = 0; i < 2; ++i) {
            int ka = kalo + 4 * i;
            #pragma unroll
            for (int kb = 0; kb < 16; ++kb) {
                int fr = ka + 8 * kb;
                float2 z = uh[i * 16 + kb];
                int e = (16 * ka + kb) * NN + c;
                #pragma unroll
                for (int w = 0; w < 4; ++w) {
                    if (ckw[w]) {
                        int dr = (fr - ORW[w]) & 127;
                        if (dr < 32 || dr >= 96) {
                            int ur = (dr < 32) ? dr : (dr - 64);
                            int pr = 8 * (ur & 7) + (ur >> 3);
                            float pv = psi[(size_t)(4 + w) * NPIX + e];
                            float2* G = (w == 0) ? G2a : (w == 1) ? G2b
                                       : (w == 2) ? G2c : G2d;
                            G[pr * SG + pcw[w]] = make_float2(z.x * pv, z.y * pv);
                        }
                    }
                }
            }
        }
        __syncthreads();
        {   // col stepA (4 grids, full width)
            int col = tid & 63, k8 = tid >> 6;
            float2 f0[8], f1[8], f2[8], f3[8];
            #pragma unroll
            for (int kb = 0; kb < 8; ++kb) {
                int o = (8 * k8 + kb) * SG + col;
                f0[kb] = G2a[o]; f1[kb] = G2b[o]; f2[kb] = G2c[o]; f3[kb] = G2d[o];
            }
            fft8<1>(f0); fft8<1>(f1); fft8<1>(f2); fft8<1>(f3);
            #pragma unroll
            for (int q = 0; q < 8; ++q) {
                float2 w = tw[2 * q * k8];
                int o = (8 * k8 + q) * SG + col;
                G2a[o] = cmul(f0[q], w); G2b[o] = cmul(f1[q], w);
                G2c[o] = cmul(f2[q], w); G2d[o] = cmul(f3[q], w);
            }
        }
        __syncthreads();
        {   // col stepB
            int col = tid & 63, q = tid >> 6;
            float2 f0[8], f1[8], f2[8], f3[8];
            #pragma unroll
            for (int k8 = 0; k8 < 8; ++k8) {
                int o = (8 * k8 + q) * SG + col;
                f0[k8] = G2a[o]; f1[k8] = G2b[o]; f2[k8] = G2c[o]; f3[k8] = G2d[o];
            }
            fft8<1>(f0); fft8<1>(f1); fft8<1>(f2); fft8<1>(f3);
            #pragma unroll
            for (int n1 = 0; n1 < 8; ++n1) {
                int o = (8 * n1 + q) * SG + col;
                G2a[o] = f0[n1]; G2b[o] = f1[n1]; G2c[o] = f2[n1]; G2d[o] = f3[n1];
            }
        }
        __syncthreads();
        {   // row stepA
            int row = tid & 63, k8 = tid >> 6;
            int base = row * SG + 8 * k8;
            float2 f0[8], f1[8], f2[8], f3[8];
            #pragma unroll
            for (int kb = 0; kb < 8; ++kb) {
                f0[kb] = G2a[base + kb]; f1[kb] = G2b[base + kb];
                f2[kb] = G2c[base + kb]; f3[kb] = G2d[base + kb];
            }
            fft8<1>(f0); fft8<1>(f1); fft8<1>(f2); fft8<1>(f3);
            #pragma unroll
            for (int q = 0; q < 8; ++q) {
                float2 w = tw[2 * q * k8];
                G2a[base + q] = cmul(f0[q], w); G2b[base + q] = cmul(f1[q], w);
                G2c[base + q] = cmul(f2[q], w); G2d[base + q] = cmul(f3[q], w);
            }
        }
        __syncthreads();
        float a2 = 0.f;
        {   // row stepB + mag (all 4 -> same coeff)
            int row = tid & 63, q = tid >> 6;
            int base = row * SG + q;
            float2 f0[8], f1[8], f2[8], f3[8];
            #pragma unroll
            for (int k8 = 0; k8 < 8; ++k8) {
                int o = base + 8 * k8;
                f0[k8] = G2a[o]; f1[k8] = G2b[o]; f2[k8] = G2c[o]; f3[k8] = G2d[o];
            }
            fft8<1>(f0); fft8<1>(f1); fft8<1>(f2); fft8<1>(f3);
            #pragma unroll
            for (int n1 = 0; n1 < 8; ++n1) {
                a2 += sqrtf(f0[n1].x * f0[n1].x + f0[n1].y * f0[n1].y);
                a2 += sqrtf(f1[n1].x * f1[n1].x + f1[n1].y * f1[n1].y);
                a2 += sqrtf(f2[n1].x * f2[n1].x + f2[n1].y * f2[n1].y);
                a2 += sqrtf(f3[n1].x * f3[n1].x + f3[n1].y * f3[n1].y);
            }
        }
        float ws2 = waveReduceSum(a2);
        if ((tid & 63) == 0) atomicAdd(&coeffs[b * 11 + 5 + 0], ws2 * S2TR);
        __syncthreads();
    }

    // ===== truncated second order j2 in {2,3}: ONE pass per j2, 4 filters =====
    // (R15: staging reads uh directly -- H eliminated, identical indices proven)
    for (int j2 = 2; j2 <= 3; ++j2) {
        int pair = (j1 == 0) ? (j2 - 1) : (j2 + 1);
        const float* p0 = psi + (size_t)(j2 * 4 + 0) * NPIX;
        const float* pq1 = p0 + NPIX;
        const float* pq2 = pq1 + NPIX;
        const float* pq3 = pq2 + NPIX;
        if (colKeep) {
            #pragma unroll
            for (int i = 0; i < 2; ++i) {
                int ka = kalo + 4 * i;
                #pragma unroll
                for (int kb = 0; kb < 16; ++kb) {
                    if (kb < 4 || kb >= 12) {
                        int pr64 = 8 * ka + ((kb < 4) ? kb : (kb - 8));
                        float2 z = uh[i * 16 + kb];
                        int e = (16 * ka + kb) * NN + c;
                        float a0 = p0[e], a1 = pq1[e], a2f = pq2[e], a3 = pq3[e];
                        G4a[pr64 * SG + pc64] =
                            make_float4(z.x * a0, z.y * a0, z.x * a1, z.y * a1);
                        G4b[pr64 * SG + pc64] =
                            make_float4(z.x * a2f, z.y * a2f, z.x * a3, z.y * a3);
                    }
                }
            }
        }
        __syncthreads();
        {   // col stepA (two packed grids = 4 filters, full width)
            int col = tid & 63, k8 = tid >> 6;
            float2 f0[8], f1[8], f2[8], f3[8];
            #pragma unroll
            for (int kb = 0; kb < 8; ++kb) {
                int o = (8 * k8 + kb) * SG + col;
                float4 v = G4a[o];
                f0[kb] = make_float2(v.x, v.y); f1[kb] = make_float2(v.z, v.w);
                float4 u = G4b[o];
                f2[kb] = make_float2(u.x, u.y); f3[kb] = make_float2(u.z, u.w);
            }
            fft8<1>(f0); fft8<1>(f1); fft8<1>(f2); fft8<1>(f3);
            #pragma unroll
            for (int q = 0; q < 8; ++q) {
                float2 w = tw[2 * q * k8];
                int o = (8 * k8 + q) * SG + col;
                float2 a = cmul(f0[q], w), d = cmul(f1[q], w);
                G4a[o] = make_float4(a.x, a.y, d.x, d.y);
                float2 a2c = cmul(f2[q], w), d2 = cmul(f3[q], w);
                G4b[o] = make_float4(a2c.x, a2c.y, d2.x, d2.y);
            }
        }
        __syncthreads();
        {   // col stepB
            int col = tid & 63, q = tid >> 6;
            float2 f0[8], f1[8], f2[8], f3[8];
            #pragma unroll
            for (int k8 = 0; k8 < 8; ++k8) {
                int o = (8 * k8 + q) * SG + col;
                float4 v = G4a[o];
                f0[k8] = make_float2(v.x, v.y); f1[k8] = make_float2(v.z, v.w);
                float4 u = G4b[o];
                f2[k8] = make_float2(u.x, u.y); f3[k8] = make_float2(u.z, u.w);
            }
            fft8<1>(f0); fft8<1>(f1); fft8<1>(f2); fft8<1>(f3);
            #pragma unroll
            for (int n1 = 0; n1 < 8; ++n1) {
                int o = (8 * n1 + q) * SG + col;
                G4a[o] = make_float4(f0[n1].x, f0[n1].y, f1[n1].x, f1[n1].y);
                G4b[o] = make_float4(f2[n1].x, f2[n1].y, f3[n1].x, f3[n1].y);
            }
        }
        __syncthreads();
        {   // row stepA
            int row = tid & 63, k8 = tid >> 6;
            int base = row * SG + 8 * k8;
            float2 f0[8], f1[8], f2[8], f3[8];
            #pragma unroll
            for (int kb = 0; kb < 8; ++kb) {
                float4 v = G4a[base + kb];
                f0[kb] = make_float2(v.x, v.y); f1[kb] = make_float2(v.z, v.w);
                float4 u = G4b[base + kb];
                f2[kb] = make_float2(u.x, u.y); f3[kb] = make_float2(u.z, u.w);
            }
            fft8<1>(f0); fft8<1>(f1); fft8<1>(f2); fft8<1>(f3);
            #pragma unroll
            for (int q = 0; q < 8; ++q) {
                float2 w = tw[2 * q * k8];
                float2 a = cmul(f0[q], w), d = cmul(f1[q], w);
                G4a[base + q] = make_float4(a.x, a.y, d.x, d.y);
                float2 a2c = cmul(f2[q], w), d2 = cmul(f3[q], w);
                G4b[base + q] = make_float4(a2c.x, a2c.y, d2.x, d2.y);
            }
        }
        __syncthreads();
        float a2 = 0.f;
        {   // row stepB + mag
            int row = tid & 63, q = tid >> 6;
            int base = row * SG + q;
            float2 f0[8], f1[8], f2[8], f3[8];
            #pragma unroll
            for (int k8 = 0; k8 < 8; ++k8) {
                float4 v = G4a[base + 8 * k8];
                f0[k8] = make_float2(v.x, v.y); f1[k8] = make_float2(v.z, v.w);
                float4 u = G4b[base + 8 * k8];
                f2[k8] = make_float2(u.x, u.y); f3[k8] = make_float2(u.z, u.w);
            }
            fft8<1>(f0); fft8<1>(f1); fft8<1>(f2); fft8<1>(f3);
            #pragma unroll
            for (int n1 = 0; n1 < 8; ++n1) {
                a2 += sqrtf(f0[n1].x * f0[n1].x + f0[n1].y * f0[n1].y);
                a2 += sqrtf(f1[n1].x * f1[n1].x + f1[n1].y * f1[n1].y);
                a2 += sqrtf(f2[n1].x * f2[n1].x + f2[n1].y * f2[n1].y);
                a2 += sqrtf(f3[n1].x * f3[n1].x + f3[n1].y * f3[n1].y);
            }
        }
        float ws2 = waveReduceSum(a2);
        if ((tid & 63) == 0) atomicAdd(&coeffs[b * 11 + 5 + pair], ws2 * S2TR);
        __syncthreads();
    }
}

// ---------- K_scat_small: j1 in {2,3} -- 43 KB LDS => 2+ blocks/CU ----------
__global__ __attribute__((amdgpu_flat_work_group_size(TT, TT), amdgpu_waves_per_eu(4, 4)))
void k_scat_small(const float2* __restrict__ ihat,
                  const float* __restrict__ psi,
                  float* __restrict__ coeffs) {
    // S layout: G2 = S[0..4160) (64x65); H32 = S[4160..5184) (32x32, perm32 freq);
    // G32 (single 32-grid, 32x33) and G32p (packed float4 32x33) alias S[0..).
    __shared__ __align__(16) float2 S[5184];
    __shared__ float2 tw[128];
    float2* G2  = S;
    float2* G32 = S;
    float4* G32p = (float4*)S;
    float2* H32 = S + 4160;
    int tid = threadIdx.x;
    int x = blockIdx.x;
    int b = x & 63, l1 = (x >> 6) & 3, j1 = 2 + (x >> 8);
    const float2* ih = ihat + (size_t)b * NPIX;
    const float*  p1 = psi + (size_t)(j1 * 4 + l1) * NPIX;
    buildTw(tw, tid);

    const float S1_64 = 3.7252902984619141e-9f;    // 2^-28
    const float S1_32 = 1.4901161193847656e-8f;    // 2^-26
    const float S2_32 = 9.0949470177292824e-13f;   // 2^-40

    int kalo = tid >> 7, c = tid & 127;

    if (j1 == 3) {
        // ===== 32-grid first order: psi_{j1=3} support +-16 (3.07 sigma margin) =====
        int m = c & 15;
        bool ck32 = (m < 2) || (m >= 14);
        int pc32 = 4 * (c >> 4) + ((m < 2) ? m : (m - 12));
        if (ck32) {
            #pragma unroll
            for (int i = 0; i < 2; ++i) {
                int ka = kalo + 4 * i;
                #pragma unroll
                for (int kb = 0; kb < 16; ++kb) {
                    if (kb < 2 || kb >= 14) {
                        int e = (16 * ka + kb) * NN + c;
                        float2 z = ih[e];
                        float  p = p1[e];
                        int pr32 = 4 * ka + ((kb < 2) ? kb : (kb - 12));
                        G32[pr32 * SG32 + pc32] = make_float2(z.x * p, z.y * p);
                    }
                }
            }
        }
        __syncthreads();
        if (tid < 256) {   // col stepA: fft4 over b per a (32 lines x 8 a)
            int line = tid & 31, a = tid >> 5;
            float2 f[4];
            #pragma unroll
            for (int kb = 0; kb < 4; ++kb) f[kb] = G32[(4 * a + kb) * SG32 + line];
            fft4<1>(f);
            #pragma unroll
            for (int t = 0; t < 4; ++t)
                G32[(4 * a + t) * SG32 + line] = cmul(f[t], tw[4 * t * a]);
        }
        __syncthreads();
        if (tid < 128) {   // col stepB: fft8 over a per t (32 lines x 4 t)
            int line = tid & 31, t = tid >> 5;
            float2 f[8];
            #pragma unroll
            for (int a = 0; a < 8; ++a) f[a] = G32[(4 * a + t) * SG32 + line];
            fft8<1>(f);
            #pragma unroll
            for (int n1 = 0; n1 < 8; ++n1) G32[(4 * n1 + t) * SG32 + line] = f[n1];
        }
        __syncthreads();
        if (tid < 256) {   // row stepA
            int row = tid & 31, a = tid >> 5;
            float2* R = G32 + row * SG32 + 4 * a;
            float2 f[4];
            #pragma unroll
            for (int kb = 0; kb < 4; ++kb) f[kb] = R[kb];
            fft4<1>(f);
            #pragma unroll
            for (int t = 0; t < 4; ++t) R[t] = cmul(f[t], tw[4 * t * a]);
        }
        __syncthreads();
        float acc = 0.f;
        if (tid < 128) {   // row stepB + mag
            int row = tid & 31, t = tid >> 5;
            float2* R = G32 + row * SG32 + t;
            float2 f[8];
            #pragma unroll
            for (int a = 0; a < 8; ++a) f[a] = R[4 * a];
            fft8<1>(f);
            #pragma unroll
            for (int n1 = 0; n1 < 8; ++n1)
                acc += sqrtf(f[n1].x * f[n1].x + f[n1].y * f[n1].y);
        }
        float ws1 = waveReduceSum(acc);
        if ((tid & 63) == 0 && tid < 128) atomicAdd(&coeffs[b * 11 + 4], ws1 * S1_32);
        return;
    }

    // ===================== j1 == 2: 64-grid first order (R13-proven) ==============
    int m = c & 15;
    bool colKeep = (m < 4) || (m >= 12);
    if (colKeep) {
        #pragma unroll
        for (int i = 0; i < 2; ++i) {
            int ka = kalo + 4 * i;
            #pragma unroll
            for (int kb = 0; kb < 16; ++kb) {
                if (kb < 4 || kb >= 12) {
                    int e = (16 * ka + kb) * NN + c;
                    float2 z = ih[e];
                    float  p = p1[e];
                    int pr64 = 8 * ka + ((kb < 4) ? kb : (kb - 8));
                    int pc64 = 8 * (c >> 4) + ((m < 4) ? m : (m - 8));
                    G2[pr64 * SG + pc64] = make_float2(z.x * p, z.y * p);
                }
            }
        }
    }
    __syncthreads();
    {   // col stepA (inverse)
        int col = tid & 63, k8 = tid >> 6;
        float2 f[8];
        #pragma unroll
        for (int kb = 0; kb < 8; ++kb) f[kb] = G2[(8 * k8 + kb) * SG + col];
        fft8<1>(f);
        #pragma unroll
        for (int q = 0; q < 8; ++q)
            G2[(8 * k8 + q) * SG + col] = cmul(f[q], tw[2 * q * k8]);
    }
    __syncthreads();
    {   // col stepB
        int col = tid & 63, q = tid >> 6;
        float2 f[8];
        #pragma unroll
        for (int k8 = 0; k8 < 8; ++k8) f[k8] = G2[(8 * k8 + q) * SG + col];
        fft8<1>(f);
        #pragma unroll
        for (int n1 = 0; n1 < 8; ++n1) G2[(8 * n1 + q) * SG + col] = f[n1];
    }
    __syncthreads();
    {   // row stepA (inverse)
        int row = tid & 63, k8 = tid >> 6;
        float2* R = G2 + row * SG + 8 * k8;
        float2 f[8];
        #pragma unroll
        for (int kb = 0; kb < 8; ++kb) f[kb] = R[kb];
        fft8<1>(f);
        #pragma unroll
        for (int q = 0; q < 8; ++q) R[q] = cmul(f[q], tw[2 * q * k8]);
    }
    __syncthreads();
    float acc = 0.f;
    {   // FUSED64: row stepB inv -> |.| (raw) -> row stepA fwd (same cells)
        int row = tid & 63, q = tid >> 6;
        float2* R = G2 + row * SG + q;
        float2 f[8];
        #pragma unroll
        for (int k8 = 0; k8 < 8; ++k8) f[k8] = R[8 * k8];
        fft8<1>(f);
        #pragma unroll
        for (int n1 = 0; n1 < 8; ++n1) {
            float mg = sqrtf(f[n1].x * f[n1].x + f[n1].y * f[n1].y);
            acc += mg;
            f[n1] = make_float2(mg, 0.f);
        }
        fft8<-1>(f);
        #pragma unroll
        for (int ka = 0; ka < 8; ++ka)
            R[8 * ka] = cmulc(f[ka], tw[2 * q * ka]);
    }
    float ws1 = waveReduceSum(acc);
    if ((tid & 63) == 0) atomicAdd(&coeffs[b * 11 + 3], ws1 * S1_64);
    __syncthreads();
    {   // row stepB (forward)
        int row2 = tid & 63, ka = tid >> 6;
        float2* R2 = G2 + row2 * SG + 8 * ka;
        float2 g[8];
        #pragma unroll
        for (int t = 0; t < 8; ++t) g[t] = R2[t];
        fft8<-1>(g);
        #pragma unroll
        for (int kb = 0; kb < 8; ++kb) R2[kb] = g[kb];
    }
    __syncthreads();
    {   // col stepA (forward)
        int col = tid & 63, t = tid >> 6;
        float2 g[8];
        #pragma unroll
        for (int n1 = 0; n1 < 8; ++n1) g[n1] = G2[(t + 8 * n1) * SG + col];
        fft8<-1>(g);
        #pragma unroll
        for (int ka = 0; ka < 8; ++ka)
            G2[(t + 8 * ka) * SG + col] = cmulc(g[ka], tw[2 * t * ka]);
    }
    __syncthreads();
    {   // col stepB (forward) -> H32: central +-16 of V only (perm32 layout)
        int col = tid & 63, ka = tid >> 6;
        float2 g[8];
        #pragma unroll
        for (int t = 0; t < 8; ++t) g[t] = G2[(8 * ka + t) * SG + col];
        fft8<-1>(g);
        int br = col & 7, ar = col >> 3;
        if (br < 2 || br >= 6) {
            int p32row = 4 * ar + (br & 3);
            #pragma unroll
            for (int kb = 0; kb < 8; ++kb) {
                if (kb < 2 || kb >= 6)
                    H32[(4 * ka + (kb & 3)) * 32 + p32row] = g[kb];
            }
        }
    }
    __syncthreads();

    // ===== truncated second order j2 = 3 on the 32-grid, 2 filters packed =====
    bool ck32 = (m < 2) || (m >= 14);
    int pc32 = 4 * (c >> 4) + ((m < 2) ? m : (m - 12));
    for (int half = 0; half < 2; ++half) {
        const float* p2a = psi + (size_t)(12 + 2 * half) * NPIX;
        const float* p2b = p2a + NPIX;
        if (ck32) {
            #pragma unroll
            for (int i = 0; i < 2; ++i) {
                int ka = kalo + 4 * i;
                #pragma unroll
                for (int kb = 0; kb < 16; ++kb) {
                    if (kb < 2 || kb >= 14) {
                        int pr32 = 4 * ka + ((kb < 2) ? kb : (kb - 12));
                        float2 z = H32[pr32 * 32 + pc32];
                        int e = (16 * ka + kb) * NN + c;
                        float pa = p2a[e], pb = p2b[e];
                        G32p[pr32 * SG32 + pc32] =
                            make_float4(z.x * pa, z.y * pa, z.x * pb, z.y * pb);
                    }
                }
            }
        }
        __syncthreads();
        if (tid < 256) {   // col stepA (packed)
            int line = tid & 31, a = tid >> 5;
            float2 f0[4], f1[4];
            #pragma unroll
            for (int kb = 0; kb < 4; ++kb) {
                float4 v = G32p[(4 * a + kb) * SG32 + line];
                f0[kb] = make_float2(v.x, v.y); f1[kb] = make_float2(v.z, v.w);
            }
            fft4<1>(f0); fft4<1>(f1);
            #pragma unroll
            for (int t = 0; t < 4; ++t) {
                float2 w = tw[4 * t * a];
                float2 aa = cmul(f0[t], w), d = cmul(f1[t], w);
                G32p[(4 * a + t) * SG32 + line] = make_float4(aa.x, aa.y, d.x, d.y);
            }
        }
        __syncthreads();
        if (tid < 128) {   // col stepB (packed)
            int line = tid & 31, t = tid >> 5;
            float2 f0[8], f1[8];
            #pragma unroll
            for (int a = 0; a < 8; ++a) {
                float4 v = G32p[(4 * a + t) * SG32 + line];
                f0[a] = make_float2(v.x, v.y); f1[a] = make_float2(v.z, v.w);
            }
            fft8<1>(f0); fft8<1>(f1);
            #pragma unroll
            for (int n1 = 0; n1 < 8; ++n1)
                G32p[(4 * n1 + t) * SG32 + line] =
                    make_float4(f0[n1].x, f0[n1].y, f1[n1].x, f1[n1].y);
        }
        __syncthreads();
        if (tid < 256) {   // row stepA (packed)
            int row = tid & 31, a = tid >> 5;
            float4* R = G32p + row * SG32 + 4 * a;
            float2 f0[4], f1[4];
            #pragma unroll
            for (int kb = 0; kb < 4; ++kb) {
                float4 v = R[kb];
                f0[kb] = make_float2(v.x, v.y); f1[kb] = make_float2(v.z, v.w);
            }
            fft4<1>(f0); fft4<1>(f1);
            #pragma unroll
            for (int t = 0; t < 4; ++t) {
                float2 w = tw[4 * t * a];
                float2 aa = cmul(f0[t], w), d = cmul(f1[t], w);
                R[t] = make_float4(aa.x, aa.y, d.x, d.y);
            }
        }
        __syncthreads();
        float a2 = 0.f;
        if (tid < 128) {   // row stepB + mag (packed)
            int row = tid & 31, t = tid >> 5;
            float4* R = G32p + row * SG32 + t;
            float2 f0[8], f1[8];
            #pragma unroll
            for (int a = 0; a < 8; ++a) {
                float4 v = R[4 * a];
                f0[a] = make_float2(v.x, v.y); f1[a] = make_float2(v.z, v.w);
            }
            fft8<1>(f0); fft8<1>(f1);
            #pragma unroll
            for (int n1 = 0; n1 < 8; ++n1) {
                a2 += sqrtf(f0[n1].x * f0[n1].x + f0[n1].y * f0[n1].y);
                a2 += sqrtf(f1[n1].x * f1[n1].x + f1[n1].y * f1[n1].y);
            }
        }
        float ws2 = waveReduceSum(a2);
        if ((tid & 63) == 0 && tid < 128)
            atomicAdd(&coeffs[b * 11 + 5 + 5], ws2 * S2_32);
        __syncthreads();
    }
}

// ---------- K_mlp: tiny MLP head (separate launch -- R12 lesson) ----------
__global__ void k_mlp(const float* __restrict__ coeffs,
                      const float* __restrict__ w1, const float* __restrict__ b1,
                      const float* __restrict__ w2, const float* __restrict__ b2,
                      float* __restrict__ out) {
    int b = threadIdx.x;
    if (b >= 64) return;
    float c[11];
    #pragma unroll
    for (int i = 0; i < 11; ++i) c[i] = coeffs[b * 11 + i];
    float h[4];
    #pragma unroll
    for (int k = 0; k < 4; ++k) {
        float s = b1[k];
        #pragma unroll
        for (int i = 0; i < 11; ++i) s += w1[k * 11 + i] * c[i];
        h[k] = fmaxf(s, 0.f);
    }
    #pragma unroll
    for (int o = 0; o < 10; ++o) {
        float s = b2[o];
        #pragma unroll
        for (int k = 0; k < 4; ++k) s += w2[o * 4 + k] * h[k];
        out[b * 10 + o] = 1.f / (1.f + expf(-s));
    }
}

extern "C" void kernel_launch(void* const* d_in, const int* in_sizes, int n_in,
                              void* d_out, int out_size, void* d_ws, size_t ws_size,
                              hipStream_t stream) {
    const float* img = (const float*)d_in[0];
    const float* w1  = (const float*)d_in[1];
    const float* b1  = (const float*)d_in[2];
    const float* w2  = (const float*)d_in[3];
    const float* b2  = (const float*)d_in[4];
    float* out = (float*)d_out;

    float*  ws     = (float*)d_ws;
    float*  psi    = ws;
    float2* ihat   = (float2*)(ws + 16 * NPIX);
    float*  coeffs = ws + 16 * NPIX + 2 * 64 * NPIX;

    hipLaunchKernelGGL(k_pre,        dim3(81),  dim3(TT), 0, stream, img, psi, ihat, coeffs);
    hipLaunchKernelGGL(k_scat_big,   dim3(512), dim3(TT), 0, stream, ihat, psi, coeffs);
    hipLaunchKernelGGL(k_scat_small, dim3(512), dim3(TT), 0, stream, ihat, psi, coeffs);
    hipLaunchKernelGGL(k_mlp,        dim3(1),   dim3(64), 0, stream, coeffs, w1, b1, w2, b2, out);
}

// Round 3
// 198.470 us; speedup vs baseline: 1.2283x; 1.1151x over previous
//
#include <hip/hip_runtime.h>
#include <math.h>

#define NN   128
#define SS   129          // LDS row stride in float2 (ODD -> conflict-free lane stride)
#define TT   512          // PROVEN: TT=512 allocates ~112-128 VGPR no-spill (R4/R6-R13);
                          // TT=1024 ALWAYS gets 64 VGPR + spill (R2/R3/R10). Never 1024.
#define NPIX 16384        // 128*128
#define EPT  32           // NPIX / TT
#define SG   65           // 64-grid row stride (float2 or float4 units)
#define SG32 33           // 32-grid row stride

// R12 lesson: NO __threadfence() tail / in-kernel MLP fold (cost ~115 us).
// R14: (j1=0,j2=1) on OFF-CENTER 64x64 frequency windows. Proven absmax 0.0.
// R15: H eliminated (register round-trip); full-width packed passes.
// R16 (this round): j1=1 retired from the 128-grid. First order on off-center
//   64-window (same R14 mapping, filter center bin 24, sigma_f 12.7); u1hat_64
//   = FFT64(u1_64) = uh/4 on the central +-32 window (exactly what the proven
//   trunc path consumed). Second-order constant 4*S2TR = 2^-42 (scale law
//   validated by proven S1_64=4*S1_128 and S2_32=16*S2TR).
//   k_scat_big -> j1=0 only, grid 256 = ONE round. k_scat_small -> grid 768.

__device__ __forceinline__ float2 cmul(float2 a, float2 w) {
    return make_float2(a.x * w.x - a.y * w.y, a.x * w.y + a.y * w.x);
}
__device__ __forceinline__ float2 cmulc(float2 a, float2 w) {   // a * conj(w)
    return make_float2(a.x * w.x + a.y * w.y, a.y * w.x - a.x * w.y);
}

// ---------- register FFT codelets (fft8/fft16 verified R2-R13) ----------
template<int SGN>
__device__ __forceinline__ void fft4(float2* f) {
    float2 t0 = make_float2(f[0].x + f[2].x, f[0].y + f[2].y);
    float2 t1 = make_float2(f[0].x - f[2].x, f[0].y - f[2].y);
    float2 t2 = make_float2(f[1].x + f[3].x, f[1].y + f[3].y);
    float2 t3 = make_float2(f[1].x - f[3].x, f[1].y - f[3].y);
    float2 t3i = (SGN > 0) ? make_float2(-t3.y, t3.x) : make_float2(t3.y, -t3.x);
    f[0] = make_float2(t0.x + t2.x, t0.y + t2.y);
    f[1] = make_float2(t1.x + t3i.x, t1.y + t3i.y);
    f[2] = make_float2(t0.x - t2.x, t0.y - t2.y);
    f[3] = make_float2(t1.x - t3i.x, t1.y - t3i.y);
}

template<int SGN>
__device__ __forceinline__ void fft8(float2* f) {
    const float R = 0.70710678118654752f;
    const float WC[4] = {1.f, R, 0.f, -R};
    const float WS[4] = {0.f, R, 1.f, R};
    #pragma unroll
    for (int stage = 0; stage < 3; ++stage) {
        const int L = 8 >> stage, half = L >> 1, step = 1 << stage;
        #pragma unroll
        for (int base = 0; base < 8; base += L) {
            #pragma unroll
            for (int j = 0; j < half; ++j) {
                float2 u = f[base + j], v = f[base + half + j];
                f[base + j] = make_float2(u.x + v.x, u.y + v.y);
                float dx = u.x - v.x, dy = u.y - v.y;
                const int t = j * step;
                const float wr = WC[t];
                const float wi = (SGN > 0) ? WS[t] : -WS[t];
                f[base + half + j] = make_float2(dx * wr - dy * wi, dx * wi + dy * wr);
            }
        }
    }
    float2 tmp;
    tmp = f[1]; f[1] = f[4]; f[4] = tmp;
    tmp = f[3]; f[3] = f[6]; f[6] = tmp;
}

template<int SGN>
__device__ __forceinline__ void fft16(float2* f) {
    const float WC[8] = {1.f, 0.92387953251f, 0.70710678119f, 0.38268343236f,
                         0.f, -0.38268343236f, -0.70710678119f, -0.92387953251f};
    const float WS[8] = {0.f, 0.38268343236f, 0.70710678119f, 0.92387953251f,
                         1.f, 0.92387953251f, 0.70710678119f, 0.38268343236f};
    #pragma unroll
    for (int stage = 0; stage < 4; ++stage) {
        const int L = 16 >> stage, half = L >> 1, step = 1 << stage;
        #pragma unroll
        for (int base = 0; base < 16; base += L) {
            #pragma unroll
            for (int j = 0; j < half; ++j) {
                float2 u = f[base + j], v = f[base + half + j];
                f[base + j] = make_float2(u.x + v.x, u.y + v.y);
                float dx = u.x - v.x, dy = u.y - v.y;
                const int t = j * step;
                const float wr = WC[t];
                const float wi = (SGN > 0) ? WS[t] : -WS[t];
                f[base + half + j] = make_float2(dx * wr - dy * wi, dx * wi + dy * wr);
            }
        }
    }
    float2 tmp;
    tmp = f[1];  f[1]  = f[8];  f[8]  = tmp;
    tmp = f[2];  f[2]  = f[4];  f[4]  = tmp;
    tmp = f[3];  f[3]  = f[12]; f[12] = tmp;
    tmp = f[5];  f[5]  = f[10]; f[10] = tmp;
    tmp = f[7];  f[7]  = f[14]; f[14] = tmp;
    tmp = f[11]; f[11] = f[13]; f[13] = tmp;
}

__device__ __forceinline__ float waveReduceSum(float v) {
    #pragma unroll
    for (int off = 32; off > 0; off >>= 1) v += __shfl_down(v, off, 64);
    return v;
}

__device__ __forceinline__ void buildTw(float2* tw, int tid) {
    if (tid < 128) {
        float s, c;
        __sincosf((float)tid * 0.04908738521234052f, &s, &c);   // 2*pi/128
        tw[tid] = make_float2(c, s);
    }
}

// ======== 128-grid sweep phases (R6-R13 proven, TT=512) ========
template<int ES, int LS>
__device__ __forceinline__ void fwdA(float2* __restrict__ F,
                                     const float2* __restrict__ tw, int tid) {
    #pragma unroll
    for (int i = 0; i < 4; ++i) {
        int u = i * TT + tid;
        int t = u >> 7, x = u & 127;
        float2* M = F + x * LS;
        float2 f[8];
        #pragma unroll
        for (int n1 = 0; n1 < 8; ++n1) f[n1] = M[(t + 16 * n1) * ES];
        fft8<-1>(f);
        #pragma unroll
        for (int ka = 0; ka < 8; ++ka)
            M[(t + 16 * ka) * ES] = cmulc(f[ka], tw[t * ka]);
    }
}

template<int ES, int LS>
__device__ __forceinline__ void fwdB(float2* __restrict__ F, int tid) {
    #pragma unroll
    for (int i = 0; i < 2; ++i) {
        int u = i * TT + tid;
        int ka = u >> 7, x = u & 127;
        float2* M = F + x * LS;
        float2 g[16];
        #pragma unroll
        for (int t = 0; t < 16; ++t) g[t] = M[(16 * ka + t) * ES];
        fft16<-1>(g);
        #pragma unroll
        for (int kb = 0; kb < 16; ++kb) M[(16 * ka + kb) * ES] = g[kb];
    }
}

__device__ __forceinline__ void fwdB_col_capture(const float2* __restrict__ F, int tid,
                                                 float2* __restrict__ uh) {
    #pragma unroll
    for (int i = 0; i < 2; ++i) {
        int u = i * TT + tid;
        int ka = u >> 7, c = u & 127;
        float2 g[16];
        #pragma unroll
        for (int t = 0; t < 16; ++t) g[t] = F[(16 * ka + t) * SS + c];
        fft16<-1>(g);
        #pragma unroll
        for (int kb = 0; kb < 16; ++kb) uh[i * 16 + kb] = g[kb];
    }
}

template<int ES, int LS>
__device__ __forceinline__ void invA(float2* __restrict__ F,
                                     const float2* __restrict__ tw, int tid) {
    #pragma unroll
    for (int i = 0; i < 2; ++i) {
        int u = i * TT + tid;
        int ka = u >> 7, x = u & 127;
        float2* M = F + x * LS;
        float2 g[16];
        #pragma unroll
        for (int kb = 0; kb < 16; ++kb) g[kb] = M[(16 * ka + kb) * ES];
        fft16<1>(g);
        #pragma unroll
        for (int t = 0; t < 16; ++t)
            M[(16 * ka + t) * ES] = cmul(g[t], tw[t * ka]);
    }
}

template<int ES, int LS>
__device__ __forceinline__ void invB(float2* __restrict__ F, int tid) {
    #pragma unroll
    for (int i = 0; i < 4; ++i) {
        int u = i * TT + tid;
        int t = u >> 7, x = u & 127;
        float2* M = F + x * LS;
        float2 f[8];
        #pragma unroll
        for (int ka = 0; ka < 8; ++ka) f[ka] = M[(16 * ka + t) * ES];
        fft8<1>(f);
        #pragma unroll
        for (int nh = 0; nh < 8; ++nh) M[(t + 16 * nh) * ES] = f[nh];
    }
}

// FUSED: inverse row stepB -> |.| (raw, acc) -> forward row stepA (same cells).
__device__ __forceinline__ void invBmag_fwdA_row(float2* __restrict__ F,
                                                 const float2* __restrict__ tw,
                                                 int tid, float& acc) {
    #pragma unroll
    for (int i = 0; i < 4; ++i) {
        int u = i * TT + tid;
        int t = u >> 7, x = u & 127;
        float2* M = F + x * SS;
        float2 f[8];
        #pragma unroll
        for (int ka = 0; ka < 8; ++ka) f[ka] = M[16 * ka + t];
        fft8<1>(f);
        #pragma unroll
        for (int nh = 0; nh < 8; ++nh) {
            float m = sqrtf(f[nh].x * f[nh].x + f[nh].y * f[nh].y);
            acc += m;
            f[nh] = make_float2(m, 0.f);
        }
        fft8<-1>(f);
        #pragma unroll
        for (int ka = 0; ka < 8; ++ka)
            M[t + 16 * ka] = cmulc(f[ka], tw[t * ka]);
    }
}

// ---------- K_pre: fused filter bank + coeff zero + i_hat FFT ----------
__global__ __attribute__((amdgpu_flat_work_group_size(TT, TT), amdgpu_waves_per_eu(2, 2)))
void k_pre(const float* __restrict__ img,
           float* __restrict__ psi,
           float2* __restrict__ ihat,
           float* __restrict__ coeffs) {
    __shared__ float2 F[NN * SS];
    __shared__ float2 tw[128];
    __shared__ float red[TT / 64];
    int blk = blockIdx.x, tid = threadIdx.x;
    if (blk >= 64) {
        if (blk == 80) {
            for (int i = tid; i < 64 * 11; i += TT)
                if (i % 11 != 0) coeffs[i] = 0.f;
            return;
        }
        int f = blk - 64;
        int j = f >> 2, l = f & 3;
        float k0    = 2.35619449019234493f / (float)(1 << j);
        float sigma = 0.8f * (float)(1 << j);
        float s2    = sigma * sigma;
        float theta = 0.78539816339744831f * (float)l;
        float k0x = k0 * cosf(theta);
        float k0y = k0 * sinf(theta);
        float beta = expf(-0.5f * s2 * k0 * k0);
        const float FSTEP = 0.04908738521234052f;
        float* dst = psi + (size_t)f * NPIX;
        for (int i = tid; i < NPIX; i += TT) {
            int pr = i >> 7, pc = i & 127;
            int kr = (pr >> 4) + 8 * (pr & 15);
            int kc = (pc >> 4) + 8 * (pc & 15);
            float fr = (float)(kr < 64 ? kr : kr - 128) * FSTEP;
            float fc = (float)(kc < 64 ? kc : kc - 128) * FSTEP;
            float dx = fr - k0x, dy = fc - k0y;
            float g1 = expf(-0.5f * s2 * (dx * dx + dy * dy));
            float g0 = expf(-0.5f * s2 * (fr * fr + fc * fc));
            dst[i] = g1 - beta * g0;
        }
        return;
    }
    int b = blk;
    buildTw(tw, tid);
    const float* im = img + (size_t)b * NPIX;
    float acc = 0.f;
    #pragma unroll
    for (int k = 0; k < EPT; ++k) {
        int e = k * TT + tid;
        float v = im[e];
        acc += v;
        F[(e >> 7) * SS + (e & 127)] = make_float2(v, 0.f);
    }
    float ws = waveReduceSum(acc);
    if ((tid & 63) == 0) red[tid >> 6] = ws;
    __syncthreads();
    if (tid == 0) {
        float t = 0.f;
        #pragma unroll
        for (int w = 0; w < TT / 64; ++w) t += red[w];
        coeffs[b * 11 + 0] = t * (1.f / 16384.f);
    }
    fwdA<1, SS>(F, tw, tid);  __syncthreads();
    fwdB<1, SS>(F, tid);      __syncthreads();
    fwdA<SS, 1>(F, tw, tid);  __syncthreads();
    float2 uh[32];
    fwdB_col_capture(F, tid, uh);
    float2* dst = ihat + (size_t)b * NPIX;
    #pragma unroll
    for (int i = 0; i < 2; ++i) {
        int u = i * TT + tid;
        int ka = u >> 7, c = u & 127;
        #pragma unroll
        for (int kb = 0; kb < 16; ++kb)
            dst[(16 * ka + kb) * NN + c] = uh[i * 16 + kb];
    }
}

// ---------- K_scat_big: j1 = 0 ONLY (grid 256 = one round) ----------
__global__ __attribute__((amdgpu_flat_work_group_size(TT, TT), amdgpu_waves_per_eu(2, 2)))
void k_scat_big(const float2* __restrict__ ihat,
                const float* __restrict__ psi,
                float* __restrict__ coeffs) {
    // F: 16640 float2 = 133,120 B.
    //   128-grid phases use F[0..16512) with stride SS.
    //   j2=1 one-pass: G2a..G2d = F + {0,4160,8320,12480}  (4x 64x65 float2)
    //   trunc passes:  G4a = (float4*)F, G4b = (float4*)(F+8320)  (2x 64x65 float4)
    __shared__ __align__(16) float2 F[16640];
    __shared__ float2 tw[128];
    float4* G4a = (float4*)F;
    float4* G4b = (float4*)(F + 8320);
    float2* G2a = F;
    float2* G2b = F + 4160;
    float2* G2c = F + 8320;
    float2* G2d = F + 12480;
    int tid = threadIdx.x;
    int x = blockIdx.x;
    int b = x & 63, l1 = x >> 6;                       // j1 == 0
    const float2* ih = ihat + (size_t)b * NPIX;
    const float*  p1 = psi + (size_t)l1 * NPIX;
    buildTw(tw, tid);

    const float S1_128 = 9.3132257461547852e-10f;   // 2^-30
    const float S2TR   = 5.6843418860808015e-14f;   // 2^-44

    int kalo = tid >> 7, c = tid & 127;
    {
        #pragma unroll
        for (int i = 0; i < 2; ++i) {
            int ka = kalo + 4 * i;
            float2 g[16];
            #pragma unroll
            for (int kb = 0; kb < 16; ++kb) {
                int e = (16 * ka + kb) * NN + c;
                float2 z = ih[e];
                float  p = p1[e];
                g[kb] = make_float2(z.x * p, z.y * p);
            }
            fft16<1>(g);
            #pragma unroll
            for (int t = 0; t < 16; ++t)
                F[(16 * ka + t) * SS + c] = cmul(g[t], tw[t * ka]);
        }
    }
    __syncthreads();
    invB<SS, 1>(F, tid);      __syncthreads();
    invA<1, SS>(F, tw, tid);  __syncthreads();
    float acc = 0.f;
    invBmag_fwdA_row(F, tw, tid, acc);
    float ws1 = waveReduceSum(acc);
    if ((tid & 63) == 0) atomicAdd(&coeffs[b * 11 + 1], ws1 * S1_128);
    __syncthreads();
    fwdB<1, SS>(F, tid);      __syncthreads();
    fwdA<SS, 1>(F, tw, tid);  __syncthreads();
    float2 uh[32];
    fwdB_col_capture(F, tid, uh);
    __syncthreads();   // capture done -> F reusable (grids alias it)

    // trunc-staging column perm (central +-32 window), shared by j2 in {2,3}
    int m = c & 15;
    bool colKeep = (m < 4) || (m >= 12);
    int pc64 = 8 * (c >> 4) + ((m < 4) ? m : (m - 8));

    {
        // ===== (j1=0, j2=1): ONE pass, 4 off-center 64-windows (R14 mapping) =====
        // o per l2 (biased 3 bins to DC): l2=0:(21,0) 1:(15,15) 2:(0,21) 3:(-15,15)
        const int ORW[4] = {21, 15, 0, -15};
        const int OCW[4] = { 0, 15, 21,  15};
        int fc = (c >> 4) + 8 * (c & 15);
        bool ckw[4]; int pcw[4];
        #pragma unroll
        for (int w = 0; w < 4; ++w) {
            int dc = (fc - OCW[w]) & 127;
            ckw[w] = (dc < 32) || (dc >= 96);
            int uc = (dc < 32) ? dc : (dc - 64);
            pcw[w] = 8 * (uc & 7) + (uc >> 3);
        }
        #pragma unroll
        for (int i = 0; i < 2; ++i) {
            int ka = kalo + 4 * i;
            #pragma unroll
            for (int kb = 0; kb < 16; ++kb) {
                int fr = ka + 8 * kb;
                float2 z = uh[i * 16 + kb];
                int e = (16 * ka + kb) * NN + c;
                #pragma unroll
                for (int w = 0; w < 4; ++w) {
                    if (ckw[w]) {
                        int dr = (fr - ORW[w]) & 127;
                        if (dr < 32 || dr >= 96) {
                            int ur = (dr < 32) ? dr : (dr - 64);
                            int pr = 8 * (ur & 7) + (ur >> 3);
                            float pv = psi[(size_t)(4 + w) * NPIX + e];
                            float2* G = (w == 0) ? G2a : (w == 1) ? G2b
                                       : (w == 2) ? G2c : G2d;
                            G[pr * SG + pcw[w]] = make_float2(z.x * pv, z.y * pv);
                        }
                    }
                }
            }
        }
        __syncthreads();
        {   // col stepA (4 grids, full width)
            int col = tid & 63, k8 = tid >> 6;
            float2 f0[8], f1[8], f2[8], f3[8];
            #pragma unroll
            for (int kb = 0; kb < 8; ++kb) {
                int o = (8 * k8 + kb) * SG + col;
                f0[kb] = G2a[o]; f1[kb] = G2b[o]; f2[kb] = G2c[o]; f3[kb] = G2d[o];
            }
            fft8<1>(f0); fft8<1>(f1); fft8<1>(f2); fft8<1>(f3);
            #pragma unroll
            for (int q = 0; q < 8; ++q) {
                float2 w = tw[2 * q * k8];
                int o = (8 * k8 + q) * SG + col;
                G2a[o] = cmul(f0[q], w); G2b[o] = cmul(f1[q], w);
                G2c[o] = cmul(f2[q], w); G2d[o] = cmul(f3[q], w);
            }
        }
        __syncthreads();
        {   // col stepB
            int col = tid & 63, q = tid >> 6;
            float2 f0[8], f1[8], f2[8], f3[8];
            #pragma unroll
            for (int k8 = 0; k8 < 8; ++k8) {
                int o = (8 * k8 + q) * SG + col;
                f0[k8] = G2a[o]; f1[k8] = G2b[o]; f2[k8] = G2c[o]; f3[k8] = G2d[o];
            }
            fft8<1>(f0); fft8<1>(f1); fft8<1>(f2); fft8<1>(f3);
            #pragma unroll
            for (int n1 = 0; n1 < 8; ++n1) {
                int o = (8 * n1 + q) * SG + col;
                G2a[o] = f0[n1]; G2b[o] = f1[n1]; G2c[o] = f2[n1]; G2d[o] = f3[n1];
            }
        }
        __syncthreads();
        {   // row stepA
            int row = tid & 63, k8 = tid >> 6;
            int base = row * SG + 8 * k8;
            float2 f0[8], f1[8], f2[8], f3[8];
            #pragma unroll
            for (int kb = 0; kb < 8; ++kb) {
                f0[kb] = G2a[base + kb]; f1[kb] = G2b[base + kb];
                f2[kb] = G2c[base + kb]; f3[kb] = G2d[base + kb];
            }
            fft8<1>(f0); fft8<1>(f1); fft8<1>(f2); fft8<1>(f3);
            #pragma unroll
            for (int q = 0; q < 8; ++q) {
                float2 w = tw[2 * q * k8];
                G2a[base + q] = cmul(f0[q], w); G2b[base + q] = cmul(f1[q], w);
                G2c[base + q] = cmul(f2[q], w); G2d[base + q] = cmul(f3[q], w);
            }
        }
        __syncthreads();
        float a2 = 0.f;
        {   // row stepB + mag (all 4 -> same coeff)
            int row = tid & 63, q = tid >> 6;
            int base = row * SG + q;
            float2 f0[8], f1[8], f2[8], f3[8];
            #pragma unroll
            for (int k8 = 0; k8 < 8; ++k8) {
                int o = base + 8 * k8;
                f0[k8] = G2a[o]; f1[k8] = G2b[o]; f2[k8] = G2c[o]; f3[k8] = G2d[o];
            }
            fft8<1>(f0); fft8<1>(f1); fft8<1>(f2); fft8<1>(f3);
            #pragma unroll
            for (int n1 = 0; n1 < 8; ++n1) {
                a2 += sqrtf(f0[n1].x * f0[n1].x + f0[n1].y * f0[n1].y);
                a2 += sqrtf(f1[n1].x * f1[n1].x + f1[n1].y * f1[n1].y);
                a2 += sqrtf(f2[n1].x * f2[n1].x + f2[n1].y * f2[n1].y);
                a2 += sqrtf(f3[n1].x * f3[n1].x + f3[n1].y * f3[n1].y);
            }
        }
        float ws2 = waveReduceSum(a2);
        if ((tid & 63) == 0) atomicAdd(&coeffs[b * 11 + 5 + 0], ws2 * S2TR);
        __syncthreads();
    }

    // ===== truncated second order j2 in {2,3}: ONE pass per j2, 4 filters =====
    for (int j2 = 2; j2 <= 3; ++j2) {
        int pair = j2 - 1;                       // (0,2)->1  (0,3)->2
        const float* p0 = psi + (size_t)(j2 * 4 + 0) * NPIX;
        const float* pq1 = p0 + NPIX;
        const float* pq2 = pq1 + NPIX;
        const float* pq3 = pq2 + NPIX;
        if (colKeep) {
            #pragma unroll
            for (int i = 0; i < 2; ++i) {
                int ka = kalo + 4 * i;
                #pragma unroll
                for (int kb = 0; kb < 16; ++kb) {
                    if (kb < 4 || kb >= 12) {
                        int pr64 = 8 * ka + ((kb < 4) ? kb : (kb - 8));
                        float2 z = uh[i * 16 + kb];
                        int e = (16 * ka + kb) * NN + c;
                        float a0 = p0[e], a1 = pq1[e], a2f = pq2[e], a3 = pq3[e];
                        G4a[pr64 * SG + pc64] =
                            make_float4(z.x * a0, z.y * a0, z.x * a1, z.y * a1);
                        G4b[pr64 * SG + pc64] =
                            make_float4(z.x * a2f, z.y * a2f, z.x * a3, z.y * a3);
                    }
                }
            }
        }
        __syncthreads();
        {   // col stepA (two packed grids = 4 filters, full width)
            int col = tid & 63, k8 = tid >> 6;
            float2 f0[8], f1[8], f2[8], f3[8];
            #pragma unroll
            for (int kb = 0; kb < 8; ++kb) {
                int o = (8 * k8 + kb) * SG + col;
                float4 v = G4a[o];
                f0[kb] = make_float2(v.x, v.y); f1[kb] = make_float2(v.z, v.w);
                float4 u = G4b[o];
                f2[kb] = make_float2(u.x, u.y); f3[kb] = make_float2(u.z, u.w);
            }
            fft8<1>(f0); fft8<1>(f1); fft8<1>(f2); fft8<1>(f3);
            #pragma unroll
            for (int q = 0; q < 8; ++q) {
                float2 w = tw[2 * q * k8];
                int o = (8 * k8 + q) * SG + col;
                float2 a = cmul(f0[q], w), d = cmul(f1[q], w);
                G4a[o] = make_float4(a.x, a.y, d.x, d.y);
                float2 a2c = cmul(f2[q], w), d2 = cmul(f3[q], w);
                G4b[o] = make_float4(a2c.x, a2c.y, d2.x, d2.y);
            }
        }
        __syncthreads();
        {   // col stepB
            int col = tid & 63, q = tid >> 6;
            float2 f0[8], f1[8], f2[8], f3[8];
            #pragma unroll
            for (int k8 = 0; k8 < 8; ++k8) {
                int o = (8 * k8 + q) * SG + col;
                float4 v = G4a[o];
                f0[k8] = make_float2(v.x, v.y); f1[k8] = make_float2(v.z, v.w);
                float4 u = G4b[o];
                f2[k8] = make_float2(u.x, u.y); f3[k8] = make_float2(u.z, u.w);
            }
            fft8<1>(f0); fft8<1>(f1); fft8<1>(f2); fft8<1>(f3);
            #pragma unroll
            for (int n1 = 0; n1 < 8; ++n1) {
                int o = (8 * n1 + q) * SG + col;
                G4a[o] = make_float4(f0[n1].x, f0[n1].y, f1[n1].x, f1[n1].y);
                G4b[o] = make_float4(f2[n1].x, f2[n1].y, f3[n1].x, f3[n1].y);
            }
        }
        __syncthreads();
        {   // row stepA
            int row = tid & 63, k8 = tid >> 6;
            int base = row * SG + 8 * k8;
            float2 f0[8], f1[8], f2[8], f3[8];
            #pragma unroll
            for (int kb = 0; kb < 8; ++kb) {
                float4 v = G4a[base + kb];
                f0[kb] = make_float2(v.x, v.y); f1[kb] = make_float2(v.z, v.w);
                float4 u = G4b[base + kb];
                f2[kb] = make_float2(u.x, u.y); f3[kb] = make_float2(u.z, u.w);
            }
            fft8<1>(f0); fft8<1>(f1); fft8<1>(f2); fft8<1>(f3);
            #pragma unroll
            for (int q = 0; q < 8; ++q) {
                float2 w = tw[2 * q * k8];
                float2 a = cmul(f0[q], w), d = cmul(f1[q], w);
                G4a[base + q] = make_float4(a.x, a.y, d.x, d.y);
                float2 a2c = cmul(f2[q], w), d2 = cmul(f3[q], w);
                G4b[base + q] = make_float4(a2c.x, a2c.y, d2.x, d2.y);
            }
        }
        __syncthreads();
        float a2 = 0.f;
        {   // row stepB + mag
            int row = tid & 63, q = tid >> 6;
            int base = row * SG + q;
            float2 f0[8], f1[8], f2[8], f3[8];
            #pragma unroll
            for (int k8 = 0; k8 < 8; ++k8) {
                float4 v = G4a[base + 8 * k8];
                f0[k8] = make_float2(v.x, v.y); f1[k8] = make_float2(v.z, v.w);
                float4 u = G4b[base + 8 * k8];
                f2[k8] = make_float2(u.x, u.y); f3[k8] = make_float2(u.z, u.w);
            }
            fft8<1>(f0); fft8<1>(f1); fft8<1>(f2); fft8<1>(f3);
            #pragma unroll
            for (int n1 = 0; n1 < 8; ++n1) {
                a2 += sqrtf(f0[n1].x * f0[n1].x + f0[n1].y * f0[n1].y);
                a2 += sqrtf(f1[n1].x * f1[n1].x + f1[n1].y * f1[n1].y);
                a2 += sqrtf(f2[n1].x * f2[n1].x + f2[n1].y * f2[n1].y);
                a2 += sqrtf(f3[n1].x * f3[n1].x + f3[n1].y * f3[n1].y);
            }
        }
        float ws2 = waveReduceSum(a2);
        if ((tid & 63) == 0) atomicAdd(&coeffs[b * 11 + 5 + pair], ws2 * S2TR);
        __syncthreads();
    }
}

// ---------- K_scat_small: j1 in {1,2,3} -- 67.6 KB LDS => 2 blocks/CU ----------
__global__ __attribute__((amdgpu_flat_work_group_size(TT, TT), amdgpu_waves_per_eu(4, 4)))
void k_scat_small(const float2* __restrict__ ihat,
                  const float* __restrict__ psi,
                  float* __restrict__ coeffs) {
    // S: 8320 float2 = 66,560 B.
    //   G2 (64x65 float2) = S[0..4160); H32 = S[4160..5184) (j1=2 path only);
    //   G4 (64x65 float4) aliases S[0..8320) (j1=1 second-order passes);
    //   G32/G32p (32-grid) alias S[0..).
    __shared__ __align__(16) float2 S[8320];
    __shared__ float2 tw[128];
    float2* G2  = S;
    float2* G32 = S;
    float4* G32p = (float4*)S;
    float4* G4  = (float4*)S;
    float2* H32 = S + 4160;
    int tid = threadIdx.x;
    int x = blockIdx.x;
    int b = x & 63, l1 = (x >> 6) & 3;
    int t0 = x >> 8;                          // 0 -> j1=1 (heavy, first), 1 -> j1=2, 2 -> j1=3
    int j1 = (t0 == 0) ? 1 : (t0 + 1);
    const float2* ih = ihat + (size_t)b * NPIX;
    const float*  p1 = psi + (size_t)(j1 * 4 + l1) * NPIX;
    buildTw(tw, tid);

    const float S1_64 = 3.7252902984619141e-9f;    // 2^-28
    const float S1_32 = 1.4901161193847656e-8f;    // 2^-26
    const float S2_32 = 9.0949470177292824e-13f;   // 2^-40
    const float S2_V  = 2.2737367544323206e-13f;   // 2^-42 = 4*S2TR (V = uh/4)

    int kalo = tid >> 7, c = tid & 127;

    if (t0 == 0) {
        // =========== j1 = 1 on off-center 64-window (R16) ===========
        // centers o = filter peak (bin 24 along theta) biased 3 bins to DC
        const int OR1[4] = {21, 15, 0, -15};
        const int OC1[4] = { 0, 15, 21,  15};
        int fc = (c >> 4) + 8 * (c & 15);
        int dc = (fc - OC1[l1]) & 127;
        bool ck = (dc < 32) || (dc >= 96);
        int ucw = (dc < 32) ? dc : (dc - 64);
        int pcd = 8 * (ucw & 7) + (ucw >> 3);
        if (ck) {
            #pragma unroll
            for (int i = 0; i < 2; ++i) {
                int ka = kalo + 4 * i;
                #pragma unroll
                for (int kb = 0; kb < 16; ++kb) {
                    int fr = ka + 8 * kb;
                    int dr = (fr - OR1[l1]) & 127;
                    if (dr < 32 || dr >= 96) {
                        int ur = (dr < 32) ? dr : (dr - 64);
                        int pr = 8 * (ur & 7) + (ur >> 3);
                        int e = (16 * ka + kb) * NN + c;
                        float2 z = ih[e];
                        float  p = p1[e];
                        G2[pr * SG + pcd] = make_float2(z.x * p, z.y * p);
                    }
                }
            }
        }
        __syncthreads();
        {   // col stepA (inverse)
            int col = tid & 63, k8 = tid >> 6;
            float2 f[8];
            #pragma unroll
            for (int kb = 0; kb < 8; ++kb) f[kb] = G2[(8 * k8 + kb) * SG + col];
            fft8<1>(f);
            #pragma unroll
            for (int q = 0; q < 8; ++q)
                G2[(8 * k8 + q) * SG + col] = cmul(f[q], tw[2 * q * k8]);
        }
        __syncthreads();
        {   // col stepB
            int col = tid & 63, q = tid >> 6;
            float2 f[8];
            #pragma unroll
            for (int k8 = 0; k8 < 8; ++k8) f[k8] = G2[(8 * k8 + q) * SG + col];
            fft8<1>(f);
            #pragma unroll
            for (int n1 = 0; n1 < 8; ++n1) G2[(8 * n1 + q) * SG + col] = f[n1];
        }
        __syncthreads();
        {   // row stepA (inverse)
            int row = tid & 63, k8 = tid >> 6;
            float2* R = G2 + row * SG + 8 * k8;
            float2 f[8];
            #pragma unroll
            for (int kb = 0; kb < 8; ++kb) f[kb] = R[kb];
            fft8<1>(f);
            #pragma unroll
            for (int q = 0; q < 8; ++q) R[q] = cmul(f[q], tw[2 * q * k8]);
        }
        __syncthreads();
        float acc = 0.f;
        {   // FUSED64: row stepB inv -> |.| -> row stepA fwd
            int row = tid & 63, q = tid >> 6;
            float2* R = G2 + row * SG + q;
            float2 f[8];
            #pragma unroll
            for (int k8 = 0; k8 < 8; ++k8) f[k8] = R[8 * k8];
            fft8<1>(f);
            #pragma unroll
            for (int n1 = 0; n1 < 8; ++n1) {
                float mg = sqrtf(f[n1].x * f[n1].x + f[n1].y * f[n1].y);
                acc += mg;
                f[n1] = make_float2(mg, 0.f);
            }
            fft8<-1>(f);
            #pragma unroll
            for (int ka = 0; ka < 8; ++ka)
                R[8 * ka] = cmulc(f[ka], tw[2 * q * ka]);
        }
        float ws1 = waveReduceSum(acc);
        if ((tid & 63) == 0) atomicAdd(&coeffs[b * 11 + 2], ws1 * S1_64);
        __syncthreads();
        {   // row stepB (forward)
            int row2 = tid & 63, ka = tid >> 6;
            float2* R2 = G2 + row2 * SG + 8 * ka;
            float2 g[8];
            #pragma unroll
            for (int t = 0; t < 8; ++t) g[t] = R2[t];
            fft8<-1>(g);
            #pragma unroll
            for (int kb = 0; kb < 8; ++kb) R2[kb] = g[kb];
        }
        __syncthreads();
        {   // col stepA (forward)
            int col = tid & 63, t = tid >> 6;
            float2 g[8];
            #pragma unroll
            for (int n1 = 0; n1 < 8; ++n1) g[n1] = G2[(t + 8 * n1) * SG + col];
            fft8<-1>(g);
            #pragma unroll
            for (int ka = 0; ka < 8; ++ka)
                G2[(t + 8 * ka) * SG + col] = cmulc(g[ka], tw[2 * t * ka]);
        }
        __syncthreads();
        float2 vh[8];
        int c6 = tid & 63, ka8 = tid >> 6;
        {   // col stepB (forward) -> V = u1hat_64 captured to registers
            float2 g[8];
            #pragma unroll
            for (int t = 0; t < 8; ++t) g[t] = G2[(8 * ka8 + t) * SG + c6];
            fft8<-1>(g);
            #pragma unroll
            for (int kb = 0; kb < 8; ++kb) vh[kb] = g[kb];
        }
        __syncthreads();   // G2 reads done -> G4 (alias) safe to write

        // psi gather indices: 64-grid storage p <-> freq u = 8*(p&7)+(p>>3);
        // 128-freq f128 = u<32 ? u : u+64; storage s = 16*(f128&7)+(f128>>3)
        int uc64 = 8 * (c6 & 7) + (c6 >> 3);
        int fc128 = (uc64 < 32) ? uc64 : (uc64 + 64);
        int scI = 16 * (fc128 & 7) + (fc128 >> 3);
        int se[8];
        #pragma unroll
        for (int kb = 0; kb < 8; ++kb) {
            int ur = 8 * kb + ka8;
            int fr128 = (ur < 32) ? ur : (ur + 64);
            se[kb] = (16 * (fr128 & 7) + (fr128 >> 3)) * NN + scI;
        }

        for (int j2 = 2; j2 <= 3; ++j2) {
            int pair = j2 + 1;                  // (1,2)->3  (1,3)->4
            for (int half = 0; half < 2; ++half) {
                const float* p2a = psi + (size_t)(j2 * 4 + 2 * half) * NPIX;
                const float* p2b = p2a + NPIX;
                #pragma unroll
                for (int kb = 0; kb < 8; ++kb) {
                    float pa = p2a[se[kb]], pb = p2b[se[kb]];
                    G4[(8 * ka8 + kb) * SG + c6] =
                        make_float4(vh[kb].x * pa, vh[kb].y * pa,
                                    vh[kb].x * pb, vh[kb].y * pb);
                }
                __syncthreads();
                {   // col stepA
                    int col = tid & 63, k8 = tid >> 6;
                    float2 f0[8], f1[8];
                    #pragma unroll
                    for (int kb = 0; kb < 8; ++kb) {
                        float4 v = G4[(8 * k8 + kb) * SG + col];
                        f0[kb] = make_float2(v.x, v.y); f1[kb] = make_float2(v.z, v.w);
                    }
                    fft8<1>(f0); fft8<1>(f1);
                    #pragma unroll
                    for (int q = 0; q < 8; ++q) {
                        float2 w = tw[2 * q * k8];
                        float2 a = cmul(f0[q], w), d = cmul(f1[q], w);
                        G4[(8 * k8 + q) * SG + col] = make_float4(a.x, a.y, d.x, d.y);
                    }
                }
                __syncthreads();
                {   // col stepB
                    int col = tid & 63, q = tid >> 6;
                    float2 f0[8], f1[8];
                    #pragma unroll
                    for (int k8 = 0; k8 < 8; ++k8) {
                        float4 v = G4[(8 * k8 + q) * SG + col];
                        f0[k8] = make_float2(v.x, v.y); f1[k8] = make_float2(v.z, v.w);
                    }
                    fft8<1>(f0); fft8<1>(f1);
                    #pragma unroll
                    for (int n1 = 0; n1 < 8; ++n1)
                        G4[(8 * n1 + q) * SG + col] =
                            make_float4(f0[n1].x, f0[n1].y, f1[n1].x, f1[n1].y);
                }
                __syncthreads();
                {   // row stepA
                    int row = tid & 63, k8 = tid >> 6;
                    float4* R = G4 + row * SG + 8 * k8;
                    float2 f0[8], f1[8];
                    #pragma unroll
                    for (int kb = 0; kb < 8; ++kb) {
                        float4 v = R[kb];
                        f0[kb] = make_float2(v.x, v.y); f1[kb] = make_float2(v.z, v.w);
                    }
                    fft8<1>(f0); fft8<1>(f1);
                    #pragma unroll
                    for (int q = 0; q < 8; ++q) {
                        float2 w = tw[2 * q * k8];
                        float2 a = cmul(f0[q], w), d = cmul(f1[q], w);
                        R[q] = make_float4(a.x, a.y, d.x, d.y);
                    }
                }
                __syncthreads();
                float a2 = 0.f;
                {   // row stepB + mag
                    int row = tid & 63, q = tid >> 6;
                    float4* R = G4 + row * SG + q;
                    float2 f0[8], f1[8];
                    #pragma unroll
                    for (int k8 = 0; k8 < 8; ++k8) {
                        float4 v = R[8 * k8];
                        f0[k8] = make_float2(v.x, v.y); f1[k8] = make_float2(v.z, v.w);
                    }
                    fft8<1>(f0); fft8<1>(f1);
                    #pragma unroll
                    for (int n1 = 0; n1 < 8; ++n1) {
                        a2 += sqrtf(f0[n1].x * f0[n1].x + f0[n1].y * f0[n1].y);
                        a2 += sqrtf(f1[n1].x * f1[n1].x + f1[n1].y * f1[n1].y);
                    }
                }
                float ws2 = waveReduceSum(a2);
                if ((tid & 63) == 0) atomicAdd(&coeffs[b * 11 + 5 + pair], ws2 * S2_V);
                __syncthreads();
            }
        }
        return;
    }

    if (t0 == 2) {
        // ===== j1=3: 32-grid first order (psi_{j1=3} support +-16) =====
        int m = c & 15;
        bool ck32 = (m < 2) || (m >= 14);
        int pc32 = 4 * (c >> 4) + ((m < 2) ? m : (m - 12));
        if (ck32) {
            #pragma unroll
            for (int i = 0; i < 2; ++i) {
                int ka = kalo + 4 * i;
                #pragma unroll
                for (int kb = 0; kb < 16; ++kb) {
                    if (kb < 2 || kb >= 14) {
                        int e = (16 * ka + kb) * NN + c;
                        float2 z = ih[e];
                        float  p = p1[e];
                        int pr32 = 4 * ka + ((kb < 2) ? kb : (kb - 12));
                        G32[pr32 * SG32 + pc32] = make_float2(z.x * p, z.y * p);
                    }
                }
            }
        }
        __syncthreads();
        if (tid < 256) {   // col stepA: fft4 over b per a (32 lines x 8 a)
            int line = tid & 31, a = tid >> 5;
            float2 f[4];
            #pragma unroll
            for (int kb = 0; kb < 4; ++kb) f[kb] = G32[(4 * a + kb) * SG32 + line];
            fft4<1>(f);
            #pragma unroll
            for (int t = 0; t < 4; ++t)
                G32[(4 * a + t) * SG32 + line] = cmul(f[t], tw[4 * t * a]);
        }
        __syncthreads();
        if (tid < 128) {   // col stepB: fft8 over a per t (32 lines x 4 t)
            int line = tid & 31, t = tid >> 5;
            float2 f[8];
            #pragma unroll
            for (int a = 0; a < 8; ++a) f[a] = G32[(4 * a + t) * SG32 + line];
            fft8<1>(f);
            #pragma unroll
            for (int n1 = 0; n1 < 8; ++n1) G32[(4 * n1 + t) * SG32 + line] = f[n1];
        }
        __syncthreads();
        if (tid < 256) {   // row stepA
            int row = tid & 31, a = tid >> 5;
            float2* R = G32 + row * SG32 + 4 * a;
            float2 f[4];
            #pragma unroll
            for (int kb = 0; kb < 4; ++kb) f[kb] = R[kb];
            fft4<1>(f);
            #pragma unroll
            for (int t = 0; t < 4; ++t) R[t] = cmul(f[t], tw[4 * t * a]);
        }
        __syncthreads();
        float acc = 0.f;
        if (tid < 128) {   // row stepB + mag
            int row = tid & 31, t = tid >> 5;
            float2* R = G32 + row * SG32 + t;
            float2 f[8];
            #pragma unroll
            for (int a = 0; a < 8; ++a) f[a] = R[4 * a];
            fft8<1>(f);
            #pragma unroll
            for (int n1 = 0; n1 < 8; ++n1)
                acc += sqrtf(f[n1].x * f[n1].x + f[n1].y * f[n1].y);
        }
        float ws1 = waveReduceSum(acc);
        if ((tid & 63) == 0 && tid < 128) atomicAdd(&coeffs[b * 11 + 4], ws1 * S1_32);
        return;
    }

    // ===================== j1 == 2: 64-grid first order (R13-proven) ==============
    int m = c & 15;
    bool colKeep = (m < 4) || (m >= 12);
    if (colKeep) {
        #pragma unroll
        for (int i = 0; i < 2; ++i) {
            int ka = kalo + 4 * i;
            #pragma unroll
            for (int kb = 0; kb < 16; ++kb) {
                if (kb < 4 || kb >= 12) {
                    int e = (16 * ka + kb) * NN + c;
                    float2 z = ih[e];
                    float  p = p1[e];
                    int pr64 = 8 * ka + ((kb < 4) ? kb : (kb - 8));
                    int pc64 = 8 * (c >> 4) + ((m < 4) ? m : (m - 8));
                    G2[pr64 * SG + pc64] = make_float2(z.x * p, z.y * p);
                }
            }
        }
    }
    __syncthreads();
    {   // col stepA (inverse)
        int col = tid & 63, k8 = tid >> 6;
        float2 f[8];
        #pragma unroll
        for (int kb = 0; kb < 8; ++kb) f[kb] = G2[(8 * k8 + kb) * SG + col];
        fft8<1>(f);
        #pragma unroll
        for (int q = 0; q < 8; ++q)
            G2[(8 * k8 + q) * SG + col] = cmul(f[q], tw[2 * q * k8]);
    }
    __syncthreads();
    {   // col stepB
        int col = tid & 63, q = tid >> 6;
        float2 f[8];
        #pragma unroll
        for (int k8 = 0; k8 < 8; ++k8) f[k8] = G2[(8 * k8 + q) * SG + col];
        fft8<1>(f);
        #pragma unroll
        for (int n1 = 0; n1 < 8; ++n1) G2[(8 * n1 + q) * SG + col] = f[n1];
    }
    __syncthreads();
    {   // row stepA (inverse)
        int row = tid & 63, k8 = tid >> 6;
        float2* R = G2 + row * SG + 8 * k8;
        float2 f[8];
        #pragma unroll
        for (int kb = 0; kb < 8; ++kb) f[kb] = R[kb];
        fft8<1>(f);
        #pragma unroll
        for (int q = 0; q < 8; ++q) R[q] = cmul(f[q], tw[2 * q * k8]);
    }
    __syncthreads();
    float acc = 0.f;
    {   // FUSED64: row stepB inv -> |.| (raw) -> row stepA fwd (same cells)
        int row = tid & 63, q = tid >> 6;
        float2* R = G2 + row * SG + q;
        float2 f[8];
        #pragma unroll
        for (int k8 = 0; k8 < 8; ++k8) f[k8] = R[8 * k8];
        fft8<1>(f);
        #pragma unroll
        for (int n1 = 0; n1 < 8; ++n1) {
            float mg = sqrtf(f[n1].x * f[n1].x + f[n1].y * f[n1].y);
            acc += mg;
            f[n1] = make_float2(mg, 0.f);
        }
        fft8<-1>(f);
        #pragma unroll
        for (int ka = 0; ka < 8; ++ka)
            R[8 * ka] = cmulc(f[ka], tw[2 * q * ka]);
    }
    float ws1 = waveReduceSum(acc);
    if ((tid & 63) == 0) atomicAdd(&coeffs[b * 11 + 3], ws1 * S1_64);
    __syncthreads();
    {   // row stepB (forward)
        int row2 = tid & 63, ka = tid >> 6;
        float2* R2 = G2 + row2 * SG + 8 * ka;
        float2 g[8];
        #pragma unroll
        for (int t = 0; t < 8; ++t) g[t] = R2[t];
        fft8<-1>(g);
        #pragma unroll
        for (int kb = 0; kb < 8; ++kb) R2[kb] = g[kb];
    }
    __syncthreads();
    {   // col stepA (forward)
        int col = tid & 63, t = tid >> 6;
        float2 g[8];
        #pragma unroll
        for (int n1 = 0; n1 < 8; ++n1) g[n1] = G2[(t + 8 * n1) * SG + col];
        fft8<-1>(g);
        #pragma unroll
        for (int ka = 0; ka < 8; ++ka)
            G2[(t + 8 * ka) * SG + col] = cmulc(g[ka], tw[2 * t * ka]);
    }
    __syncthreads();
    {   // col stepB (forward) -> H32: central +-16 of V only (perm32 layout)
        int col = tid & 63, ka = tid >> 6;
        float2 g[8];
        #pragma unroll
        for (int t = 0; t < 8; ++t) g[t] = G2[(8 * ka + t) * SG + col];
        fft8<-1>(g);
        int br = col & 7, ar = col >> 3;
        if (br < 2 || br >= 6) {
            int p32row = 4 * ar + (br & 3);
            #pragma unroll
            for (int kb = 0; kb < 8; ++kb) {
                if (kb < 2 || kb >= 6)
                    H32[(4 * ka + (kb & 3)) * 32 + p32row] = g[kb];
            }
        }
    }
    __syncthreads();

    // ===== truncated second order j2 = 3 on the 32-grid, 2 filters packed =====
    bool ck32 = (m < 2) || (m >= 14);
    int pc32 = 4 * (c >> 4) + ((m < 2) ? m : (m - 12));
    for (int half = 0; half < 2; ++half) {
        const float* p2a = psi + (size_t)(12 + 2 * half) * NPIX;
        const float* p2b = p2a + NPIX;
        if (ck32) {
            #pragma unroll
            for (int i = 0; i < 2; ++i) {
                int ka = kalo + 4 * i;
                #pragma unroll
                for (int kb = 0; kb < 16; ++kb) {
                    if (kb < 2 || kb >= 14) {
                        int pr32 = 4 * ka + ((kb < 2) ? kb : (kb - 12));
                        float2 z = H32[pr32 * 32 + pc32];
                        int e = (16 * ka + kb) * NN + c;
                        float pa = p2a[e], pb = p2b[e];
                        G32p[pr32 * SG32 + pc32] =
                            make_float4(z.x * pa, z.y * pa, z.x * pb, z.y * pb);
                    }
                }
            }
        }
        __syncthreads();
        if (tid < 256) {   // col stepA (packed)
            int line = tid & 31, a = tid >> 5;
            float2 f0[4], f1[4];
            #pragma unroll
            for (int kb = 0; kb < 4; ++kb) {
                float4 v = G32p[(4 * a + kb) * SG32 + line];
                f0[kb] = make_float2(v.x, v.y); f1[kb] = make_float2(v.z, v.w);
            }
            fft4<1>(f0); fft4<1>(f1);
            #pragma unroll
            for (int t = 0; t < 4; ++t) {
                float2 w = tw[4 * t * a];
                float2 aa = cmul(f0[t], w), d = cmul(f1[t], w);
                G32p[(4 * a + t) * SG32 + line] = make_float4(aa.x, aa.y, d.x, d.y);
            }
        }
        __syncthreads();
        if (tid < 128) {   // col stepB (packed)
            int line = tid & 31, t = tid >> 5;
            float2 f0[8], f1[8];
            #pragma unroll
            for (int a = 0; a < 8; ++a) {
                float4 v = G32p[(4 * a + t) * SG32 + line];
                f0[a] = make_float2(v.x, v.y); f1[a] = make_float2(v.z, v.w);
            }
            fft8<1>(f0); fft8<1>(f1);
            #pragma unroll
            for (int n1 = 0; n1 < 8; ++n1)
                G32p[(4 * n1 + t) * SG32 + line] =
                    make_float4(f0[n1].x, f0[n1].y, f1[n1].x, f1[n1].y);
        }
        __syncthreads();
        if (tid < 256) {   // row stepA (packed)
            int row = tid & 31, a = tid >> 5;
            float4* R = G32p + row * SG32 + 4 * a;
            float2 f0[4], f1[4];
            #pragma unroll
            for (int kb = 0; kb < 4; ++kb) {
                float4 v = R[kb];
                f0[kb] = make_float2(v.x, v.y); f1[kb] = make_float2(v.z, v.w);
            }
            fft4<1>(f0); fft4<1>(f1);
            #pragma unroll
            for (int t = 0; t < 4; ++t) {
                float2 w = tw[4 * t * a];
                float2 aa = cmul(f0[t], w), d = cmul(f1[t], w);
                R[t] = make_float4(aa.x, aa.y, d.x, d.y);
            }
        }
        __syncthreads();
        float a2 = 0.f;
        if (tid < 128) {   // row stepB + mag (packed)
            int row = tid & 31, t = tid >> 5;
            float4* R = G32p + row * SG32 + t;
            float2 f0[8], f1[8];
            #pragma unroll
            for (int a = 0; a < 8; ++a) {
                float4 v = R[4 * a];
                f0[a] = make_float2(v.x, v.y); f1[a] = make_float2(v.z, v.w);
            }
            fft8<1>(f0); fft8<1>(f1);
            #pragma unroll
            for (int n1 = 0; n1 < 8; ++n1) {
                a2 += sqrtf(f0[n1].x * f0[n1].x + f0[n1].y * f0[n1].y);
                a2 += sqrtf(f1[n1].x * f1[n1].x + f1[n1].y * f1[n1].y);
            }
        }
        float ws2 = waveReduceSum(a2);
        if ((tid & 63) == 0 && tid < 128)
            atomicAdd(&coeffs[b * 11 + 5 + 5], ws2 * S2_32);
        __syncthreads();
    }
}

// ---------- K_mlp: tiny MLP head (separate launch -- R12 lesson) ----------
__global__ void k_mlp(const float* __restrict__ coeffs,
                      const float* __restrict__ w1, const float* __restrict__ b1,
                      const float* __restrict__ w2, const float* __restrict__ b2,
                      float* __restrict__ out) {
    int b = threadIdx.x;
    if (b >= 64) return;
    float c[11];
    #pragma unroll
    for (int i = 0; i < 11; ++i) c[i] = coeffs[b * 11 + i];
    float h[4];
    #pragma unroll
    for (int k = 0; k < 4; ++k) {
        float s = b1[k];
        #pragma unroll
        for (int i = 0; i < 11; ++i) s += w1[k * 11 + i] * c[i];
        h[k] = fmaxf(s, 0.f);
    }
    #pragma unroll
    for (int o = 0; o < 10; ++o) {
        float s = b2[o];
        #pragma unroll
        for (int k = 0; k < 4; ++k) s += w2[o * 4 + k] * h[k];
        out[b * 10 + o] = 1.f / (1.f + expf(-s));
    }
}

extern "C" void kernel_launch(void* const* d_in, const int* in_sizes, int n_in,
                              void* d_out, int out_size, void* d_ws, size_t ws_size,
                              hipStream_t stream) {
    const float* img = (const float*)d_in[0];
    const float* w1  = (const float*)d_in[1];
    const float* b1  = (const float*)d_in[2];
    const float* w2  = (const float*)d_in[3];
    const float* b2  = (const float*)d_in[4];
    float* out = (float*)d_out;

    float*  ws     = (float*)d_ws;
    float*  psi    = ws;
    float2* ihat   = (float2*)(ws + 16 * NPIX);
    float*  coeffs = ws + 16 * NPIX + 2 * 64 * NPIX;

    hipLaunchKernelGGL(k_pre,        dim3(81),  dim3(TT), 0, stream, img, psi, ihat, coeffs);
    hipLaunchKernelGGL(k_scat_big,   dim3(256), dim3(TT), 0, stream, ihat, psi, coeffs);
    hipLaunchKernelGGL(k_scat_small, dim3(768), dim3(TT), 0, stream, ihat, psi, coeffs);
    hipLaunchKernelGGL(k_mlp,        dim3(1),   dim3(64), 0, stream, coeffs, w1, b1, w2, b2, out);
}

// Round 4
// 184.508 us; speedup vs baseline: 1.3213x; 1.0757x over previous
//
#include <hip/hip_runtime.h>
#include <math.h>

#define NN   128
#define SS   129          // LDS row stride in float2 (ODD -> conflict-free lane stride)
#define TT   512          // PROVEN: TT=512 allocates ~112-128 VGPR no-spill (R4/R6-R13);
                          // TT=1024 ALWAYS gets 64 VGPR + spill (R2/R3/R10). Never 1024.
#define NPIX 16384        // 128*128
#define EPT  32           // NPIX / TT
#define SG   65           // 64-grid row stride (float2 or float4 units)
#define SG32 33           // 32-grid row stride

// R12 lesson: NO __threadfence() tail / in-kernel MLP fold (cost ~115 us).
// R14: (j1=0,j2=1) on OFF-CENTER 64x64 frequency windows. Proven absmax 0.0.
// R15: H eliminated (register round-trip); full-width packed passes.
// R16: j1=1 retired from the 128-grid (off-center 64-window first order;
//      V = uh/4 on central window; S2_V = 2^-42). Proven absmax 0.0.
// R17 (this round): ALL j2=3 pairs on the 32-grid (psi_{j2=3} fits +-16 at
//      >=3.1 sigma, same margin as proven (2,3) truncation):
//      (0,3): 64-grid pass -> 32-grid 4-filter pass, scale 2^-42 (=4*S2TR)
//      (1,3): two G4 passes -> one 32-grid 4-filter pass, scale 2^-40 (=4*S2_V,
//             == proven S2_32 -- scale-chain cross-check)
//      (2,3): two quarter-width passes -> one 4-filter pass (H32 -> S+6144)
//      Shared primitive pass32x4 = proven packed-32 phases, grid-select by tid.

__device__ __forceinline__ float2 cmul(float2 a, float2 w) {
    return make_float2(a.x * w.x - a.y * w.y, a.x * w.y + a.y * w.x);
}
__device__ __forceinline__ float2 cmulc(float2 a, float2 w) {   // a * conj(w)
    return make_float2(a.x * w.x + a.y * w.y, a.y * w.x - a.x * w.y);
}

// ---------- register FFT codelets (fft4/fft8/fft16 verified R2-R16) ----------
template<int SGN>
__device__ __forceinline__ void fft4(float2* f) {
    float2 t0 = make_float2(f[0].x + f[2].x, f[0].y + f[2].y);
    float2 t1 = make_float2(f[0].x - f[2].x, f[0].y - f[2].y);
    float2 t2 = make_float2(f[1].x + f[3].x, f[1].y + f[3].y);
    float2 t3 = make_float2(f[1].x - f[3].x, f[1].y - f[3].y);
    float2 t3i = (SGN > 0) ? make_float2(-t3.y, t3.x) : make_float2(t3.y, -t3.x);
    f[0] = make_float2(t0.x + t2.x, t0.y + t2.y);
    f[1] = make_float2(t1.x + t3i.x, t1.y + t3i.y);
    f[2] = make_float2(t0.x - t2.x, t0.y - t2.y);
    f[3] = make_float2(t1.x - t3i.x, t1.y - t3i.y);
}

template<int SGN>
__device__ __forceinline__ void fft8(float2* f) {
    const float R = 0.70710678118654752f;
    const float WC[4] = {1.f, R, 0.f, -R};
    const float WS[4] = {0.f, R, 1.f, R};
    #pragma unroll
    for (int stage = 0; stage < 3; ++stage) {
        const int L = 8 >> stage, half = L >> 1, step = 1 << stage;
        #pragma unroll
        for (int base = 0; base < 8; base += L) {
            #pragma unroll
            for (int j = 0; j < half; ++j) {
                float2 u = f[base + j], v = f[base + half + j];
                f[base + j] = make_float2(u.x + v.x, u.y + v.y);
                float dx = u.x - v.x, dy = u.y - v.y;
                const int t = j * step;
                const float wr = WC[t];
                const float wi = (SGN > 0) ? WS[t] : -WS[t];
                f[base + half + j] = make_float2(dx * wr - dy * wi, dx * wi + dy * wr);
            }
        }
    }
    float2 tmp;
    tmp = f[1]; f[1] = f[4]; f[4] = tmp;
    tmp = f[3]; f[3] = f[6]; f[6] = tmp;
}

template<int SGN>
__device__ __forceinline__ void fft16(float2* f) {
    const float WC[8] = {1.f, 0.92387953251f, 0.70710678119f, 0.38268343236f,
                         0.f, -0.38268343236f, -0.70710678119f, -0.92387953251f};
    const float WS[8] = {0.f, 0.38268343236f, 0.70710678119f, 0.92387953251f,
                         1.f, 0.92387953251f, 0.70710678119f, 0.38268343236f};
    #pragma unroll
    for (int stage = 0; stage < 4; ++stage) {
        const int L = 16 >> stage, half = L >> 1, step = 1 << stage;
        #pragma unroll
        for (int base = 0; base < 16; base += L) {
            #pragma unroll
            for (int j = 0; j < half; ++j) {
                float2 u = f[base + j], v = f[base + half + j];
                f[base + j] = make_float2(u.x + v.x, u.y + v.y);
                float dx = u.x - v.x, dy = u.y - v.y;
                const int t = j * step;
                const float wr = WC[t];
                const float wi = (SGN > 0) ? WS[t] : -WS[t];
                f[base + half + j] = make_float2(dx * wr - dy * wi, dx * wi + dy * wr);
            }
        }
    }
    float2 tmp;
    tmp = f[1];  f[1]  = f[8];  f[8]  = tmp;
    tmp = f[2];  f[2]  = f[4];  f[4]  = tmp;
    tmp = f[3];  f[3]  = f[12]; f[12] = tmp;
    tmp = f[5];  f[5]  = f[10]; f[10] = tmp;
    tmp = f[7];  f[7]  = f[14]; f[14] = tmp;
    tmp = f[11]; f[11] = f[13]; f[13] = tmp;
}

__device__ __forceinline__ float waveReduceSum(float v) {
    #pragma unroll
    for (int off = 32; off > 0; off >>= 1) v += __shfl_down(v, off, 64);
    return v;
}

__device__ __forceinline__ void buildTw(float2* tw, int tid) {
    if (tid < 128) {
        float s, c;
        __sincosf((float)tid * 0.04908738521234052f, &s, &c);   // 2*pi/128
        tw[tid] = make_float2(c, s);
    }
}

// ======== 32-grid 4-filter inverse pass (R17; port of proven packed-32) ========
// Entry: staging into P4a/P4b complete (function starts with the barrier).
// Returns per-thread partial sum of |field| over all 4 packed filters.
__device__ __forceinline__ float pass32x4(float4* __restrict__ P4a,
                                          float4* __restrict__ P4b,
                                          const float2* __restrict__ tw, int tid) {
    __syncthreads();
    {   // col stepA: fft4 over b per a; 2 grids x (32 lines x 8 a) = 512
        float4* P = (tid & 256) ? P4b : P4a;
        int line = tid & 31, a = (tid >> 5) & 7;
        float2 f0[4], f1[4];
        #pragma unroll
        for (int kb = 0; kb < 4; ++kb) {
            float4 v = P[(4 * a + kb) * SG32 + line];
            f0[kb] = make_float2(v.x, v.y); f1[kb] = make_float2(v.z, v.w);
        }
        fft4<1>(f0); fft4<1>(f1);
        #pragma unroll
        for (int t = 0; t < 4; ++t) {
            float2 w = tw[4 * t * a];
            float2 aa = cmul(f0[t], w), d = cmul(f1[t], w);
            P[(4 * a + t) * SG32 + line] = make_float4(aa.x, aa.y, d.x, d.y);
        }
    }
    __syncthreads();
    if (tid < 256) {   // col stepB: fft8 over a per t; 2 grids x (32 x 4)
        float4* P = (tid & 128) ? P4b : P4a;
        int line = tid & 31, t = (tid >> 5) & 3;
        float2 f0[8], f1[8];
        #pragma unroll
        for (int a = 0; a < 8; ++a) {
            float4 v = P[(4 * a + t) * SG32 + line];
            f0[a] = make_float2(v.x, v.y); f1[a] = make_float2(v.z, v.w);
        }
        fft8<1>(f0); fft8<1>(f1);
        #pragma unroll
        for (int n1 = 0; n1 < 8; ++n1)
            P[(4 * n1 + t) * SG32 + line] =
                make_float4(f0[n1].x, f0[n1].y, f1[n1].x, f1[n1].y);
    }
    __syncthreads();
    {   // row stepA
        float4* P = (tid & 256) ? P4b : P4a;
        int row = tid & 31, a = (tid >> 5) & 7;
        float4* R = P + row * SG32 + 4 * a;
        float2 f0[4], f1[4];
        #pragma unroll
        for (int kb = 0; kb < 4; ++kb) {
            float4 v = R[kb];
            f0[kb] = make_float2(v.x, v.y); f1[kb] = make_float2(v.z, v.w);
        }
        fft4<1>(f0); fft4<1>(f1);
        #pragma unroll
        for (int t = 0; t < 4; ++t) {
            float2 w = tw[4 * t * a];
            float2 aa = cmul(f0[t], w), d = cmul(f1[t], w);
            R[t] = make_float4(aa.x, aa.y, d.x, d.y);
        }
    }
    __syncthreads();
    float a2 = 0.f;
    if (tid < 256) {   // row stepB + mag
        float4* P = (tid & 128) ? P4b : P4a;
        int row = tid & 31, t = (tid >> 5) & 3;
        float4* R = P + row * SG32 + t;
        float2 f0[8], f1[8];
        #pragma unroll
        for (int a = 0; a < 8; ++a) {
            float4 v = R[4 * a];
            f0[a] = make_float2(v.x, v.y); f1[a] = make_float2(v.z, v.w);
        }
        fft8<1>(f0); fft8<1>(f1);
        #pragma unroll
        for (int n1 = 0; n1 < 8; ++n1) {
            a2 += sqrtf(f0[n1].x * f0[n1].x + f0[n1].y * f0[n1].y);
            a2 += sqrtf(f1[n1].x * f1[n1].x + f1[n1].y * f1[n1].y);
        }
    }
    return a2;
}

// ======== 128-grid sweep phases (R6-R13 proven, TT=512) ========
template<int ES, int LS>
__device__ __forceinline__ void fwdA(float2* __restrict__ F,
                                     const float2* __restrict__ tw, int tid) {
    #pragma unroll
    for (int i = 0; i < 4; ++i) {
        int u = i * TT + tid;
        int t = u >> 7, x = u & 127;
        float2* M = F + x * LS;
        float2 f[8];
        #pragma unroll
        for (int n1 = 0; n1 < 8; ++n1) f[n1] = M[(t + 16 * n1) * ES];
        fft8<-1>(f);
        #pragma unroll
        for (int ka = 0; ka < 8; ++ka)
            M[(t + 16 * ka) * ES] = cmulc(f[ka], tw[t * ka]);
    }
}

template<int ES, int LS>
__device__ __forceinline__ void fwdB(float2* __restrict__ F, int tid) {
    #pragma unroll
    for (int i = 0; i < 2; ++i) {
        int u = i * TT + tid;
        int ka = u >> 7, x = u & 127;
        float2* M = F + x * LS;
        float2 g[16];
        #pragma unroll
        for (int t = 0; t < 16; ++t) g[t] = M[(16 * ka + t) * ES];
        fft16<-1>(g);
        #pragma unroll
        for (int kb = 0; kb < 16; ++kb) M[(16 * ka + kb) * ES] = g[kb];
    }
}

__device__ __forceinline__ void fwdB_col_capture(const float2* __restrict__ F, int tid,
                                                 float2* __restrict__ uh) {
    #pragma unroll
    for (int i = 0; i < 2; ++i) {
        int u = i * TT + tid;
        int ka = u >> 7, c = u & 127;
        float2 g[16];
        #pragma unroll
        for (int t = 0; t < 16; ++t) g[t] = F[(16 * ka + t) * SS + c];
        fft16<-1>(g);
        #pragma unroll
        for (int kb = 0; kb < 16; ++kb) uh[i * 16 + kb] = g[kb];
    }
}

template<int ES, int LS>
__device__ __forceinline__ void invA(float2* __restrict__ F,
                                     const float2* __restrict__ tw, int tid) {
    #pragma unroll
    for (int i = 0; i < 2; ++i) {
        int u = i * TT + tid;
        int ka = u >> 7, x = u & 127;
        float2* M = F + x * LS;
        float2 g[16];
        #pragma unroll
        for (int kb = 0; kb < 16; ++kb) g[kb] = M[(16 * ka + kb) * ES];
        fft16<1>(g);
        #pragma unroll
        for (int t = 0; t < 16; ++t)
            M[(16 * ka + t) * ES] = cmul(g[t], tw[t * ka]);
    }
}

template<int ES, int LS>
__device__ __forceinline__ void invB(float2* __restrict__ F, int tid) {
    #pragma unroll
    for (int i = 0; i < 4; ++i) {
        int u = i * TT + tid;
        int t = u >> 7, x = u & 127;
        float2* M = F + x * LS;
        float2 f[8];
        #pragma unroll
        for (int ka = 0; ka < 8; ++ka) f[ka] = M[(16 * ka + t) * ES];
        fft8<1>(f);
        #pragma unroll
        for (int nh = 0; nh < 8; ++nh) M[(t + 16 * nh) * ES] = f[nh];
    }
}

// FUSED: inverse row stepB -> |.| (raw, acc) -> forward row stepA (same cells).
__device__ __forceinline__ void invBmag_fwdA_row(float2* __restrict__ F,
                                                 const float2* __restrict__ tw,
                                                 int tid, float& acc) {
    #pragma unroll
    for (int i = 0; i < 4; ++i) {
        int u = i * TT + tid;
        int t = u >> 7, x = u & 127;
        float2* M = F + x * SS;
        float2 f[8];
        #pragma unroll
        for (int ka = 0; ka < 8; ++ka) f[ka] = M[16 * ka + t];
        fft8<1>(f);
        #pragma unroll
        for (int nh = 0; nh < 8; ++nh) {
            float m = sqrtf(f[nh].x * f[nh].x + f[nh].y * f[nh].y);
            acc += m;
            f[nh] = make_float2(m, 0.f);
        }
        fft8<-1>(f);
        #pragma unroll
        for (int ka = 0; ka < 8; ++ka)
            M[t + 16 * ka] = cmulc(f[ka], tw[t * ka]);
    }
}

// ---------- K_pre: fused filter bank + coeff zero + i_hat FFT ----------
__global__ __attribute__((amdgpu_flat_work_group_size(TT, TT), amdgpu_waves_per_eu(2, 2)))
void k_pre(const float* __restrict__ img,
           float* __restrict__ psi,
           float2* __restrict__ ihat,
           float* __restrict__ coeffs) {
    __shared__ float2 F[NN * SS];
    __shared__ float2 tw[128];
    __shared__ float red[TT / 64];
    int blk = blockIdx.x, tid = threadIdx.x;
    if (blk >= 64) {
        if (blk == 80) {
            for (int i = tid; i < 64 * 11; i += TT)
                if (i % 11 != 0) coeffs[i] = 0.f;
            return;
        }
        int f = blk - 64;
        int j = f >> 2, l = f & 3;
        float k0    = 2.35619449019234493f / (float)(1 << j);
        float sigma = 0.8f * (float)(1 << j);
        float s2    = sigma * sigma;
        float theta = 0.78539816339744831f * (float)l;
        float k0x = k0 * cosf(theta);
        float k0y = k0 * sinf(theta);
        float beta = expf(-0.5f * s2 * k0 * k0);
        const float FSTEP = 0.04908738521234052f;
        float* dst = psi + (size_t)f * NPIX;
        for (int i = tid; i < NPIX; i += TT) {
            int pr = i >> 7, pc = i & 127;
            int kr = (pr >> 4) + 8 * (pr & 15);
            int kc = (pc >> 4) + 8 * (pc & 15);
            float fr = (float)(kr < 64 ? kr : kr - 128) * FSTEP;
            float fc = (float)(kc < 64 ? kc : kc - 128) * FSTEP;
            float dx = fr - k0x, dy = fc - k0y;
            float g1 = expf(-0.5f * s2 * (dx * dx + dy * dy));
            float g0 = expf(-0.5f * s2 * (fr * fr + fc * fc));
            dst[i] = g1 - beta * g0;
        }
        return;
    }
    int b = blk;
    buildTw(tw, tid);
    const float* im = img + (size_t)b * NPIX;
    float acc = 0.f;
    #pragma unroll
    for (int k = 0; k < EPT; ++k) {
        int e = k * TT + tid;
        float v = im[e];
        acc += v;
        F[(e >> 7) * SS + (e & 127)] = make_float2(v, 0.f);
    }
    float ws = waveReduceSum(acc);
    if ((tid & 63) == 0) red[tid >> 6] = ws;
    __syncthreads();
    if (tid == 0) {
        float t = 0.f;
        #pragma unroll
        for (int w = 0; w < TT / 64; ++w) t += red[w];
        coeffs[b * 11 + 0] = t * (1.f / 16384.f);
    }
    fwdA<1, SS>(F, tw, tid);  __syncthreads();
    fwdB<1, SS>(F, tid);      __syncthreads();
    fwdA<SS, 1>(F, tw, tid);  __syncthreads();
    float2 uh[32];
    fwdB_col_capture(F, tid, uh);
    float2* dst = ihat + (size_t)b * NPIX;
    #pragma unroll
    for (int i = 0; i < 2; ++i) {
        int u = i * TT + tid;
        int ka = u >> 7, c = u & 127;
        #pragma unroll
        for (int kb = 0; kb < 16; ++kb)
            dst[(16 * ka + kb) * NN + c] = uh[i * 16 + kb];
    }
}

// ---------- K_scat_big: j1 = 0 ONLY (grid 256 = one round) ----------
__global__ __attribute__((amdgpu_flat_work_group_size(TT, TT), amdgpu_waves_per_eu(2, 2)))
void k_scat_big(const float2* __restrict__ ihat,
                const float* __restrict__ psi,
                float* __restrict__ coeffs) {
    // F: 16640 float2 = 133,120 B.
    //   128-grid phases use F[0..16512) with stride SS.
    //   j2=1 one-pass: G2a..G2d = F + {0,4160,8320,12480}  (4x 64x65 float2)
    //   j2=2 pass:     G4a = (float4*)F, G4b = (float4*)(F+8320) (2x 64x65 float4)
    //   j2=3 pass:     P4a/P4b = two 32x33 float4 grids at F[0..4224)  (R17)
    __shared__ __align__(16) float2 F[16640];
    __shared__ float2 tw[128];
    float4* G4a = (float4*)F;
    float4* G4b = (float4*)(F + 8320);
    float2* G2a = F;
    float2* G2b = F + 4160;
    float2* G2c = F + 8320;
    float2* G2d = F + 12480;
    float4* P4a = (float4*)F;
    float4* P4b = (float4*)F + 1056;
    int tid = threadIdx.x;
    int x = blockIdx.x;
    int b = x & 63, l1 = x >> 6;                       // j1 == 0
    const float2* ih = ihat + (size_t)b * NPIX;
    const float*  p1 = psi + (size_t)l1 * NPIX;
    buildTw(tw, tid);

    const float S1_128 = 9.3132257461547852e-10f;   // 2^-30
    const float S2TR   = 5.6843418860808015e-14f;   // 2^-44
    const float S2_03  = 2.2737367544323206e-13f;   // 2^-42 = 4*S2TR (32-grid)

    int kalo = tid >> 7, c = tid & 127;
    {
        #pragma unroll
        for (int i = 0; i < 2; ++i) {
            int ka = kalo + 4 * i;
            float2 g[16];
            #pragma unroll
            for (int kb = 0; kb < 16; ++kb) {
                int e = (16 * ka + kb) * NN + c;
                float2 z = ih[e];
                float  p = p1[e];
                g[kb] = make_float2(z.x * p, z.y * p);
            }
            fft16<1>(g);
            #pragma unroll
            for (int t = 0; t < 16; ++t)
                F[(16 * ka + t) * SS + c] = cmul(g[t], tw[t * ka]);
        }
    }
    __syncthreads();
    invB<SS, 1>(F, tid);      __syncthreads();
    invA<1, SS>(F, tw, tid);  __syncthreads();
    float acc = 0.f;
    invBmag_fwdA_row(F, tw, tid, acc);
    float ws1 = waveReduceSum(acc);
    if ((tid & 63) == 0) atomicAdd(&coeffs[b * 11 + 1], ws1 * S1_128);
    __syncthreads();
    fwdB<1, SS>(F, tid);      __syncthreads();
    fwdA<SS, 1>(F, tw, tid);  __syncthreads();
    float2 uh[32];
    fwdB_col_capture(F, tid, uh);
    __syncthreads();   // capture done -> F reusable (grids alias it)

    // trunc-staging column perm (central +-32 window), for j2=2
    int m = c & 15;
    bool colKeep = (m < 4) || (m >= 12);
    int pc64 = 8 * (c >> 4) + ((m < 4) ? m : (m - 8));

    {
        // ===== (j1=0, j2=1): ONE pass, 4 off-center 64-windows (R14 mapping) =====
        // o per l2 (biased 3 bins to DC): l2=0:(21,0) 1:(15,15) 2:(0,21) 3:(-15,15)
        const int ORW[4] = {21, 15, 0, -15};
        const int OCW[4] = { 0, 15, 21,  15};
        int fc = (c >> 4) + 8 * (c & 15);
        bool ckw[4]; int pcw[4];
        #pragma unroll
        for (int w = 0; w < 4; ++w) {
            int dc = (fc - OCW[w]) & 127;
            ckw[w] = (dc < 32) || (dc >= 96);
            int uc = (dc < 32) ? dc : (dc - 64);
            pcw[w] = 8 * (uc & 7) + (uc >> 3);
        }
        #pragma unroll
        for (int i = 0; i < 2; ++i) {
            int ka = kalo + 4 * i;
            #pragma unroll
            for (int kb = 0; kb < 16; ++kb) {
                int fr = ka + 8 * kb;
                float2 z = uh[i * 16 + kb];
                int e = (16 * ka + kb) * NN + c;
                #pragma unroll
                for (int w = 0; w < 4; ++w) {
                    if (ckw[w]) {
                        int dr = (fr - ORW[w]) & 127;
                        if (dr < 32 || dr >= 96) {
                            int ur = (dr < 32) ? dr : (dr - 64);
                            int pr = 8 * (ur & 7) + (ur >> 3);
                            float pv = psi[(size_t)(4 + w) * NPIX + e];
                            float2* G = (w == 0) ? G2a : (w == 1) ? G2b
                                       : (w == 2) ? G2c : G2d;
                            G[pr * SG + pcw[w]] = make_float2(z.x * pv, z.y * pv);
                        }
                    }
                }
            }
        }
        __syncthreads();
        {   // col stepA (4 grids, full width)
            int col = tid & 63, k8 = tid >> 6;
            float2 f0[8], f1[8], f2[8], f3[8];
            #pragma unroll
            for (int kb = 0; kb < 8; ++kb) {
                int o = (8 * k8 + kb) * SG + col;
                f0[kb] = G2a[o]; f1[kb] = G2b[o]; f2[kb] = G2c[o]; f3[kb] = G2d[o];
            }
            fft8<1>(f0); fft8<1>(f1); fft8<1>(f2); fft8<1>(f3);
            #pragma unroll
            for (int q = 0; q < 8; ++q) {
                float2 w = tw[2 * q * k8];
                int o = (8 * k8 + q) * SG + col;
                G2a[o] = cmul(f0[q], w); G2b[o] = cmul(f1[q], w);
                G2c[o] = cmul(f2[q], w); G2d[o] = cmul(f3[q], w);
            }
        }
        __syncthreads();
        {   // col stepB
            int col = tid & 63, q = tid >> 6;
            float2 f0[8], f1[8], f2[8], f3[8];
            #pragma unroll
            for (int k8 = 0; k8 < 8; ++k8) {
                int o = (8 * k8 + q) * SG + col;
                f0[k8] = G2a[o]; f1[k8] = G2b[o]; f2[k8] = G2c[o]; f3[k8] = G2d[o];
            }
            fft8<1>(f0); fft8<1>(f1); fft8<1>(f2); fft8<1>(f3);
            #pragma unroll
            for (int n1 = 0; n1 < 8; ++n1) {
                int o = (8 * n1 + q) * SG + col;
                G2a[o] = f0[n1]; G2b[o] = f1[n1]; G2c[o] = f2[n1]; G2d[o] = f3[n1];
            }
        }
        __syncthreads();
        {   // row stepA
            int row = tid & 63, k8 = tid >> 6;
            int base = row * SG + 8 * k8;
            float2 f0[8], f1[8], f2[8], f3[8];
            #pragma unroll
            for (int kb = 0; kb < 8; ++kb) {
                f0[kb] = G2a[base + kb]; f1[kb] = G2b[base + kb];
                f2[kb] = G2c[base + kb]; f3[kb] = G2d[base + kb];
            }
            fft8<1>(f0); fft8<1>(f1); fft8<1>(f2); fft8<1>(f3);
            #pragma unroll
            for (int q = 0; q < 8; ++q) {
                float2 w = tw[2 * q * k8];
                G2a[base + q] = cmul(f0[q], w); G2b[base + q] = cmul(f1[q], w);
                G2c[base + q] = cmul(f2[q], w); G2d[base + q] = cmul(f3[q], w);
            }
        }
        __syncthreads();
        float a2 = 0.f;
        {   // row stepB + mag (all 4 -> same coeff)
            int row = tid & 63, q = tid >> 6;
            int base = row * SG + q;
            float2 f0[8], f1[8], f2[8], f3[8];
            #pragma unroll
            for (int k8 = 0; k8 < 8; ++k8) {
                int o = base + 8 * k8;
                f0[k8] = G2a[o]; f1[k8] = G2b[o]; f2[k8] = G2c[o]; f3[k8] = G2d[o];
            }
            fft8<1>(f0); fft8<1>(f1); fft8<1>(f2); fft8<1>(f3);
            #pragma unroll
            for (int n1 = 0; n1 < 8; ++n1) {
                a2 += sqrtf(f0[n1].x * f0[n1].x + f0[n1].y * f0[n1].y);
                a2 += sqrtf(f1[n1].x * f1[n1].x + f1[n1].y * f1[n1].y);
                a2 += sqrtf(f2[n1].x * f2[n1].x + f2[n1].y * f2[n1].y);
                a2 += sqrtf(f3[n1].x * f3[n1].x + f3[n1].y * f3[n1].y);
            }
        }
        float ws2 = waveReduceSum(a2);
        if ((tid & 63) == 0) atomicAdd(&coeffs[b * 11 + 5 + 0], ws2 * S2TR);
        __syncthreads();
    }

    {   // ===== (0,2): ONE pass, 4 filters, central +-32 64-grid =====
        const float* p0 = psi + (size_t)8 * NPIX;
        const float* pq1 = p0 + NPIX;
        const float* pq2 = pq1 + NPIX;
        const float* pq3 = pq2 + NPIX;
        if (colKeep) {
            #pragma unroll
            for (int i = 0; i < 2; ++i) {
                int ka = kalo + 4 * i;
                #pragma unroll
                for (int kb = 0; kb < 16; ++kb) {
                    if (kb < 4 || kb >= 12) {
                        int pr64 = 8 * ka + ((kb < 4) ? kb : (kb - 8));
                        float2 z = uh[i * 16 + kb];
                        int e = (16 * ka + kb) * NN + c;
                        float a0 = p0[e], a1 = pq1[e], a2f = pq2[e], a3 = pq3[e];
                        G4a[pr64 * SG + pc64] =
                            make_float4(z.x * a0, z.y * a0, z.x * a1, z.y * a1);
                        G4b[pr64 * SG + pc64] =
                            make_float4(z.x * a2f, z.y * a2f, z.x * a3, z.y * a3);
                    }
                }
            }
        }
        __syncthreads();
        {   // col stepA (two packed grids = 4 filters, full width)
            int col = tid & 63, k8 = tid >> 6;
            float2 f0[8], f1[8], f2[8], f3[8];
            #pragma unroll
            for (int kb = 0; kb < 8; ++kb) {
                int o = (8 * k8 + kb) * SG + col;
                float4 v = G4a[o];
                f0[kb] = make_float2(v.x, v.y); f1[kb] = make_float2(v.z, v.w);
                float4 u = G4b[o];
                f2[kb] = make_float2(u.x, u.y); f3[kb] = make_float2(u.z, u.w);
            }
            fft8<1>(f0); fft8<1>(f1); fft8<1>(f2); fft8<1>(f3);
            #pragma unroll
            for (int q = 0; q < 8; ++q) {
                float2 w = tw[2 * q * k8];
                int o = (8 * k8 + q) * SG + col;
                float2 a = cmul(f0[q], w), d = cmul(f1[q], w);
                G4a[o] = make_float4(a.x, a.y, d.x, d.y);
                float2 a2c = cmul(f2[q], w), d2 = cmul(f3[q], w);
                G4b[o] = make_float4(a2c.x, a2c.y, d2.x, d2.y);
            }
        }
        __syncthreads();
        {   // col stepB
            int col = tid & 63, q = tid >> 6;
            float2 f0[8], f1[8], f2[8], f3[8];
            #pragma unroll
            for (int k8 = 0; k8 < 8; ++k8) {
                int o = (8 * k8 + q) * SG + col;
                float4 v = G4a[o];
                f0[k8] = make_float2(v.x, v.y); f1[k8] = make_float2(v.z, v.w);
                float4 u = G4b[o];
                f2[k8] = make_float2(u.x, u.y); f3[k8] = make_float2(u.z, u.w);
            }
            fft8<1>(f0); fft8<1>(f1); fft8<1>(f2); fft8<1>(f3);
            #pragma unroll
            for (int n1 = 0; n1 < 8; ++n1) {
                int o = (8 * n1 + q) * SG + col;
                G4a[o] = make_float4(f0[n1].x, f0[n1].y, f1[n1].x, f1[n1].y);
                G4b[o] = make_float4(f2[n1].x, f2[n1].y, f3[n1].x, f3[n1].y);
            }
        }
        __syncthreads();
        {   // row stepA
            int row = tid & 63, k8 = tid >> 6;
            int base = row * SG + 8 * k8;
            float2 f0[8], f1[8], f2[8], f3[8];
            #pragma unroll
            for (int kb = 0; kb < 8; ++kb) {
                float4 v = G4a[base + kb];
                f0[kb] = make_float2(v.x, v.y); f1[kb] = make_float2(v.z, v.w);
                float4 u = G4b[base + kb];
                f2[kb] = make_float2(u.x, u.y); f3[kb] = make_float2(u.z, u.w);
            }
            fft8<1>(f0); fft8<1>(f1); fft8<1>(f2); fft8<1>(f3);
            #pragma unroll
            for (int q = 0; q < 8; ++q) {
                float2 w = tw[2 * q * k8];
                float2 a = cmul(f0[q], w), d = cmul(f1[q], w);
                G4a[base + q] = make_float4(a.x, a.y, d.x, d.y);
                float2 a2c = cmul(f2[q], w), d2 = cmul(f3[q], w);
                G4b[base + q] = make_float4(a2c.x, a2c.y, d2.x, d2.y);
            }
        }
        __syncthreads();
        float a2 = 0.f;
        {   // row stepB + mag
            int row = tid & 63, q = tid >> 6;
            int base = row * SG + q;
            float2 f0[8], f1[8], f2[8], f3[8];
            #pragma unroll
            for (int k8 = 0; k8 < 8; ++k8) {
                float4 v = G4a[base + 8 * k8];
                f0[k8] = make_float2(v.x, v.y); f1[k8] = make_float2(v.z, v.w);
                float4 u = G4b[base + 8 * k8];
                f2[k8] = make_float2(u.x, u.y); f3[k8] = make_float2(u.z, u.w);
            }
            fft8<1>(f0); fft8<1>(f1); fft8<1>(f2); fft8<1>(f3);
            #pragma unroll
            for (int n1 = 0; n1 < 8; ++n1) {
                a2 += sqrtf(f0[n1].x * f0[n1].x + f0[n1].y * f0[n1].y);
                a2 += sqrtf(f1[n1].x * f1[n1].x + f1[n1].y * f1[n1].y);
                a2 += sqrtf(f2[n1].x * f2[n1].x + f2[n1].y * f2[n1].y);
                a2 += sqrtf(f3[n1].x * f3[n1].x + f3[n1].y * f3[n1].y);
            }
        }
        float ws2 = waveReduceSum(a2);
        if ((tid & 63) == 0) atomicAdd(&coeffs[b * 11 + 5 + 1], ws2 * S2TR);
        __syncthreads();
    }

    {   // ===== (0,3): 32-grid 4-filter pass (R17; central +-16 of uh) =====
        bool ck32 = (m < 2) || (m >= 14);
        int pc32 = 4 * (c >> 4) + ((m < 2) ? m : (m - 12));
        const float* p0 = psi + (size_t)12 * NPIX;
        const float* pq1 = p0 + NPIX;
        const float* pq2 = pq1 + NPIX;
        const float* pq3 = pq2 + NPIX;
        if (ck32) {
            #pragma unroll
            for (int i = 0; i < 2; ++i) {
                int ka = kalo + 4 * i;
                #pragma unroll
                for (int kb = 0; kb < 16; ++kb) {
                    if (kb < 2 || kb >= 14) {
                        int pr32 = 4 * ka + ((kb < 2) ? kb : (kb - 12));
                        float2 z = uh[i * 16 + kb];
                        int e = (16 * ka + kb) * NN + c;
                        float a0 = p0[e], a1 = pq1[e], a2f = pq2[e], a3 = pq3[e];
                        P4a[pr32 * SG32 + pc32] =
                            make_float4(z.x * a0, z.y * a0, z.x * a1, z.y * a1);
                        P4b[pr32 * SG32 + pc32] =
                            make_float4(z.x * a2f, z.y * a2f, z.x * a3, z.y * a3);
                    }
                }
            }
        }
        float a2 = pass32x4(P4a, P4b, tw, tid);
        float ws2 = waveReduceSum(a2);
        if ((tid & 63) == 0) atomicAdd(&coeffs[b * 11 + 5 + 2], ws2 * S2_03);
    }
}

// ---------- K_scat_small: j1 in {1,2,3} -- 66.6 KB LDS => 2 blocks/CU ----------
__global__ __attribute__((amdgpu_flat_work_group_size(TT, TT), amdgpu_waves_per_eu(4, 4)))
void k_scat_small(const float2* __restrict__ ihat,
                  const float* __restrict__ psi,
                  float* __restrict__ coeffs) {
    // S: 8320 float2 = 66,560 B.
    //   G2 (64x65 float2) = S[0..4160); H32 = S[6144..7168) (j1=2 path only);
    //   G4 (64x65 float4) aliases S[0..8320) (j1=1 (1,2) passes);
    //   P4a/P4b (two 32x33 float4) alias S[0..4224) (32-grid passes, R17);
    //   G32 (32x33 float2) aliases S[0..) (j1=3 first order).
    __shared__ __align__(16) float2 S[8320];
    __shared__ float2 tw[128];
    float2* G2  = S;
    float2* G32 = S;
    float4* G4  = (float4*)S;
    float4* P4a = (float4*)S;
    float4* P4b = (float4*)S + 1056;
    float2* H32 = S + 6144;
    int tid = threadIdx.x;
    int x = blockIdx.x;
    int b = x & 63, l1 = (x >> 6) & 3;
    int t0 = x >> 8;                          // 0 -> j1=1 (heavy, first), 1 -> j1=2, 2 -> j1=3
    int j1 = (t0 == 0) ? 1 : (t0 + 1);
    const float2* ih = ihat + (size_t)b * NPIX;
    const float*  p1 = psi + (size_t)(j1 * 4 + l1) * NPIX;
    buildTw(tw, tid);

    const float S1_64 = 3.7252902984619141e-9f;    // 2^-28
    const float S1_32 = 1.4901161193847656e-8f;    // 2^-26
    const float S2_32 = 9.0949470177292824e-13f;   // 2^-40 (also (1,3): 4*S2_V)
    const float S2_V  = 2.2737367544323206e-13f;   // 2^-42 = 4*S2TR (V = uh/4)

    int kalo = tid >> 7, c = tid & 127;

    if (t0 == 0) {
        // =========== j1 = 1 on off-center 64-window (R16) ===========
        const int OR1[4] = {21, 15, 0, -15};
        const int OC1[4] = { 0, 15, 21,  15};
        int fc = (c >> 4) + 8 * (c & 15);
        int dc = (fc - OC1[l1]) & 127;
        bool ck = (dc < 32) || (dc >= 96);
        int ucw = (dc < 32) ? dc : (dc - 64);
        int pcd = 8 * (ucw & 7) + (ucw >> 3);
        if (ck) {
            #pragma unroll
            for (int i = 0; i < 2; ++i) {
                int ka = kalo + 4 * i;
                #pragma unroll
                for (int kb = 0; kb < 16; ++kb) {
                    int fr = ka + 8 * kb;
                    int dr = (fr - OR1[l1]) & 127;
                    if (dr < 32 || dr >= 96) {
                        int ur = (dr < 32) ? dr : (dr - 64);
                        int pr = 8 * (ur & 7) + (ur >> 3);
                        int e = (16 * ka + kb) * NN + c;
                        float2 z = ih[e];
                        float  p = p1[e];
                        G2[pr * SG + pcd] = make_float2(z.x * p, z.y * p);
                    }
                }
            }
        }
        __syncthreads();
        {   // col stepA (inverse)
            int col = tid & 63, k8 = tid >> 6;
            float2 f[8];
            #pragma unroll
            for (int kb = 0; kb < 8; ++kb) f[kb] = G2[(8 * k8 + kb) * SG + col];
            fft8<1>(f);
            #pragma unroll
            for (int q = 0; q < 8; ++q)
                G2[(8 * k8 + q) * SG + col] = cmul(f[q], tw[2 * q * k8]);
        }
        __syncthreads();
        {   // col stepB
            int col = tid & 63, q = tid >> 6;
            float2 f[8];
            #pragma unroll
            for (int k8 = 0; k8 < 8; ++k8) f[k8] = G2[(8 * k8 + q) * SG + col];
            fft8<1>(f);
            #pragma unroll
            for (int n1 = 0; n1 < 8; ++n1) G2[(8 * n1 + q) * SG + col] = f[n1];
        }
        __syncthreads();
        {   // row stepA (inverse)
            int row = tid & 63, k8 = tid >> 6;
            float2* R = G2 + row * SG + 8 * k8;
            float2 f[8];
            #pragma unroll
            for (int kb = 0; kb < 8; ++kb) f[kb] = R[kb];
            fft8<1>(f);
            #pragma unroll
            for (int q = 0; q < 8; ++q) R[q] = cmul(f[q], tw[2 * q * k8]);
        }
        __syncthreads();
        float acc = 0.f;
        {   // FUSED64: row stepB inv -> |.| -> row stepA fwd
            int row = tid & 63, q = tid >> 6;
            float2* R = G2 + row * SG + q;
            float2 f[8];
            #pragma unroll
            for (int k8 = 0; k8 < 8; ++k8) f[k8] = R[8 * k8];
            fft8<1>(f);
            #pragma unroll
            for (int n1 = 0; n1 < 8; ++n1) {
                float mg = sqrtf(f[n1].x * f[n1].x + f[n1].y * f[n1].y);
                acc += mg;
                f[n1] = make_float2(mg, 0.f);
            }
            fft8<-1>(f);
            #pragma unroll
            for (int ka = 0; ka < 8; ++ka)
                R[8 * ka] = cmulc(f[ka], tw[2 * q * ka]);
        }
        float ws1 = waveReduceSum(acc);
        if ((tid & 63) == 0) atomicAdd(&coeffs[b * 11 + 2], ws1 * S1_64);
        __syncthreads();
        {   // row stepB (forward)
            int row2 = tid & 63, ka = tid >> 6;
            float2* R2 = G2 + row2 * SG + 8 * ka;
            float2 g[8];
            #pragma unroll
            for (int t = 0; t < 8; ++t) g[t] = R2[t];
            fft8<-1>(g);
            #pragma unroll
            for (int kb = 0; kb < 8; ++kb) R2[kb] = g[kb];
        }
        __syncthreads();
        {   // col stepA (forward)
            int col = tid & 63, t = tid >> 6;
            float2 g[8];
            #pragma unroll
            for (int n1 = 0; n1 < 8; ++n1) g[n1] = G2[(t + 8 * n1) * SG + col];
            fft8<-1>(g);
            #pragma unroll
            for (int ka = 0; ka < 8; ++ka)
                G2[(t + 8 * ka) * SG + col] = cmulc(g[ka], tw[2 * t * ka]);
        }
        __syncthreads();
        float2 vh[8];
        int c6 = tid & 63, ka8 = tid >> 6;
        {   // col stepB (forward) -> V = u1hat_64 captured to registers
            // vh[kb] = V at 64-freq row u64 = 8*kb + ka8, storage col c6
            float2 g[8];
            #pragma unroll
            for (int t = 0; t < 8; ++t) g[t] = G2[(8 * ka8 + t) * SG + c6];
            fft8<-1>(g);
            #pragma unroll
            for (int kb = 0; kb < 8; ++kb) vh[kb] = g[kb];
        }
        __syncthreads();   // G2 reads done -> G4/P4 (aliases) safe to write

        // psi gather indices: 64-grid storage p <-> freq u = 8*(p&7)+(p>>3);
        // 128-freq f128 = u<32 ? u : u+64; storage s = 16*(f128&7)+(f128>>3)
        int uc64 = 8 * (c6 & 7) + (c6 >> 3);
        int fc128 = (uc64 < 32) ? uc64 : (uc64 + 64);
        int scI = 16 * (fc128 & 7) + (fc128 >> 3);
        int se[8];
        #pragma unroll
        for (int kb = 0; kb < 8; ++kb) {
            int ur = 8 * kb + ka8;
            int fr128 = (ur < 32) ? ur : (ur + 64);
            se[kb] = (16 * (fr128 & 7) + (fr128 >> 3)) * NN + scI;
        }

        {   // ===== (1,2): two passes (2 filters each, G4 = full S) =====
            for (int half = 0; half < 2; ++half) {
                const float* p2a = psi + (size_t)(8 + 2 * half) * NPIX;
                const float* p2b = p2a + NPIX;
                #pragma unroll
                for (int kb = 0; kb < 8; ++kb) {
                    float pa = p2a[se[kb]], pb = p2b[se[kb]];
                    G4[(8 * ka8 + kb) * SG + c6] =
                        make_float4(vh[kb].x * pa, vh[kb].y * pa,
                                    vh[kb].x * pb, vh[kb].y * pb);
                }
                __syncthreads();
                {   // col stepA
                    int col = tid & 63, k8 = tid >> 6;
                    float2 f0[8], f1[8];
                    #pragma unroll
                    for (int kb = 0; kb < 8; ++kb) {
                        float4 v = G4[(8 * k8 + kb) * SG + col];
                        f0[kb] = make_float2(v.x, v.y); f1[kb] = make_float2(v.z, v.w);
                    }
                    fft8<1>(f0); fft8<1>(f1);
                    #pragma unroll
                    for (int q = 0; q < 8; ++q) {
                        float2 w = tw[2 * q * k8];
                        float2 a = cmul(f0[q], w), d = cmul(f1[q], w);
                        G4[(8 * k8 + q) * SG + col] = make_float4(a.x, a.y, d.x, d.y);
                    }
                }
                __syncthreads();
                {   // col stepB
                    int col = tid & 63, q = tid >> 6;
                    float2 f0[8], f1[8];
                    #pragma unroll
                    for (int k8 = 0; k8 < 8; ++k8) {
                        float4 v = G4[(8 * k8 + q) * SG + col];
                        f0[k8] = make_float2(v.x, v.y); f1[k8] = make_float2(v.z, v.w);
                    }
                    fft8<1>(f0); fft8<1>(f1);
                    #pragma unroll
                    for (int n1 = 0; n1 < 8; ++n1)
                        G4[(8 * n1 + q) * SG + col] =
                            make_float4(f0[n1].x, f0[n1].y, f1[n1].x, f1[n1].y);
                }
                __syncthreads();
                {   // row stepA
                    int row = tid & 63, k8 = tid >> 6;
                    float4* R = G4 + row * SG + 8 * k8;
                    float2 f0[8], f1[8];
                    #pragma unroll
                    for (int kb = 0; kb < 8; ++kb) {
                        float4 v = R[kb];
                        f0[kb] = make_float2(v.x, v.y); f1[kb] = make_float2(v.z, v.w);
                    }
                    fft8<1>(f0); fft8<1>(f1);
                    #pragma unroll
                    for (int q = 0; q < 8; ++q) {
                        float2 w = tw[2 * q * k8];
                        float2 a = cmul(f0[q], w), d = cmul(f1[q], w);
                        R[q] = make_float4(a.x, a.y, d.x, d.y);
                    }
                }
                __syncthreads();
                float a2 = 0.f;
                {   // row stepB + mag
                    int row = tid & 63, q = tid >> 6;
                    float4* R = G4 + row * SG + q;
                    float2 f0[8], f1[8];
                    #pragma unroll
                    for (int k8 = 0; k8 < 8; ++k8) {
                        float4 v = R[8 * k8];
                        f0[k8] = make_float2(v.x, v.y); f1[k8] = make_float2(v.z, v.w);
                    }
                    fft8<1>(f0); fft8<1>(f1);
                    #pragma unroll
                    for (int n1 = 0; n1 < 8; ++n1) {
                        a2 += sqrtf(f0[n1].x * f0[n1].x + f0[n1].y * f0[n1].y);
                        a2 += sqrtf(f1[n1].x * f1[n1].x + f1[n1].y * f1[n1].y);
                    }
                }
                float ws2 = waveReduceSum(a2);
                if ((tid & 63) == 0) atomicAdd(&coeffs[b * 11 + 5 + 3], ws2 * S2_V);
                __syncthreads();
            }
        }

        {   // ===== (1,3): ONE 32-grid 4-filter pass (R17; central +-16 of V) =====
            // rows: u64 = 8*kb + ka8 in [0,16)u[48,64) <=> kb in {0,1,6,7};
            //       pr32 = 4*ka8 + (kb&3)  (proven H32-capture perm)
            // cols: m6 = c6&7 in {0,1,6,7}; p32c = 4*(c6>>3) + ((m6<2)?m6:(m6-4))
            int m6 = c6 & 7;
            bool ckV = (m6 < 2) || (m6 >= 6);
            int p32c = 4 * (c6 >> 3) + ((m6 < 2) ? m6 : (m6 - 4));
            const float* p0 = psi + (size_t)12 * NPIX;
            const float* pq1 = p0 + NPIX;
            const float* pq2 = pq1 + NPIX;
            const float* pq3 = pq2 + NPIX;
            if (ckV) {
                #pragma unroll
                for (int kb = 0; kb < 8; ++kb) {
                    if (kb < 2 || kb >= 6) {
                        int pr32 = 4 * ka8 + (kb & 3);
                        float2 z = vh[kb];
                        float a0 = p0[se[kb]], a1 = pq1[se[kb]];
                        float a2f = pq2[se[kb]], a3 = pq3[se[kb]];
                        P4a[pr32 * SG32 + p32c] =
                            make_float4(z.x * a0, z.y * a0, z.x * a1, z.y * a1);
                        P4b[pr32 * SG32 + p32c] =
                            make_float4(z.x * a2f, z.y * a2f, z.x * a3, z.y * a3);
                    }
                }
            }
            float a2 = pass32x4(P4a, P4b, tw, tid);
            float ws2 = waveReduceSum(a2);
            if ((tid & 63) == 0) atomicAdd(&coeffs[b * 11 + 5 + 4], ws2 * S2_32);
        }
        return;
    }

    if (t0 == 2) {
        // ===== j1=3: 32-grid first order (psi_{j1=3} support +-16) =====
        int m = c & 15;
        bool ck32 = (m < 2) || (m >= 14);
        int pc32 = 4 * (c >> 4) + ((m < 2) ? m : (m - 12));
        if (ck32) {
            #pragma unroll
            for (int i = 0; i < 2; ++i) {
                int ka = kalo + 4 * i;
                #pragma unroll
                for (int kb = 0; kb < 16; ++kb) {
                    if (kb < 2 || kb >= 14) {
                        int e = (16 * ka + kb) * NN + c;
                        float2 z = ih[e];
                        float  p = p1[e];
                        int pr32 = 4 * ka + ((kb < 2) ? kb : (kb - 12));
                        G32[pr32 * SG32 + pc32] = make_float2(z.x * p, z.y * p);
                    }
                }
            }
        }
        __syncthreads();
        if (tid < 256) {   // col stepA: fft4 over b per a (32 lines x 8 a)
            int line = tid & 31, a = tid >> 5;
            float2 f[4];
            #pragma unroll
            for (int kb = 0; kb < 4; ++kb) f[kb] = G32[(4 * a + kb) * SG32 + line];
            fft4<1>(f);
            #pragma unroll
            for (int t = 0; t < 4; ++t)
                G32[(4 * a + t) * SG32 + line] = cmul(f[t], tw[4 * t * a]);
        }
        __syncthreads();
        if (tid < 128) {   // col stepB: fft8 over a per t (32 lines x 4 t)
            int line = tid & 31, t = tid >> 5;
            float2 f[8];
            #pragma unroll
            for (int a = 0; a < 8; ++a) f[a] = G32[(4 * a + t) * SG32 + line];
            fft8<1>(f);
            #pragma unroll
            for (int n1 = 0; n1 < 8; ++n1) G32[(4 * n1 + t) * SG32 + line] = f[n1];
        }
        __syncthreads();
        if (tid < 256) {   // row stepA
            int row = tid & 31, a = tid >> 5;
            float2* R = G32 + row * SG32 + 4 * a;
            float2 f[4];
            #pragma unroll
            for (int kb = 0; kb < 4; ++kb) f[kb] = R[kb];
            fft4<1>(f);
            #pragma unroll
            for (int t = 0; t < 4; ++t) R[t] = cmul(f[t], tw[4 * t * a]);
        }
        __syncthreads();
        float acc = 0.f;
        if (tid < 128) {   // row stepB + mag
            int row = tid & 31, t = tid >> 5;
            float2* R = G32 + row * SG32 + t;
            float2 f[8];
            #pragma unroll
            for (int a = 0; a < 8; ++a) f[a] = R[4 * a];
            fft8<1>(f);
            #pragma unroll
            for (int n1 = 0; n1 < 8; ++n1)
                acc += sqrtf(f[n1].x * f[n1].x + f[n1].y * f[n1].y);
        }
        float ws1 = waveReduceSum(acc);
        if ((tid & 63) == 0 && tid < 128) atomicAdd(&coeffs[b * 11 + 4], ws1 * S1_32);
        return;
    }

    // ===================== j1 == 2: 64-grid first order (R13-proven) ==============
    int m = c & 15;
    bool colKeep = (m < 4) || (m >= 12);
    if (colKeep) {
        #pragma unroll
        for (int i = 0; i < 2; ++i) {
            int ka = kalo + 4 * i;
            #pragma unroll
            for (int kb = 0; kb < 16; ++kb) {
                if (kb < 4 || kb >= 12) {
                    int e = (16 * ka + kb) * NN + c;
                    float2 z = ih[e];
                    float  p = p1[e];
                    int pr64 = 8 * ka + ((kb < 4) ? kb : (kb - 8));
                    int pc64 = 8 * (c >> 4) + ((m < 4) ? m : (m - 8));
                    G2[pr64 * SG + pc64] = make_float2(z.x * p, z.y * p);
                }
            }
        }
    }
    __syncthreads();
    {   // col stepA (inverse)
        int col = tid & 63, k8 = tid >> 6;
        float2 f[8];
        #pragma unroll
        for (int kb = 0; kb < 8; ++kb) f[kb] = G2[(8 * k8 + kb) * SG + col];
        fft8<1>(f);
        #pragma unroll
        for (int q = 0; q < 8; ++q)
            G2[(8 * k8 + q) * SG + col] = cmul(f[q], tw[2 * q * k8]);
    }
    __syncthreads();
    {   // col stepB
        int col = tid & 63, q = tid >> 6;
        float2 f[8];
        #pragma unroll
        for (int k8 = 0; k8 < 8; ++k8) f[k8] = G2[(8 * k8 + q) * SG + col];
        fft8<1>(f);
        #pragma unroll
        for (int n1 = 0; n1 < 8; ++n1) G2[(8 * n1 + q) * SG + col] = f[n1];
    }
    __syncthreads();
    {   // row stepA (inverse)
        int row = tid & 63, k8 = tid >> 6;
        float2* R = G2 + row * SG + 8 * k8;
        float2 f[8];
        #pragma unroll
        for (int kb = 0; kb < 8; ++kb) f[kb] = R[kb];
        fft8<1>(f);
        #pragma unroll
        for (int q = 0; q < 8; ++q) R[q] = cmul(f[q], tw[2 * q * k8]);
    }
    __syncthreads();
    float acc = 0.f;
    {   // FUSED64: row stepB inv -> |.| (raw) -> row stepA fwd (same cells)
        int row = tid & 63, q = tid >> 6;
        float2* R = G2 + row * SG + q;
        float2 f[8];
        #pragma unroll
        for (int k8 = 0; k8 < 8; ++k8) f[k8] = R[8 * k8];
        fft8<1>(f);
        #pragma unroll
        for (int n1 = 0; n1 < 8; ++n1) {
            float mg = sqrtf(f[n1].x * f[n1].x + f[n1].y * f[n1].y);
            acc += mg;
            f[n1] = make_float2(mg, 0.f);
        }
        fft8<-1>(f);
        #pragma unroll
        for (int ka = 0; ka < 8; ++ka)
            R[8 * ka] = cmulc(f[ka], tw[2 * q * ka]);
    }
    float ws1 = waveReduceSum(acc);
    if ((tid & 63) == 0) atomicAdd(&coeffs[b * 11 + 3], ws1 * S1_64);
    __syncthreads();
    {   // row stepB (forward)
        int row2 = tid & 63, ka = tid >> 6;
        float2* R2 = G2 + row2 * SG + 8 * ka;
        float2 g[8];
        #pragma unroll
        for (int t = 0; t < 8; ++t) g[t] = R2[t];
        fft8<-1>(g);
        #pragma unroll
        for (int kb = 0; kb < 8; ++kb) R2[kb] = g[kb];
    }
    __syncthreads();
    {   // col stepA (forward)
        int col = tid & 63, t = tid >> 6;
        float2 g[8];
        #pragma unroll
        for (int n1 = 0; n1 < 8; ++n1) g[n1] = G2[(t + 8 * n1) * SG + col];
        fft8<-1>(g);
        #pragma unroll
        for (int ka = 0; ka < 8; ++ka)
            G2[(t + 8 * ka) * SG + col] = cmulc(g[ka], tw[2 * t * ka]);
    }
    __syncthreads();
    {   // col stepB (forward) -> H32: central +-16 of V only (perm32 layout)
        int col = tid & 63, ka = tid >> 6;
        float2 g[8];
        #pragma unroll
        for (int t = 0; t < 8; ++t) g[t] = G2[(8 * ka + t) * SG + col];
        fft8<-1>(g);
        int br = col & 7, ar = col >> 3;
        if (br < 2 || br >= 6) {
            int p32row = 4 * ar + (br & 3);
            #pragma unroll
            for (int kb = 0; kb < 8; ++kb) {
                if (kb < 2 || kb >= 6)
                    H32[(4 * ka + (kb & 3)) * 32 + p32row] = g[kb];
            }
        }
    }
    __syncthreads();

    {   // ===== (2,3): ONE 32-grid 4-filter pass (R17) =====
        bool ck32 = (m < 2) || (m >= 14);
        int pc32 = 4 * (c >> 4) + ((m < 2) ? m : (m - 12));
        const float* p0 = psi + (size_t)12 * NPIX;
        const float* pq1 = p0 + NPIX;
        const float* pq2 = pq1 + NPIX;
        const float* pq3 = pq2 + NPIX;
        if (ck32) {
            #pragma unroll
            for (int i = 0; i < 2; ++i) {
                int ka = kalo + 4 * i;
                #pragma unroll
                for (int kb = 0; kb < 16; ++kb) {
                    if (kb < 2 || kb >= 14) {
                        int pr32 = 4 * ka + ((kb < 2) ? kb : (kb - 12));
                        float2 z = H32[pr32 * 32 + pc32];
                        int e = (16 * ka + kb) * NN + c;
                        float a0 = p0[e], a1 = pq1[e], a2f = pq2[e], a3 = pq3[e];
                        P4a[pr32 * SG32 + pc32] =
                            make_float4(z.x * a0, z.y * a0, z.x * a1, z.y * a1);
                        P4b[pr32 * SG32 + pc32] =
                            make_float4(z.x * a2f, z.y * a2f, z.x * a3, z.y * a3);
                    }
                }
            }
        }
        float a2 = pass32x4(P4a, P4b, tw, tid);
        float ws2 = waveReduceSum(a2);
        if ((tid & 63) == 0) atomicAdd(&coeffs[b * 11 + 5 + 5], ws2 * S2_32);
    }
}

// ---------- K_mlp: tiny MLP head (separate launch -- R12 lesson) ----------
__global__ void k_mlp(const float* __restrict__ coeffs,
                      const float* __restrict__ w1, const float* __restrict__ b1,
                      const float* __restrict__ w2, const float* __restrict__ b2,
                      float* __restrict__ out) {
    int b = threadIdx.x;
    if (b >= 64) return;
    float c[11];
    #pragma unroll
    for (int i = 0; i < 11; ++i) c[i] = coeffs[b * 11 + i];
    float h[4];
    #pragma unroll
    for (int k = 0; k < 4; ++k) {
        float s = b1[k];
        #pragma unroll
        for (int i = 0; i < 11; ++i) s += w1[k * 11 + i] * c[i];
        h[k] = fmaxf(s, 0.f);
    }
    #pragma unroll
    for (int o = 0; o < 10; ++o) {
        float s = b2[o];
        #pragma unroll
        for (int k = 0; k < 4; ++k) s += w2[o * 4 + k] * h[k];
        out[b * 10 + o] = 1.f / (1.f + expf(-s));
    }
}

extern "C" void kernel_launch(void* const* d_in, const int* in_sizes, int n_in,
                              void* d_out, int out_size, void* d_ws, size_t ws_size,
                              hipStream_t stream) {
    const float* img = (const float*)d_in[0];
    const float* w1  = (const float*)d_in[1];
    const float* b1  = (const float*)d_in[2];
    const float* w2  = (const float*)d_in[3];
    const float* b2  = (const float*)d_in[4];
    float* out = (float*)d_out;

    float*  ws     = (float*)d_ws;
    float*  psi    = ws;
    float2* ihat   = (float2*)(ws + 16 * NPIX);
    float*  coeffs = ws + 16 * NPIX + 2 * 64 * NPIX;

    hipLaunchKernelGGL(k_pre,        dim3(81),  dim3(TT), 0, stream, img, psi, ihat, coeffs);
    hipLaunchKernelGGL(k_scat_big,   dim3(256), dim3(TT), 0, stream, ihat, psi, coeffs);
    hipLaunchKernelGGL(k_scat_small, dim3(768), dim3(TT), 0, stream, ihat, psi, coeffs);
    hipLaunchKernelGGL(k_mlp,        dim3(1),   dim3(64), 0, stream, coeffs, w1, b1, w2, b2, out);
}

// Round 5
// 182.575 us; speedup vs baseline: 1.3353x; 1.0106x over previous
//
#include <hip/hip_runtime.h>
#include <math.h>

#define NN   128
#define SS   129          // LDS row stride in float2 (ODD -> conflict-free lane stride)
#define TT   512          // PROVEN: TT=512 no-spill; TT=1024 ALWAYS spills. Never 1024.
#define NPIX 16384        // 128*128
#define EPT  32           // NPIX / TT
#define SG   65           // 64-grid row stride (float2 or float4 units)
#define SG32 33           // 32-grid row stride

// R12 lesson: NO __threadfence() tail / in-kernel MLP fold (cost ~115 us).
// R14: (j1=0,j2=1) on OFF-CENTER 64x64 frequency windows. Proven absmax 0.0.
//      (far-side margin 2.28 sigma -- the precedent for R18's 2.04-2.12 sigma)
// R15: H eliminated; full-width packed passes.
// R16: j1=1 retired from the 128-grid (off-center 64-window; V = uh/4).
// R17: all j2=3 pairs on the 32-grid (pass32x4; scale ladder 2^-42/2^-40).
// R18 (this round): all j2=2 pairs on OFF-CENTER 32-windows (center bin 12,
//      sigma_f 6.37; o biased 3 bins to DC: {(9,0),(6,6),(0,9),(-6,6)}).
//      j2=2 (4 float2 grids, per-l2 windows) + j2=3 (2 float4 grids, central)
//      fused into ONE 5-barrier pass32combo per j1. Scales unchanged:
//      (0,2)=(0,3)=2^-42, (1,2)=(1,3)=2^-40.

__device__ __forceinline__ float2 cmul(float2 a, float2 w) {
    return make_float2(a.x * w.x - a.y * w.y, a.x * w.y + a.y * w.x);
}
__device__ __forceinline__ float2 cmulc(float2 a, float2 w) {   // a * conj(w)
    return make_float2(a.x * w.x + a.y * w.y, a.y * w.x - a.x * w.y);
}

// ---------- register FFT codelets (fft4/fft8/fft16 verified R2-R17) ----------
template<int SGN>
__device__ __forceinline__ void fft4(float2* f) {
    float2 t0 = make_float2(f[0].x + f[2].x, f[0].y + f[2].y);
    float2 t1 = make_float2(f[0].x - f[2].x, f[0].y - f[2].y);
    float2 t2 = make_float2(f[1].x + f[3].x, f[1].y + f[3].y);
    float2 t3 = make_float2(f[1].x - f[3].x, f[1].y - f[3].y);
    float2 t3i = (SGN > 0) ? make_float2(-t3.y, t3.x) : make_float2(t3.y, -t3.x);
    f[0] = make_float2(t0.x + t2.x, t0.y + t2.y);
    f[1] = make_float2(t1.x + t3i.x, t1.y + t3i.y);
    f[2] = make_float2(t0.x - t2.x, t0.y - t2.y);
    f[3] = make_float2(t1.x - t3i.x, t1.y - t3i.y);
}

template<int SGN>
__device__ __forceinline__ void fft8(float2* f) {
    const float R = 0.70710678118654752f;
    const float WC[4] = {1.f, R, 0.f, -R};
    const float WS[4] = {0.f, R, 1.f, R};
    #pragma unroll
    for (int stage = 0; stage < 3; ++stage) {
        const int L = 8 >> stage, half = L >> 1, step = 1 << stage;
        #pragma unroll
        for (int base = 0; base < 8; base += L) {
            #pragma unroll
            for (int j = 0; j < half; ++j) {
                float2 u = f[base + j], v = f[base + half + j];
                f[base + j] = make_float2(u.x + v.x, u.y + v.y);
                float dx = u.x - v.x, dy = u.y - v.y;
                const int t = j * step;
                const float wr = WC[t];
                const float wi = (SGN > 0) ? WS[t] : -WS[t];
                f[base + half + j] = make_float2(dx * wr - dy * wi, dx * wi + dy * wr);
            }
        }
    }
    float2 tmp;
    tmp = f[1]; f[1] = f[4]; f[4] = tmp;
    tmp = f[3]; f[3] = f[6]; f[6] = tmp;
}

template<int SGN>
__device__ __forceinline__ void fft16(float2* f) {
    const float WC[8] = {1.f, 0.92387953251f, 0.70710678119f, 0.38268343236f,
                         0.f, -0.38268343236f, -0.70710678119f, -0.92387953251f};
    const float WS[8] = {0.f, 0.38268343236f, 0.70710678119f, 0.92387953251f,
                         1.f, 0.92387953251f, 0.70710678119f, 0.38268343236f};
    #pragma unroll
    for (int stage = 0; stage < 4; ++stage) {
        const int L = 16 >> stage, half = L >> 1, step = 1 << stage;
        #pragma unroll
        for (int base = 0; base < 16; base += L) {
            #pragma unroll
            for (int j = 0; j < half; ++j) {
                float2 u = f[base + j], v = f[base + half + j];
                f[base + j] = make_float2(u.x + v.x, u.y + v.y);
                float dx = u.x - v.x, dy = u.y - v.y;
                const int t = j * step;
                const float wr = WC[t];
                const float wi = (SGN > 0) ? WS[t] : -WS[t];
                f[base + half + j] = make_float2(dx * wr - dy * wi, dx * wi + dy * wr);
            }
        }
    }
    float2 tmp;
    tmp = f[1];  f[1]  = f[8];  f[8]  = tmp;
    tmp = f[2];  f[2]  = f[4];  f[4]  = tmp;
    tmp = f[3];  f[3]  = f[12]; f[12] = tmp;
    tmp = f[5];  f[5]  = f[10]; f[10] = tmp;
    tmp = f[7];  f[7]  = f[14]; f[14] = tmp;
    tmp = f[11]; f[11] = f[13]; f[13] = tmp;
}

__device__ __forceinline__ float waveReduceSum(float v) {
    #pragma unroll
    for (int off = 32; off > 0; off >>= 1) v += __shfl_down(v, off, 64);
    return v;
}

__device__ __forceinline__ void buildTw(float2* tw, int tid) {
    if (tid < 128) {
        float s, c;
        __sincosf((float)tid * 0.04908738521234052f, &s, &c);   // 2*pi/128
        tw[tid] = make_float2(c, s);
    }
}

// ======== 32-grid 4-filter inverse pass (R17 proven) ========
__device__ __forceinline__ float pass32x4(float4* __restrict__ P4a,
                                          float4* __restrict__ P4b,
                                          const float2* __restrict__ tw, int tid) {
    __syncthreads();
    {   // col stepA
        float4* P = (tid & 256) ? P4b : P4a;
        int line = tid & 31, a = (tid >> 5) & 7;
        float2 f0[4], f1[4];
        #pragma unroll
        for (int kb = 0; kb < 4; ++kb) {
            float4 v = P[(4 * a + kb) * SG32 + line];
            f0[kb] = make_float2(v.x, v.y); f1[kb] = make_float2(v.z, v.w);
        }
        fft4<1>(f0); fft4<1>(f1);
        #pragma unroll
        for (int t = 0; t < 4; ++t) {
            float2 w = tw[4 * t * a];
            float2 aa = cmul(f0[t], w), d = cmul(f1[t], w);
            P[(4 * a + t) * SG32 + line] = make_float4(aa.x, aa.y, d.x, d.y);
        }
    }
    __syncthreads();
    if (tid < 256) {   // col stepB
        float4* P = (tid & 128) ? P4b : P4a;
        int line = tid & 31, t = (tid >> 5) & 3;
        float2 f0[8], f1[8];
        #pragma unroll
        for (int a = 0; a < 8; ++a) {
            float4 v = P[(4 * a + t) * SG32 + line];
            f0[a] = make_float2(v.x, v.y); f1[a] = make_float2(v.z, v.w);
        }
        fft8<1>(f0); fft8<1>(f1);
        #pragma unroll
        for (int n1 = 0; n1 < 8; ++n1)
            P[(4 * n1 + t) * SG32 + line] =
                make_float4(f0[n1].x, f0[n1].y, f1[n1].x, f1[n1].y);
    }
    __syncthreads();
    {   // row stepA
        float4* P = (tid & 256) ? P4b : P4a;
        int row = tid & 31, a = (tid >> 5) & 7;
        float4* R = P + row * SG32 + 4 * a;
        float2 f0[4], f1[4];
        #pragma unroll
        for (int kb = 0; kb < 4; ++kb) {
            float4 v = R[kb];
            f0[kb] = make_float2(v.x, v.y); f1[kb] = make_float2(v.z, v.w);
        }
        fft4<1>(f0); fft4<1>(f1);
        #pragma unroll
        for (int t = 0; t < 4; ++t) {
            float2 w = tw[4 * t * a];
            float2 aa = cmul(f0[t], w), d = cmul(f1[t], w);
            R[t] = make_float4(aa.x, aa.y, d.x, d.y);
        }
    }
    __syncthreads();
    float a2 = 0.f;
    if (tid < 256) {   // row stepB + mag
        float4* P = (tid & 128) ? P4b : P4a;
        int row = tid & 31, t = (tid >> 5) & 3;
        float4* R = P + row * SG32 + t;
        float2 f0[8], f1[8];
        #pragma unroll
        for (int a = 0; a < 8; ++a) {
            float4 v = R[4 * a];
            f0[a] = make_float2(v.x, v.y); f1[a] = make_float2(v.z, v.w);
        }
        fft8<1>(f0); fft8<1>(f1);
        #pragma unroll
        for (int n1 = 0; n1 < 8; ++n1) {
            a2 += sqrtf(f0[n1].x * f0[n1].x + f0[n1].y * f0[n1].y);
            a2 += sqrtf(f1[n1].x * f1[n1].x + f1[n1].y * f1[n1].y);
        }
    }
    return a2;
}

// ======== R18: fused 8-filter 32-grid pass: 4 float2 grids (j2=2, per-l2
// off-center windows) + 2 float4 grids (j2=3, central window). 4 barriers.
// aq = sum|.| over Q grids (j2=2 coeff); ap = over P grids (j2=3 coeff).
__device__ __forceinline__ void pass32combo(float2* __restrict__ Q0, float2* __restrict__ Q1,
                                            float2* __restrict__ Q2, float2* __restrict__ Q3,
                                            float4* __restrict__ Pa, float4* __restrict__ Pb,
                                            const float2* __restrict__ tw, int tid,
                                            float& aq, float& ap) {
    __syncthreads();
    {   // col stepA: threads 0-255 {Q0,Q1,Pa}; 256-511 {Q2,Q3,Pb}
        float2* Qx = (tid & 256) ? Q2 : Q0;
        float2* Qy = (tid & 256) ? Q3 : Q1;
        float4* P  = (tid & 256) ? Pb : Pa;
        int line = tid & 31, a = (tid >> 5) & 7;
        float2 q0[4], q1[4], f0[4], f1[4];
        #pragma unroll
        for (int kb = 0; kb < 4; ++kb) {
            int o = (4 * a + kb) * SG32 + line;
            q0[kb] = Qx[o]; q1[kb] = Qy[o];
            float4 v = P[o];
            f0[kb] = make_float2(v.x, v.y); f1[kb] = make_float2(v.z, v.w);
        }
        fft4<1>(q0); fft4<1>(q1); fft4<1>(f0); fft4<1>(f1);
        #pragma unroll
        for (int t = 0; t < 4; ++t) {
            float2 w = tw[4 * t * a];
            int o = (4 * a + t) * SG32 + line;
            Qx[o] = cmul(q0[t], w); Qy[o] = cmul(q1[t], w);
            float2 aa = cmul(f0[t], w), d = cmul(f1[t], w);
            P[o] = make_float4(aa.x, aa.y, d.x, d.y);
        }
    }
    __syncthreads();
    if (tid < 256) {   // col stepB: threads 0-127 {Q0,Q1,Pa}; 128-255 {Q2,Q3,Pb}
        float2* Qx = (tid & 128) ? Q2 : Q0;
        float2* Qy = (tid & 128) ? Q3 : Q1;
        float4* P  = (tid & 128) ? Pb : Pa;
        int line = tid & 31, t = (tid >> 5) & 3;
        float2 q0[8], q1[8], f0[8], f1[8];
        #pragma unroll
        for (int a = 0; a < 8; ++a) {
            int o = (4 * a + t) * SG32 + line;
            q0[a] = Qx[o]; q1[a] = Qy[o];
            float4 v = P[o];
            f0[a] = make_float2(v.x, v.y); f1[a] = make_float2(v.z, v.w);
        }
        fft8<1>(q0); fft8<1>(q1); fft8<1>(f0); fft8<1>(f1);
        #pragma unroll
        for (int n1 = 0; n1 < 8; ++n1) {
            int o = (4 * n1 + t) * SG32 + line;
            Qx[o] = q0[n1]; Qy[o] = q1[n1];
            P[o] = make_float4(f0[n1].x, f0[n1].y, f1[n1].x, f1[n1].y);
        }
    }
    __syncthreads();
    {   // row stepA
        float2* Qx = (tid & 256) ? Q2 : Q0;
        float2* Qy = (tid & 256) ? Q3 : Q1;
        float4* P  = (tid & 256) ? Pb : Pa;
        int row = tid & 31, a = (tid >> 5) & 7;
        int base = row * SG32 + 4 * a;
        float2 q0[4], q1[4], f0[4], f1[4];
        #pragma unroll
        for (int kb = 0; kb < 4; ++kb) {
            q0[kb] = Qx[base + kb]; q1[kb] = Qy[base + kb];
            float4 v = P[base + kb];
            f0[kb] = make_float2(v.x, v.y); f1[kb] = make_float2(v.z, v.w);
        }
        fft4<1>(q0); fft4<1>(q1); fft4<1>(f0); fft4<1>(f1);
        #pragma unroll
        for (int t = 0; t < 4; ++t) {
            float2 w = tw[4 * t * a];
            Qx[base + t] = cmul(q0[t], w); Qy[base + t] = cmul(q1[t], w);
            float2 aa = cmul(f0[t], w), d = cmul(f1[t], w);
            P[base + t] = make_float4(aa.x, aa.y, d.x, d.y);
        }
    }
    __syncthreads();
    aq = 0.f; ap = 0.f;
    if (tid < 256) {   // row stepB + mag (split accumulators)
        float2* Qx = (tid & 128) ? Q2 : Q0;
        float2* Qy = (tid & 128) ? Q3 : Q1;
        float4* P  = (tid & 128) ? Pb : Pa;
        int row = tid & 31, t = (tid >> 5) & 3;
        int base = row * SG32 + t;
        float2 q0[8], q1[8], f0[8], f1[8];
        #pragma unroll
        for (int a = 0; a < 8; ++a) {
            int o = base + 4 * a;
            q0[a] = Qx[o]; q1[a] = Qy[o];
            float4 v = P[o];
            f0[a] = make_float2(v.x, v.y); f1[a] = make_float2(v.z, v.w);
        }
        fft8<1>(q0); fft8<1>(q1); fft8<1>(f0); fft8<1>(f1);
        #pragma unroll
        for (int n1 = 0; n1 < 8; ++n1) {
            aq += sqrtf(q0[n1].x * q0[n1].x + q0[n1].y * q0[n1].y);
            aq += sqrtf(q1[n1].x * q1[n1].x + q1[n1].y * q1[n1].y);
            ap += sqrtf(f0[n1].x * f0[n1].x + f0[n1].y * f0[n1].y);
            ap += sqrtf(f1[n1].x * f1[n1].x + f1[n1].y * f1[n1].y);
        }
    }
}

// ======== 128-grid sweep phases (R6-R13 proven, TT=512) ========
template<int ES, int LS>
__device__ __forceinline__ void fwdA(float2* __restrict__ F,
                                     const float2* __restrict__ tw, int tid) {
    #pragma unroll
    for (int i = 0; i < 4; ++i) {
        int u = i * TT + tid;
        int t = u >> 7, x = u & 127;
        float2* M = F + x * LS;
        float2 f[8];
        #pragma unroll
        for (int n1 = 0; n1 < 8; ++n1) f[n1] = M[(t + 16 * n1) * ES];
        fft8<-1>(f);
        #pragma unroll
        for (int ka = 0; ka < 8; ++ka)
            M[(t + 16 * ka) * ES] = cmulc(f[ka], tw[t * ka]);
    }
}

template<int ES, int LS>
__device__ __forceinline__ void fwdB(float2* __restrict__ F, int tid) {
    #pragma unroll
    for (int i = 0; i < 2; ++i) {
        int u = i * TT + tid;
        int ka = u >> 7, x = u & 127;
        float2* M = F + x * LS;
        float2 g[16];
        #pragma unroll
        for (int t = 0; t < 16; ++t) g[t] = M[(16 * ka + t) * ES];
        fft16<-1>(g);
        #pragma unroll
        for (int kb = 0; kb < 16; ++kb) M[(16 * ka + kb) * ES] = g[kb];
    }
}

__device__ __forceinline__ void fwdB_col_capture(const float2* __restrict__ F, int tid,
                                                 float2* __restrict__ uh) {
    #pragma unroll
    for (int i = 0; i < 2; ++i) {
        int u = i * TT + tid;
        int ka = u >> 7, c = u & 127;
        float2 g[16];
        #pragma unroll
        for (int t = 0; t < 16; ++t) g[t] = F[(16 * ka + t) * SS + c];
        fft16<-1>(g);
        #pragma unroll
        for (int kb = 0; kb < 16; ++kb) uh[i * 16 + kb] = g[kb];
    }
}

template<int ES, int LS>
__device__ __forceinline__ void invA(float2* __restrict__ F,
                                     const float2* __restrict__ tw, int tid) {
    #pragma unroll
    for (int i = 0; i < 2; ++i) {
        int u = i * TT + tid;
        int ka = u >> 7, x = u & 127;
        float2* M = F + x * LS;
        float2 g[16];
        #pragma unroll
        for (int kb = 0; kb < 16; ++kb) g[kb] = M[(16 * ka + kb) * ES];
        fft16<1>(g);
        #pragma unroll
        for (int t = 0; t < 16; ++t)
            M[(16 * ka + t) * ES] = cmul(g[t], tw[t * ka]);
    }
}

template<int ES, int LS>
__device__ __forceinline__ void invB(float2* __restrict__ F, int tid) {
    #pragma unroll
    for (int i = 0; i < 4; ++i) {
        int u = i * TT + tid;
        int t = u >> 7, x = u & 127;
        float2* M = F + x * LS;
        float2 f[8];
        #pragma unroll
        for (int ka = 0; ka < 8; ++ka) f[ka] = M[(16 * ka + t) * ES];
        fft8<1>(f);
        #pragma unroll
        for (int nh = 0; nh < 8; ++nh) M[(t + 16 * nh) * ES] = f[nh];
    }
}

// FUSED: inverse row stepB -> |.| (raw, acc) -> forward row stepA (same cells).
__device__ __forceinline__ void invBmag_fwdA_row(float2* __restrict__ F,
                                                 const float2* __restrict__ tw,
                                                 int tid, float& acc) {
    #pragma unroll
    for (int i = 0; i < 4; ++i) {
        int u = i * TT + tid;
        int t = u >> 7, x = u & 127;
        float2* M = F + x * SS;
        float2 f[8];
        #pragma unroll
        for (int ka = 0; ka < 8; ++ka) f[ka] = M[16 * ka + t];
        fft8<1>(f);
        #pragma unroll
        for (int nh = 0; nh < 8; ++nh) {
            float m = sqrtf(f[nh].x * f[nh].x + f[nh].y * f[nh].y);
            acc += m;
            f[nh] = make_float2(m, 0.f);
        }
        fft8<-1>(f);
        #pragma unroll
        for (int ka = 0; ka < 8; ++ka)
            M[t + 16 * ka] = cmulc(f[ka], tw[t * ka]);
    }
}

// ---------- K_pre: fused filter bank + coeff zero + i_hat FFT ----------
__global__ __attribute__((amdgpu_flat_work_group_size(TT, TT), amdgpu_waves_per_eu(2, 2)))
void k_pre(const float* __restrict__ img,
           float* __restrict__ psi,
           float2* __restrict__ ihat,
           float* __restrict__ coeffs) {
    __shared__ float2 F[NN * SS];
    __shared__ float2 tw[128];
    __shared__ float red[TT / 64];
    int blk = blockIdx.x, tid = threadIdx.x;
    if (blk >= 64) {
        if (blk == 80) {
            for (int i = tid; i < 64 * 11; i += TT)
                if (i % 11 != 0) coeffs[i] = 0.f;
            return;
        }
        int f = blk - 64;
        int j = f >> 2, l = f & 3;
        float k0    = 2.35619449019234493f / (float)(1 << j);
        float sigma = 0.8f * (float)(1 << j);
        float s2    = sigma * sigma;
        float theta = 0.78539816339744831f * (float)l;
        float k0x = k0 * cosf(theta);
        float k0y = k0 * sinf(theta);
        float beta = expf(-0.5f * s2 * k0 * k0);
        const float FSTEP = 0.04908738521234052f;
        float* dst = psi + (size_t)f * NPIX;
        for (int i = tid; i < NPIX; i += TT) {
            int pr = i >> 7, pc = i & 127;
            int kr = (pr >> 4) + 8 * (pr & 15);
            int kc = (pc >> 4) + 8 * (pc & 15);
            float fr = (float)(kr < 64 ? kr : kr - 128) * FSTEP;
            float fc = (float)(kc < 64 ? kc : kc - 128) * FSTEP;
            float dx = fr - k0x, dy = fc - k0y;
            float g1 = expf(-0.5f * s2 * (dx * dx + dy * dy));
            float g0 = expf(-0.5f * s2 * (fr * fr + fc * fc));
            dst[i] = g1 - beta * g0;
        }
        return;
    }
    int b = blk;
    buildTw(tw, tid);
    const float* im = img + (size_t)b * NPIX;
    float acc = 0.f;
    #pragma unroll
    for (int k = 0; k < EPT; ++k) {
        int e = k * TT + tid;
        float v = im[e];
        acc += v;
        F[(e >> 7) * SS + (e & 127)] = make_float2(v, 0.f);
    }
    float ws = waveReduceSum(acc);
    if ((tid & 63) == 0) red[tid >> 6] = ws;
    __syncthreads();
    if (tid == 0) {
        float t = 0.f;
        #pragma unroll
        for (int w = 0; w < TT / 64; ++w) t += red[w];
        coeffs[b * 11 + 0] = t * (1.f / 16384.f);
    }
    fwdA<1, SS>(F, tw, tid);  __syncthreads();
    fwdB<1, SS>(F, tid);      __syncthreads();
    fwdA<SS, 1>(F, tw, tid);  __syncthreads();
    float2 uh[32];
    fwdB_col_capture(F, tid, uh);
    float2* dst = ihat + (size_t)b * NPIX;
    #pragma unroll
    for (int i = 0; i < 2; ++i) {
        int u = i * TT + tid;
        int ka = u >> 7, c = u & 127;
        #pragma unroll
        for (int kb = 0; kb < 16; ++kb)
            dst[(16 * ka + kb) * NN + c] = uh[i * 16 + kb];
    }
}

// ---------- K_scat_big: j1 = 0 ONLY (grid 256 = one round) ----------
__global__ __attribute__((amdgpu_flat_work_group_size(TT, TT), amdgpu_waves_per_eu(2, 2)))
void k_scat_big(const float2* __restrict__ ihat,
                const float* __restrict__ psi,
                float* __restrict__ coeffs) {
    // F: 16640 float2 = 133,120 B.
    //   128-grid phases: F[0..16512) stride SS.
    //   j2=1 one-pass: G2a..G2d = F + {0,4160,8320,12480}  (4x 64x65 float2)
    //   R18 combo: Q0..Q3 = F + {0,1056,2112,3168} (float2 32x33);
    //              Pa=(float4*)(F+4224), Pb=(float4*)(F+6336)
    __shared__ __align__(16) float2 F[16640];
    __shared__ float2 tw[128];
    float2* G2a = F;
    float2* G2b = F + 4160;
    float2* G2c = F + 8320;
    float2* G2d = F + 12480;
    float2* Q0 = F;
    float2* Q1 = F + 1056;
    float2* Q2 = F + 2112;
    float2* Q3 = F + 3168;
    float4* Pa = (float4*)(F + 4224);
    float4* Pb = (float4*)(F + 6336);
    int tid = threadIdx.x;
    int x = blockIdx.x;
    int b = x & 63, l1 = x >> 6;                       // j1 == 0
    const float2* ih = ihat + (size_t)b * NPIX;
    const float*  p1 = psi + (size_t)l1 * NPIX;
    buildTw(tw, tid);

    const float S1_128 = 9.3132257461547852e-10f;   // 2^-30
    const float S2TR   = 5.6843418860808015e-14f;   // 2^-44
    const float S2_03  = 2.2737367544323206e-13f;   // 2^-42 (32-grid from uh)

    int kalo = tid >> 7, c = tid & 127;
    {
        #pragma unroll
        for (int i = 0; i < 2; ++i) {
            int ka = kalo + 4 * i;
            float2 g[16];
            #pragma unroll
            for (int kb = 0; kb < 16; ++kb) {
                int e = (16 * ka + kb) * NN + c;
                float2 z = ih[e];
                float  p = p1[e];
                g[kb] = make_float2(z.x * p, z.y * p);
            }
            fft16<1>(g);
            #pragma unroll
            for (int t = 0; t < 16; ++t)
                F[(16 * ka + t) * SS + c] = cmul(g[t], tw[t * ka]);
        }
    }
    __syncthreads();
    invB<SS, 1>(F, tid);      __syncthreads();
    invA<1, SS>(F, tw, tid);  __syncthreads();
    float acc = 0.f;
    invBmag_fwdA_row(F, tw, tid, acc);
    float ws1 = waveReduceSum(acc);
    if ((tid & 63) == 0) atomicAdd(&coeffs[b * 11 + 1], ws1 * S1_128);
    __syncthreads();
    fwdB<1, SS>(F, tid);      __syncthreads();
    fwdA<SS, 1>(F, tw, tid);  __syncthreads();
    float2 uh[32];
    fwdB_col_capture(F, tid, uh);
    __syncthreads();   // capture done -> F reusable (grids alias it)

    int m = c & 15;
    int fc = (c >> 4) + 8 * (c & 15);

    {
        // ===== (j1=0, j2=1): ONE pass, 4 off-center 64-windows (R14 mapping) =====
        const int ORW[4] = {21, 15, 0, -15};
        const int OCW[4] = { 0, 15, 21,  15};
        bool ckw[4]; int pcw[4];
        #pragma unroll
        for (int w = 0; w < 4; ++w) {
            int dc = (fc - OCW[w]) & 127;
            ckw[w] = (dc < 32) || (dc >= 96);
            int uc = (dc < 32) ? dc : (dc - 64);
            pcw[w] = 8 * (uc & 7) + (uc >> 3);
        }
        #pragma unroll
        for (int i = 0; i < 2; ++i) {
            int ka = kalo + 4 * i;
            #pragma unroll
            for (int kb = 0; kb < 16; ++kb) {
                int fr = ka + 8 * kb;
                float2 z = uh[i * 16 + kb];
                int e = (16 * ka + kb) * NN + c;
                #pragma unroll
                for (int w = 0; w < 4; ++w) {
                    if (ckw[w]) {
                        int dr = (fr - ORW[w]) & 127;
                        if (dr < 32 || dr >= 96) {
                            int ur = (dr < 32) ? dr : (dr - 64);
                            int pr = 8 * (ur & 7) + (ur >> 3);
                            float pv = psi[(size_t)(4 + w) * NPIX + e];
                            float2* G = (w == 0) ? G2a : (w == 1) ? G2b
                                       : (w == 2) ? G2c : G2d;
                            G[pr * SG + pcw[w]] = make_float2(z.x * pv, z.y * pv);
                        }
                    }
                }
            }
        }
        __syncthreads();
        {   // col stepA (4 grids, full width)
            int col = tid & 63, k8 = tid >> 6;
            float2 f0[8], f1[8], f2[8], f3[8];
            #pragma unroll
            for (int kb = 0; kb < 8; ++kb) {
                int o = (8 * k8 + kb) * SG + col;
                f0[kb] = G2a[o]; f1[kb] = G2b[o]; f2[kb] = G2c[o]; f3[kb] = G2d[o];
            }
            fft8<1>(f0); fft8<1>(f1); fft8<1>(f2); fft8<1>(f3);
            #pragma unroll
            for (int q = 0; q < 8; ++q) {
                float2 w = tw[2 * q * k8];
                int o = (8 * k8 + q) * SG + col;
                G2a[o] = cmul(f0[q], w); G2b[o] = cmul(f1[q], w);
                G2c[o] = cmul(f2[q], w); G2d[o] = cmul(f3[q], w);
            }
        }
        __syncthreads();
        {   // col stepB
            int col = tid & 63, q = tid >> 6;
            float2 f0[8], f1[8], f2[8], f3[8];
            #pragma unroll
            for (int k8 = 0; k8 < 8; ++k8) {
                int o = (8 * k8 + q) * SG + col;
                f0[k8] = G2a[o]; f1[k8] = G2b[o]; f2[k8] = G2c[o]; f3[k8] = G2d[o];
            }
            fft8<1>(f0); fft8<1>(f1); fft8<1>(f2); fft8<1>(f3);
            #pragma unroll
            for (int n1 = 0; n1 < 8; ++n1) {
                int o = (8 * n1 + q) * SG + col;
                G2a[o] = f0[n1]; G2b[o] = f1[n1]; G2c[o] = f2[n1]; G2d[o] = f3[n1];
            }
        }
        __syncthreads();
        {   // row stepA
            int row = tid & 63, k8 = tid >> 6;
            int base = row * SG + 8 * k8;
            float2 f0[8], f1[8], f2[8], f3[8];
            #pragma unroll
            for (int kb = 0; kb < 8; ++kb) {
                f0[kb] = G2a[base + kb]; f1[kb] = G2b[base + kb];
                f2[kb] = G2c[base + kb]; f3[kb] = G2d[base + kb];
            }
            fft8<1>(f0); fft8<1>(f1); fft8<1>(f2); fft8<1>(f3);
            #pragma unroll
            for (int q = 0; q < 8; ++q) {
                float2 w = tw[2 * q * k8];
                G2a[base + q] = cmul(f0[q], w); G2b[base + q] = cmul(f1[q], w);
                G2c[base + q] = cmul(f2[q], w); G2d[base + q] = cmul(f3[q], w);
            }
        }
        __syncthreads();
        float a2 = 0.f;
        {   // row stepB + mag (all 4 -> same coeff)
            int row = tid & 63, q = tid >> 6;
            int base = row * SG + q;
            float2 f0[8], f1[8], f2[8], f3[8];
            #pragma unroll
            for (int k8 = 0; k8 < 8; ++k8) {
                int o = base + 8 * k8;
                f0[k8] = G2a[o]; f1[k8] = G2b[o]; f2[k8] = G2c[o]; f3[k8] = G2d[o];
            }
            fft8<1>(f0); fft8<1>(f1); fft8<1>(f2); fft8<1>(f3);
            #pragma unroll
            for (int n1 = 0; n1 < 8; ++n1) {
                a2 += sqrtf(f0[n1].x * f0[n1].x + f0[n1].y * f0[n1].y);
                a2 += sqrtf(f1[n1].x * f1[n1].x + f1[n1].y * f1[n1].y);
                a2 += sqrtf(f2[n1].x * f2[n1].x + f2[n1].y * f2[n1].y);
                a2 += sqrtf(f3[n1].x * f3[n1].x + f3[n1].y * f3[n1].y);
            }
        }
        float ws2 = waveReduceSum(a2);
        if ((tid & 63) == 0) atomicAdd(&coeffs[b * 11 + 5 + 0], ws2 * S2TR);
        __syncthreads();
    }

    {   // ===== (0,2)+(0,3): fused 32-grid combo pass (R18) =====
        // (0,2): off-center windows o = {(9,0),(6,6),(0,9),(-6,6)} (bias 3 to DC)
        // (0,3): central +-16 (proven R17 predicate)
        const int OR2[4] = {9, 6, 0, -6};
        const int OC2[4] = {0, 6, 9,  6};
        bool ckq[4]; int pcq[4];
        #pragma unroll
        for (int w = 0; w < 4; ++w) {
            int dc = (fc - OC2[w]) & 127;
            ckq[w] = (dc < 16) || (dc >= 112);
            int f32c = (dc < 16) ? dc : (dc - 96);
            pcq[w] = 4 * (f32c & 7) + (f32c >> 3);
        }
        bool ck32 = (m < 2) || (m >= 14);
        int pc32 = 4 * (c >> 4) + ((m < 2) ? m : (m - 12));
        const float* p30 = psi + (size_t)12 * NPIX;
        #pragma unroll
        for (int i = 0; i < 2; ++i) {
            int ka = kalo + 4 * i;
            #pragma unroll
            for (int kb = 0; kb < 16; ++kb) {
                int fr = ka + 8 * kb;
                float2 z = uh[i * 16 + kb];
                int e = (16 * ka + kb) * NN + c;
                #pragma unroll
                for (int w = 0; w < 4; ++w) {
                    if (ckq[w]) {
                        int dr = (fr - OR2[w]) & 127;
                        if (dr < 16 || dr >= 112) {
                            int f32r = (dr < 16) ? dr : (dr - 96);
                            int pr = 4 * (f32r & 7) + (f32r >> 3);
                            float pv = psi[(size_t)(8 + w) * NPIX + e];
                            float2* Q = (w == 0) ? Q0 : (w == 1) ? Q1
                                       : (w == 2) ? Q2 : Q3;
                            Q[pr * SG32 + pcq[w]] = make_float2(z.x * pv, z.y * pv);
                        }
                    }
                }
                if (ck32 && (kb < 2 || kb >= 14)) {
                    int pr32 = 4 * ka + ((kb < 2) ? kb : (kb - 12));
                    float a0 = p30[e], a1 = p30[NPIX + e];
                    float a2f = p30[2 * NPIX + e], a3 = p30[3 * NPIX + e];
                    Pa[pr32 * SG32 + pc32] =
                        make_float4(z.x * a0, z.y * a0, z.x * a1, z.y * a1);
                    Pb[pr32 * SG32 + pc32] =
                        make_float4(z.x * a2f, z.y * a2f, z.x * a3, z.y * a3);
                }
            }
        }
        float aq, ap;
        pass32combo(Q0, Q1, Q2, Q3, Pa, Pb, tw, tid, aq, ap);
        float wsq = waveReduceSum(aq);
        float wsp = waveReduceSum(ap);
        if ((tid & 63) == 0) {
            atomicAdd(&coeffs[b * 11 + 5 + 1], wsq * S2_03);
            atomicAdd(&coeffs[b * 11 + 5 + 2], wsp * S2_03);
        }
    }
}

// ---------- K_scat_small: j1 in {1,2,3} -- 67.6 KB LDS => 2 blocks/CU ----------
__global__ __attribute__((amdgpu_flat_work_group_size(TT, TT), amdgpu_waves_per_eu(4, 4)))
void k_scat_small(const float2* __restrict__ ihat,
                  const float* __restrict__ psi,
                  float* __restrict__ coeffs) {
    // S: 8448 float2 = 67,584 B.
    //   G2 (64x65 float2) = S[0..4160); H32 = S[6144..7168) (j1=2 path);
    //   j1=2 (2,3): P4a=(float4*)S [0..2112), P4b=+1056 [2112..4224) (R17);
    //   j1=1 combo: Qs0..Qs3 = S+{0,1056,2112,3168}; Psa=(float4*)(S+4224),
    //               Psb=(float4*)(S+6336)  (R18);
    //   G32 (32x33 float2) aliases S[0..) (j1=3 first order).
    __shared__ __align__(16) float2 S[8448];
    __shared__ float2 tw[128];
    float2* G2  = S;
    float2* G32 = S;
    float4* P4a = (float4*)S;
    float4* P4b = (float4*)S + 1056;
    float2* Qs0 = S;
    float2* Qs1 = S + 1056;
    float2* Qs2 = S + 2112;
    float2* Qs3 = S + 3168;
    float4* Psa = (float4*)(S + 4224);
    float4* Psb = (float4*)(S + 6336);
    float2* H32 = S + 6144;
    int tid = threadIdx.x;
    int x = blockIdx.x;
    int b = x & 63, l1 = (x >> 6) & 3;
    int t0 = x >> 8;                          // 0 -> j1=1 (heavy, first), 1 -> j1=2, 2 -> j1=3
    int j1 = (t0 == 0) ? 1 : (t0 + 1);
    const float2* ih = ihat + (size_t)b * NPIX;
    const float*  p1 = psi + (size_t)(j1 * 4 + l1) * NPIX;
    buildTw(tw, tid);

    const float S1_64 = 3.7252902984619141e-9f;    // 2^-28
    const float S1_32 = 1.4901161193847656e-8f;    // 2^-26
    const float S2_32 = 9.0949470177292824e-13f;   // 2^-40 (32-grid from V)

    int kalo = tid >> 7, c = tid & 127;

    if (t0 == 0) {
        // =========== j1 = 1 on off-center 64-window (R16) ===========
        const int OR1[4] = {21, 15, 0, -15};
        const int OC1[4] = { 0, 15, 21,  15};
        int fc = (c >> 4) + 8 * (c & 15);
        int dc = (fc - OC1[l1]) & 127;
        bool ck = (dc < 32) || (dc >= 96);
        int ucw = (dc < 32) ? dc : (dc - 64);
        int pcd = 8 * (ucw & 7) + (ucw >> 3);
        if (ck) {
            #pragma unroll
            for (int i = 0; i < 2; ++i) {
                int ka = kalo + 4 * i;
                #pragma unroll
                for (int kb = 0; kb < 16; ++kb) {
                    int fr = ka + 8 * kb;
                    int dr = (fr - OR1[l1]) & 127;
                    if (dr < 32 || dr >= 96) {
                        int ur = (dr < 32) ? dr : (dr - 64);
                        int pr = 8 * (ur & 7) + (ur >> 3);
                        int e = (16 * ka + kb) * NN + c;
                        float2 z = ih[e];
                        float  p = p1[e];
                        G2[pr * SG + pcd] = make_float2(z.x * p, z.y * p);
                    }
                }
            }
        }
        __syncthreads();
        {   // col stepA (inverse)
            int col = tid & 63, k8 = tid >> 6;
            float2 f[8];
            #pragma unroll
            for (int kb = 0; kb < 8; ++kb) f[kb] = G2[(8 * k8 + kb) * SG + col];
            fft8<1>(f);
            #pragma unroll
            for (int q = 0; q < 8; ++q)
                G2[(8 * k8 + q) * SG + col] = cmul(f[q], tw[2 * q * k8]);
        }
        __syncthreads();
        {   // col stepB
            int col = tid & 63, q = tid >> 6;
            float2 f[8];
            #pragma unroll
            for (int k8 = 0; k8 < 8; ++k8) f[k8] = G2[(8 * k8 + q) * SG + col];
            fft8<1>(f);
            #pragma unroll
            for (int n1 = 0; n1 < 8; ++n1) G2[(8 * n1 + q) * SG + col] = f[n1];
        }
        __syncthreads();
        {   // row stepA (inverse)
            int row = tid & 63, k8 = tid >> 6;
            float2* R = G2 + row * SG + 8 * k8;
            float2 f[8];
            #pragma unroll
            for (int kb = 0; kb < 8; ++kb) f[kb] = R[kb];
            fft8<1>(f);
            #pragma unroll
            for (int q = 0; q < 8; ++q) R[q] = cmul(f[q], tw[2 * q * k8]);
        }
        __syncthreads();
        float acc = 0.f;
        {   // FUSED64: row stepB inv -> |.| -> row stepA fwd
            int row = tid & 63, q = tid >> 6;
            float2* R = G2 + row * SG + q;
            float2 f[8];
            #pragma unroll
            for (int k8 = 0; k8 < 8; ++k8) f[k8] = R[8 * k8];
            fft8<1>(f);
            #pragma unroll
            for (int n1 = 0; n1 < 8; ++n1) {
                float mg = sqrtf(f[n1].x * f[n1].x + f[n1].y * f[n1].y);
                acc += mg;
                f[n1] = make_float2(mg, 0.f);
            }
            fft8<-1>(f);
            #pragma unroll
            for (int ka = 0; ka < 8; ++ka)
                R[8 * ka] = cmulc(f[ka], tw[2 * q * ka]);
        }
        float ws1 = waveReduceSum(acc);
        if ((tid & 63) == 0) atomicAdd(&coeffs[b * 11 + 2], ws1 * S1_64);
        __syncthreads();
        {   // row stepB (forward)
            int row2 = tid & 63, ka = tid >> 6;
            float2* R2 = G2 + row2 * SG + 8 * ka;
            float2 g[8];
            #pragma unroll
            for (int t = 0; t < 8; ++t) g[t] = R2[t];
            fft8<-1>(g);
            #pragma unroll
            for (int kb = 0; kb < 8; ++kb) R2[kb] = g[kb];
        }
        __syncthreads();
        {   // col stepA (forward)
            int col = tid & 63, t = tid >> 6;
            float2 g[8];
            #pragma unroll
            for (int n1 = 0; n1 < 8; ++n1) g[n1] = G2[(t + 8 * n1) * SG + col];
            fft8<-1>(g);
            #pragma unroll
            for (int ka = 0; ka < 8; ++ka)
                G2[(t + 8 * ka) * SG + col] = cmulc(g[ka], tw[2 * t * ka]);
        }
        __syncthreads();
        float2 vh[8];
        int c6 = tid & 63, ka8 = tid >> 6;
        {   // col stepB (forward) -> V = u1hat_64 captured to registers
            float2 g[8];
            #pragma unroll
            for (int t = 0; t < 8; ++t) g[t] = G2[(8 * ka8 + t) * SG + c6];
            fft8<-1>(g);
            #pragma unroll
            for (int kb = 0; kb < 8; ++kb) vh[kb] = g[kb];
        }
        __syncthreads();   // G2 reads done -> combo grids (aliases) safe to write

        // psi gather indices: 64-grid storage p <-> freq u = 8*(p&7)+(p>>3);
        // 128-freq f128 = u<32 ? u : u+64; storage s = 16*(f128&7)+(f128>>3)
        int uc64 = 8 * (c6 & 7) + (c6 >> 3);
        int fc128 = (uc64 < 32) ? uc64 : (uc64 + 64);
        int scI = 16 * (fc128 & 7) + (fc128 >> 3);
        int se[8];
        #pragma unroll
        for (int kb = 0; kb < 8; ++kb) {
            int ur = 8 * kb + ka8;
            int fr128 = (ur < 32) ? ur : (ur + 64);
            se[kb] = (16 * (fr128 & 7) + (fr128 >> 3)) * NN + scI;
        }

        {   // ===== (1,2)+(1,3): fused 32-grid combo pass (R18) =====
            // (1,2): off-center windows on 64-freq (same o's as big's (0,2))
            // (1,3): central +-16 of V (proven R17 predicates)
            const int OR2[4] = {9, 6, 0, -6};
            const int OC2[4] = {0, 6, 9,  6};
            bool ckq[4]; int pcq[4];
            #pragma unroll
            for (int w = 0; w < 4; ++w) {
                int dcw = (uc64 - OC2[w]) & 63;
                ckq[w] = (dcw < 16) || (dcw >= 48);
                int f32c = (dcw < 16) ? dcw : (dcw - 32);
                pcq[w] = 4 * (f32c & 7) + (f32c >> 3);
            }
            int m6 = c6 & 7;
            bool ckV = (m6 < 2) || (m6 >= 6);
            int p32c = 4 * (c6 >> 3) + ((m6 < 2) ? m6 : (m6 - 4));
            const float* p30 = psi + (size_t)12 * NPIX;
            #pragma unroll
            for (int kb = 0; kb < 8; ++kb) {
                int ur = 8 * kb + ka8;
                float2 z = vh[kb];
                int e = se[kb];
                #pragma unroll
                for (int w = 0; w < 4; ++w) {
                    if (ckq[w]) {
                        int dr = (ur - OR2[w]) & 63;
                        if (dr < 16 || dr >= 48) {
                            int f32r = (dr < 16) ? dr : (dr - 32);
                            int pr = 4 * (f32r & 7) + (f32r >> 3);
                            float pv = psi[(size_t)(8 + w) * NPIX + e];
                            float2* Q = (w == 0) ? Qs0 : (w == 1) ? Qs1
                                       : (w == 2) ? Qs2 : Qs3;
                            Q[pr * SG32 + pcq[w]] = make_float2(z.x * pv, z.y * pv);
                        }
                    }
                }
                if (ckV && (kb < 2 || kb >= 6)) {
                    int pr32 = 4 * ka8 + (kb & 3);
                    float a0 = p30[e], a1 = p30[NPIX + e];
                    float a2f = p30[2 * NPIX + e], a3 = p30[3 * NPIX + e];
                    Psa[pr32 * SG32 + p32c] =
                        make_float4(z.x * a0, z.y * a0, z.x * a1, z.y * a1);
                    Psb[pr32 * SG32 + p32c] =
                        make_float4(z.x * a2f, z.y * a2f, z.x * a3, z.y * a3);
                }
            }
            float aq, ap;
            pass32combo(Qs0, Qs1, Qs2, Qs3, Psa, Psb, tw, tid, aq, ap);
            float wsq = waveReduceSum(aq);
            float wsp = waveReduceSum(ap);
            if ((tid & 63) == 0) {
                atomicAdd(&coeffs[b * 11 + 5 + 3], wsq * S2_32);
                atomicAdd(&coeffs[b * 11 + 5 + 4], wsp * S2_32);
            }
        }
        return;
    }

    if (t0 == 2) {
        // ===== j1=3: 32-grid first order (psi_{j1=3} support +-16) =====
        int m = c & 15;
        bool ck32 = (m < 2) || (m >= 14);
        int pc32 = 4 * (c >> 4) + ((m < 2) ? m : (m - 12));
        if (ck32) {
            #pragma unroll
            for (int i = 0; i < 2; ++i) {
                int ka = kalo + 4 * i;
                #pragma unroll
                for (int kb = 0; kb < 16; ++kb) {
                    if (kb < 2 || kb >= 14) {
                        int e = (16 * ka + kb) * NN + c;
                        float2 z = ih[e];
                        float  p = p1[e];
                        int pr32 = 4 * ka + ((kb < 2) ? kb : (kb - 12));
                        G32[pr32 * SG32 + pc32] = make_float2(z.x * p, z.y * p);
                    }
                }
            }
        }
        __syncthreads();
        if (tid < 256) {   // col stepA: fft4 over b per a (32 lines x 8 a)
            int line = tid & 31, a = tid >> 5;
            float2 f[4];
            #pragma unroll
            for (int kb = 0; kb < 4; ++kb) f[kb] = G32[(4 * a + kb) * SG32 + line];
            fft4<1>(f);
            #pragma unroll
            for (int t = 0; t < 4; ++t)
                G32[(4 * a + t) * SG32 + line] = cmul(f[t], tw[4 * t * a]);
        }
        __syncthreads();
        if (tid < 128) {   // col stepB: fft8 over a per t (32 lines x 4 t)
            int line = tid & 31, t = tid >> 5;
            float2 f[8];
            #pragma unroll
            for (int a = 0; a < 8; ++a) f[a] = G32[(4 * a + t) * SG32 + line];
            fft8<1>(f);
            #pragma unroll
            for (int n1 = 0; n1 < 8; ++n1) G32[(4 * n1 + t) * SG32 + line] = f[n1];
        }
        __syncthreads();
        if (tid < 256) {   // row stepA
            int row = tid & 31, a = tid >> 5;
            float2* R = G32 + row * SG32 + 4 * a;
            float2 f[4];
            #pragma unroll
            for (int kb = 0; kb < 4; ++kb) f[kb] = R[kb];
            fft4<1>(f);
            #pragma unroll
            for (int t = 0; t < 4; ++t) R[t] = cmul(f[t], tw[4 * t * a]);
        }
        __syncthreads();
        float acc = 0.f;
        if (tid < 128) {   // row stepB + mag
            int row = tid & 31, t = tid >> 5;
            float2* R = G32 + row * SG32 + t;
            float2 f[8];
            #pragma unroll
            for (int a = 0; a < 8; ++a) f[a] = R[4 * a];
            fft8<1>(f);
            #pragma unroll
            for (int n1 = 0; n1 < 8; ++n1)
                acc += sqrtf(f[n1].x * f[n1].x + f[n1].y * f[n1].y);
        }
        float ws1 = waveReduceSum(acc);
        if ((tid & 63) == 0 && tid < 128) atomicAdd(&coeffs[b * 11 + 4], ws1 * S1_32);
        return;
    }

    // ===================== j1 == 2: 64-grid first order (R13-proven) ==============
    int m = c & 15;
    bool colKeep = (m < 4) || (m >= 12);
    if (colKeep) {
        #pragma unroll
        for (int i = 0; i < 2; ++i) {
            int ka = kalo + 4 * i;
            #pragma unroll
            for (int kb = 0; kb < 16; ++kb) {
                if (kb < 4 || kb >= 12) {
                    int e = (16 * ka + kb) * NN + c;
                    float2 z = ih[e];
                    float  p = p1[e];
                    int pr64 = 8 * ka + ((kb < 4) ? kb : (kb - 8));
                    int pc64 = 8 * (c >> 4) + ((m < 4) ? m : (m - 8));
                    G2[pr64 * SG + pc64] = make_float2(z.x * p, z.y * p);
                }
            }
        }
    }
    __syncthreads();
    {   // col stepA (inverse)
        int col = tid & 63, k8 = tid >> 6;
        float2 f[8];
        #pragma unroll
        for (int kb = 0; kb < 8; ++kb) f[kb] = G2[(8 * k8 + kb) * SG + col];
        fft8<1>(f);
        #pragma unroll
        for (int q = 0; q < 8; ++q)
            G2[(8 * k8 + q) * SG + col] = cmul(f[q], tw[2 * q * k8]);
    }
    __syncthreads();
    {   // col stepB
        int col = tid & 63, q = tid >> 6;
        float2 f[8];
        #pragma unroll
        for (int k8 = 0; k8 < 8; ++k8) f[k8] = G2[(8 * k8 + q) * SG + col];
        fft8<1>(f);
        #pragma unroll
        for (int n1 = 0; n1 < 8; ++n1) G2[(8 * n1 + q) * SG + col] = f[n1];
    }
    __syncthreads();
    {   // row stepA (inverse)
        int row = tid & 63, k8 = tid >> 6;
        float2* R = G2 + row * SG + 8 * k8;
        float2 f[8];
        #pragma unroll
        for (int kb = 0; kb < 8; ++kb) f[kb] = R[kb];
        fft8<1>(f);
        #pragma unroll
        for (int q = 0; q < 8; ++q) R[q] = cmul(f[q], tw[2 * q * k8]);
    }
    __syncthreads();
    float acc = 0.f;
    {   // FUSED64: row stepB inv -> |.| (raw) -> row stepA fwd (same cells)
        int row = tid & 63, q = tid >> 6;
        float2* R = G2 + row * SG + q;
        float2 f[8];
        #pragma unroll
        for (int k8 = 0; k8 < 8; ++k8) f[k8] = R[8 * k8];
        fft8<1>(f);
        #pragma unroll
        for (int n1 = 0; n1 < 8; ++n1) {
            float mg = sqrtf(f[n1].x * f[n1].x + f[n1].y * f[n1].y);
            acc += mg;
            f[n1] = make_float2(mg, 0.f);
        }
        fft8<-1>(f);
        #pragma unroll
        for (int ka = 0; ka < 8; ++ka)
            R[8 * ka] = cmulc(f[ka], tw[2 * q * ka]);
    }
    float ws1 = waveReduceSum(acc);
    if ((tid & 63) == 0) atomicAdd(&coeffs[b * 11 + 3], ws1 * S1_64);
    __syncthreads();
    {   // row stepB (forward)
        int row2 = tid & 63, ka = tid >> 6;
        float2* R2 = G2 + row2 * SG + 8 * ka;
        float2 g[8];
        #pragma unroll
        for (int t = 0; t < 8; ++t) g[t] = R2[t];
        fft8<-1>(g);
        #pragma unroll
        for (int kb = 0; kb < 8; ++kb) R2[kb] = g[kb];
    }
    __syncthreads();
    {   // col stepA (forward)
        int col = tid & 63, t = tid >> 6;
        float2 g[8];
        #pragma unroll
        for (int n1 = 0; n1 < 8; ++n1) g[n1] = G2[(t + 8 * n1) * SG + col];
        fft8<-1>(g);
        #pragma unroll
        for (int ka = 0; ka < 8; ++ka)
            G2[(t + 8 * ka) * SG + col] = cmulc(g[ka], tw[2 * t * ka]);
    }
    __syncthreads();
    {   // col stepB (forward) -> H32: central +-16 of V only (perm32 layout)
        int col = tid & 63, ka = tid >> 6;
        float2 g[8];
        #pragma unroll
        for (int t = 0; t < 8; ++t) g[t] = G2[(8 * ka + t) * SG + col];
        fft8<-1>(g);
        int br = col & 7, ar = col >> 3;
        if (br < 2 || br >= 6) {
            int p32row = 4 * ar + (br & 3);
            #pragma unroll
            for (int kb = 0; kb < 8; ++kb) {
                if (kb < 2 || kb >= 6)
                    H32[(4 * ka + (kb & 3)) * 32 + p32row] = g[kb];
            }
        }
    }
    __syncthreads();

    {   // ===== (2,3): ONE 32-grid 4-filter pass (R17 proven) =====
        bool ck32 = (m < 2) || (m >= 14);
        int pc32 = 4 * (c >> 4) + ((m < 2) ? m : (m - 12));
        const float* p0 = psi + (size_t)12 * NPIX;
        const float* pq1 = p0 + NPIX;
        const float* pq2 = pq1 + NPIX;
        const float* pq3 = pq2 + NPIX;
        if (ck32) {
            #pragma unroll
            for (int i = 0; i < 2; ++i) {
                int ka = kalo + 4 * i;
                #pragma unroll
                for (int kb = 0; kb < 16; ++kb) {
                    if (kb < 2 || kb >= 14) {
                        int pr32 = 4 * ka + ((kb < 2) ? kb : (kb - 12));
                        float2 z = H32[pr32 * 32 + pc32];
                        int e = (16 * ka + kb) * NN + c;
                        float a0 = p0[e], a1 = pq1[e], a2f = pq2[e], a3 = pq3[e];
                        P4a[pr32 * SG32 + pc32] =
                            make_float4(z.x * a0, z.y * a0, z.x * a1, z.y * a1);
                        P4b[pr32 * SG32 + pc32] =
                            make_float4(z.x * a2f, z.y * a2f, z.x * a3, z.y * a3);
                    }
                }
            }
        }
        float a2 = pass32x4(P4a, P4b, tw, tid);
        float ws2 = waveReduceSum(a2);
        if ((tid & 63) == 0) atomicAdd(&coeffs[b * 11 + 5 + 5], ws2 * S2_32);
    }
}

// ---------- K_mlp: tiny MLP head (separate launch -- R12 lesson) ----------
__global__ void k_mlp(const float* __restrict__ coeffs,
                      const float* __restrict__ w1, const float* __restrict__ b1,
                      const float* __restrict__ w2, const float* __restrict__ b2,
                      float* __restrict__ out) {
    int b = threadIdx.x;
    if (b >= 64) return;
    float c[11];
    #pragma unroll
    for (int i = 0; i < 11; ++i) c[i] = coeffs[b * 11 + i];
    float h[4];
    #pragma unroll
    for (int k = 0; k < 4; ++k) {
        float s = b1[k];
        #pragma unroll
        for (int i = 0; i < 11; ++i) s += w1[k * 11 + i] * c[i];
        h[k] = fmaxf(s, 0.f);
    }
    #pragma unroll
    for (int o = 0; o < 10; ++o) {
        float s = b2[o];
        #pragma unroll
        for (int k = 0; k < 4; ++k) s += w2[o * 4 + k] * h[k];
        out[b * 10 + o] = 1.f / (1.f + expf(-s));
    }
}

extern "C" void kernel_launch(void* const* d_in, const int* in_sizes, int n_in,
                              void* d_out, int out_size, void* d_ws, size_t ws_size,
                              hipStream_t stream) {
    const float* img = (const float*)d_in[0];
    const float* w1  = (const float*)d_in[1];
    const float* b1  = (const float*)d_in[2];
    const float* w2  = (const float*)d_in[3];
    const float* b2  = (const float*)d_in[4];
    float* out = (float*)d_out;

    float*  ws     = (float*)d_ws;
    float*  psi    = ws;
    float2* ihat   = (float2*)(ws + 16 * NPIX);
    float*  coeffs = ws + 16 * NPIX + 2 * 64 * NPIX;

    hipLaunchKernelGGL(k_pre,        dim3(81),  dim3(TT), 0, stream, img, psi, ihat, coeffs);
    hipLaunchKernelGGL(k_scat_big,   dim3(256), dim3(TT), 0, stream, ihat, psi, coeffs);
    hipLaunchKernelGGL(k_scat_small, dim3(768), dim3(TT), 0, stream, ihat, psi, coeffs);
    hipLaunchKernelGGL(k_mlp,        dim3(1),   dim3(64), 0, stream, coeffs, w1, b1, w2, b2, out);
}

// Round 6
// 177.262 us; speedup vs baseline: 1.3753x; 1.0300x over previous
//
#include <hip/hip_runtime.h>
#include <math.h>

#define NN   128
#define SS   129          // LDS row stride in float2 (ODD -> conflict-free lane stride)
#define TT   512          // PROVEN: TT=512 no-spill; TT=1024 ALWAYS spills. Never 1024.
#define NPIX 16384        // 128*128
#define EPT  32           // NPIX / TT
#define SG   65           // 64-grid row stride (float2 or float4 units)
#define SG32 33           // 32-grid row stride

// R12 lesson: NO __threadfence() tail / in-kernel MLP fold (cost ~115 us).
// R14: (j1=0,j2=1) on OFF-CENTER 64x64 frequency windows. Proven absmax 0.0.
// R15: H eliminated; full-width packed passes.
// R16: j1=1 retired from the 128-grid (off-center 64-window; V = uh/4).
// R17: all j2=3 pairs on the 32-grid (pass32x4; scales 2^-42/2^-40).
// R18: j2=2 pairs on off-center 32-windows. COMBO KEPT IN SMALL ONLY --
//      R5 measured big's fused staging as a 3us regression (VALUBusy 47->37:
//      divergent 4-window staging at 1 block/CU); big reverted to R4 form.
// R19 (this round): k_pre split into k_pre1 (256 row-strip blocks, FFT along c)
//      + k_pre2 (256 col-strip blocks, FFT along r + capture + s0 from DC bin).
//      Was 64 blocks on 256 CUs (75% idle). Intermediate ALIASES ihat (each
//      pre2 block fully loads its strip to LDS before any global write).

__device__ __forceinline__ float2 cmul(float2 a, float2 w) {
    return make_float2(a.x * w.x - a.y * w.y, a.x * w.y + a.y * w.x);
}
__device__ __forceinline__ float2 cmulc(float2 a, float2 w) {   // a * conj(w)
    return make_float2(a.x * w.x + a.y * w.y, a.y * w.x - a.x * w.y);
}

// ---------- register FFT codelets (fft4/fft8/fft16 verified R2-R18) ----------
template<int SGN>
__device__ __forceinline__ void fft4(float2* f) {
    float2 t0 = make_float2(f[0].x + f[2].x, f[0].y + f[2].y);
    float2 t1 = make_float2(f[0].x - f[2].x, f[0].y - f[2].y);
    float2 t2 = make_float2(f[1].x + f[3].x, f[1].y + f[3].y);
    float2 t3 = make_float2(f[1].x - f[3].x, f[1].y - f[3].y);
    float2 t3i = (SGN > 0) ? make_float2(-t3.y, t3.x) : make_float2(t3.y, -t3.x);
    f[0] = make_float2(t0.x + t2.x, t0.y + t2.y);
    f[1] = make_float2(t1.x + t3i.x, t1.y + t3i.y);
    f[2] = make_float2(t0.x - t2.x, t0.y - t2.y);
    f[3] = make_float2(t1.x - t3i.x, t1.y - t3i.y);
}

template<int SGN>
__device__ __forceinline__ void fft8(float2* f) {
    const float R = 0.70710678118654752f;
    const float WC[4] = {1.f, R, 0.f, -R};
    const float WS[4] = {0.f, R, 1.f, R};
    #pragma unroll
    for (int stage = 0; stage < 3; ++stage) {
        const int L = 8 >> stage, half = L >> 1, step = 1 << stage;
        #pragma unroll
        for (int base = 0; base < 8; base += L) {
            #pragma unroll
            for (int j = 0; j < half; ++j) {
                float2 u = f[base + j], v = f[base + half + j];
                f[base + j] = make_float2(u.x + v.x, u.y + v.y);
                float dx = u.x - v.x, dy = u.y - v.y;
                const int t = j * step;
                const float wr = WC[t];
                const float wi = (SGN > 0) ? WS[t] : -WS[t];
                f[base + half + j] = make_float2(dx * wr - dy * wi, dx * wi + dy * wr);
            }
        }
    }
    float2 tmp;
    tmp = f[1]; f[1] = f[4]; f[4] = tmp;
    tmp = f[3]; f[3] = f[6]; f[6] = tmp;
}

template<int SGN>
__device__ __forceinline__ void fft16(float2* f) {
    const float WC[8] = {1.f, 0.92387953251f, 0.70710678119f, 0.38268343236f,
                         0.f, -0.38268343236f, -0.70710678119f, -0.92387953251f};
    const float WS[8] = {0.f, 0.38268343236f, 0.70710678119f, 0.92387953251f,
                         1.f, 0.92387953251f, 0.70710678119f, 0.38268343236f};
    #pragma unroll
    for (int stage = 0; stage < 4; ++stage) {
        const int L = 16 >> stage, half = L >> 1, step = 1 << stage;
        #pragma unroll
        for (int base = 0; base < 16; base += L) {
            #pragma unroll
            for (int j = 0; j < half; ++j) {
                float2 u = f[base + j], v = f[base + half + j];
                f[base + j] = make_float2(u.x + v.x, u.y + v.y);
                float dx = u.x - v.x, dy = u.y - v.y;
                const int t = j * step;
                const float wr = WC[t];
                const float wi = (SGN > 0) ? WS[t] : -WS[t];
                f[base + half + j] = make_float2(dx * wr - dy * wi, dx * wi + dy * wr);
            }
        }
    }
    float2 tmp;
    tmp = f[1];  f[1]  = f[8];  f[8]  = tmp;
    tmp = f[2];  f[2]  = f[4];  f[4]  = tmp;
    tmp = f[3];  f[3]  = f[12]; f[12] = tmp;
    tmp = f[5];  f[5]  = f[10]; f[10] = tmp;
    tmp = f[7];  f[7]  = f[14]; f[14] = tmp;
    tmp = f[11]; f[11] = f[13]; f[13] = tmp;
}

__device__ __forceinline__ float waveReduceSum(float v) {
    #pragma unroll
    for (int off = 32; off > 0; off >>= 1) v += __shfl_down(v, off, 64);
    return v;
}

__device__ __forceinline__ void buildTw(float2* tw, int tid) {
    if (tid < 128) {
        float s, c;
        __sincosf((float)tid * 0.04908738521234052f, &s, &c);   // 2*pi/128
        tw[tid] = make_float2(c, s);
    }
}

// ======== 32-grid 4-filter inverse pass (R17 proven) ========
__device__ __forceinline__ float pass32x4(float4* __restrict__ P4a,
                                          float4* __restrict__ P4b,
                                          const float2* __restrict__ tw, int tid) {
    __syncthreads();
    {   // col stepA
        float4* P = (tid & 256) ? P4b : P4a;
        int line = tid & 31, a = (tid >> 5) & 7;
        float2 f0[4], f1[4];
        #pragma unroll
        for (int kb = 0; kb < 4; ++kb) {
            float4 v = P[(4 * a + kb) * SG32 + line];
            f0[kb] = make_float2(v.x, v.y); f1[kb] = make_float2(v.z, v.w);
        }
        fft4<1>(f0); fft4<1>(f1);
        #pragma unroll
        for (int t = 0; t < 4; ++t) {
            float2 w = tw[4 * t * a];
            float2 aa = cmul(f0[t], w), d = cmul(f1[t], w);
            P[(4 * a + t) * SG32 + line] = make_float4(aa.x, aa.y, d.x, d.y);
        }
    }
    __syncthreads();
    if (tid < 256) {   // col stepB
        float4* P = (tid & 128) ? P4b : P4a;
        int line = tid & 31, t = (tid >> 5) & 3;
        float2 f0[8], f1[8];
        #pragma unroll
        for (int a = 0; a < 8; ++a) {
            float4 v = P[(4 * a + t) * SG32 + line];
            f0[a] = make_float2(v.x, v.y); f1[a] = make_float2(v.z, v.w);
        }
        fft8<1>(f0); fft8<1>(f1);
        #pragma unroll
        for (int n1 = 0; n1 < 8; ++n1)
            P[(4 * n1 + t) * SG32 + line] =
                make_float4(f0[n1].x, f0[n1].y, f1[n1].x, f1[n1].y);
    }
    __syncthreads();
    {   // row stepA
        float4* P = (tid & 256) ? P4b : P4a;
        int row = tid & 31, a = (tid >> 5) & 7;
        float4* R = P + row * SG32 + 4 * a;
        float2 f0[4], f1[4];
        #pragma unroll
        for (int kb = 0; kb < 4; ++kb) {
            float4 v = R[kb];
            f0[kb] = make_float2(v.x, v.y); f1[kb] = make_float2(v.z, v.w);
        }
        fft4<1>(f0); fft4<1>(f1);
        #pragma unroll
        for (int t = 0; t < 4; ++t) {
            float2 w = tw[4 * t * a];
            float2 aa = cmul(f0[t], w), d = cmul(f1[t], w);
            R[t] = make_float4(aa.x, aa.y, d.x, d.y);
        }
    }
    __syncthreads();
    float a2 = 0.f;
    if (tid < 256) {   // row stepB + mag
        float4* P = (tid & 128) ? P4b : P4a;
        int row = tid & 31, t = (tid >> 5) & 3;
        float4* R = P + row * SG32 + t;
        float2 f0[8], f1[8];
        #pragma unroll
        for (int a = 0; a < 8; ++a) {
            float4 v = R[4 * a];
            f0[a] = make_float2(v.x, v.y); f1[a] = make_float2(v.z, v.w);
        }
        fft8<1>(f0); fft8<1>(f1);
        #pragma unroll
        for (int n1 = 0; n1 < 8; ++n1) {
            a2 += sqrtf(f0[n1].x * f0[n1].x + f0[n1].y * f0[n1].y);
            a2 += sqrtf(f1[n1].x * f1[n1].x + f1[n1].y * f1[n1].y);
        }
    }
    return a2;
}

// ======== R18: fused 8-filter 32-grid pass (SMALL ONLY -- see R19 note) ========
__device__ __forceinline__ void pass32combo(float2* __restrict__ Q0, float2* __restrict__ Q1,
                                            float2* __restrict__ Q2, float2* __restrict__ Q3,
                                            float4* __restrict__ Pa, float4* __restrict__ Pb,
                                            const float2* __restrict__ tw, int tid,
                                            float& aq, float& ap) {
    __syncthreads();
    {   // col stepA: threads 0-255 {Q0,Q1,Pa}; 256-511 {Q2,Q3,Pb}
        float2* Qx = (tid & 256) ? Q2 : Q0;
        float2* Qy = (tid & 256) ? Q3 : Q1;
        float4* P  = (tid & 256) ? Pb : Pa;
        int line = tid & 31, a = (tid >> 5) & 7;
        float2 q0[4], q1[4], f0[4], f1[4];
        #pragma unroll
        for (int kb = 0; kb < 4; ++kb) {
            int o = (4 * a + kb) * SG32 + line;
            q0[kb] = Qx[o]; q1[kb] = Qy[o];
            float4 v = P[o];
            f0[kb] = make_float2(v.x, v.y); f1[kb] = make_float2(v.z, v.w);
        }
        fft4<1>(q0); fft4<1>(q1); fft4<1>(f0); fft4<1>(f1);
        #pragma unroll
        for (int t = 0; t < 4; ++t) {
            float2 w = tw[4 * t * a];
            int o = (4 * a + t) * SG32 + line;
            Qx[o] = cmul(q0[t], w); Qy[o] = cmul(q1[t], w);
            float2 aa = cmul(f0[t], w), d = cmul(f1[t], w);
            P[o] = make_float4(aa.x, aa.y, d.x, d.y);
        }
    }
    __syncthreads();
    if (tid < 256) {   // col stepB
        float2* Qx = (tid & 128) ? Q2 : Q0;
        float2* Qy = (tid & 128) ? Q3 : Q1;
        float4* P  = (tid & 128) ? Pb : Pa;
        int line = tid & 31, t = (tid >> 5) & 3;
        float2 q0[8], q1[8], f0[8], f1[8];
        #pragma unroll
        for (int a = 0; a < 8; ++a) {
            int o = (4 * a + t) * SG32 + line;
            q0[a] = Qx[o]; q1[a] = Qy[o];
            float4 v = P[o];
            f0[a] = make_float2(v.x, v.y); f1[a] = make_float2(v.z, v.w);
        }
        fft8<1>(q0); fft8<1>(q1); fft8<1>(f0); fft8<1>(f1);
        #pragma unroll
        for (int n1 = 0; n1 < 8; ++n1) {
            int o = (4 * n1 + t) * SG32 + line;
            Qx[o] = q0[n1]; Qy[o] = q1[n1];
            P[o] = make_float4(f0[n1].x, f0[n1].y, f1[n1].x, f1[n1].y);
        }
    }
    __syncthreads();
    {   // row stepA
        float2* Qx = (tid & 256) ? Q2 : Q0;
        float2* Qy = (tid & 256) ? Q3 : Q1;
        float4* P  = (tid & 256) ? Pb : Pa;
        int row = tid & 31, a = (tid >> 5) & 7;
        int base = row * SG32 + 4 * a;
        float2 q0[4], q1[4], f0[4], f1[4];
        #pragma unroll
        for (int kb = 0; kb < 4; ++kb) {
            q0[kb] = Qx[base + kb]; q1[kb] = Qy[base + kb];
            float4 v = P[base + kb];
            f0[kb] = make_float2(v.x, v.y); f1[kb] = make_float2(v.z, v.w);
        }
        fft4<1>(q0); fft4<1>(q1); fft4<1>(f0); fft4<1>(f1);
        #pragma unroll
        for (int t = 0; t < 4; ++t) {
            float2 w = tw[4 * t * a];
            Qx[base + t] = cmul(q0[t], w); Qy[base + t] = cmul(q1[t], w);
            float2 aa = cmul(f0[t], w), d = cmul(f1[t], w);
            P[base + t] = make_float4(aa.x, aa.y, d.x, d.y);
        }
    }
    __syncthreads();
    aq = 0.f; ap = 0.f;
    if (tid < 256) {   // row stepB + mag (split accumulators)
        float2* Qx = (tid & 128) ? Q2 : Q0;
        float2* Qy = (tid & 128) ? Q3 : Q1;
        float4* P  = (tid & 128) ? Pb : Pa;
        int row = tid & 31, t = (tid >> 5) & 3;
        int base = row * SG32 + t;
        float2 q0[8], q1[8], f0[8], f1[8];
        #pragma unroll
        for (int a = 0; a < 8; ++a) {
            int o = base + 4 * a;
            q0[a] = Qx[o]; q1[a] = Qy[o];
            float4 v = P[o];
            f0[a] = make_float2(v.x, v.y); f1[a] = make_float2(v.z, v.w);
        }
        fft8<1>(q0); fft8<1>(q1); fft8<1>(f0); fft8<1>(f1);
        #pragma unroll
        for (int n1 = 0; n1 < 8; ++n1) {
            aq += sqrtf(q0[n1].x * q0[n1].x + q0[n1].y * q0[n1].y);
            aq += sqrtf(q1[n1].x * q1[n1].x + q1[n1].y * q1[n1].y);
            ap += sqrtf(f0[n1].x * f0[n1].x + f0[n1].y * f0[n1].y);
            ap += sqrtf(f1[n1].x * f1[n1].x + f1[n1].y * f1[n1].y);
        }
    }
}

// ======== 128-grid sweep phases (R6-R13 proven, TT=512) ========
template<int ES, int LS>
__device__ __forceinline__ void fwdA(float2* __restrict__ F,
                                     const float2* __restrict__ tw, int tid) {
    #pragma unroll
    for (int i = 0; i < 4; ++i) {
        int u = i * TT + tid;
        int t = u >> 7, x = u & 127;
        float2* M = F + x * LS;
        float2 f[8];
        #pragma unroll
        for (int n1 = 0; n1 < 8; ++n1) f[n1] = M[(t + 16 * n1) * ES];
        fft8<-1>(f);
        #pragma unroll
        for (int ka = 0; ka < 8; ++ka)
            M[(t + 16 * ka) * ES] = cmulc(f[ka], tw[t * ka]);
    }
}

template<int ES, int LS>
__device__ __forceinline__ void fwdB(float2* __restrict__ F, int tid) {
    #pragma unroll
    for (int i = 0; i < 2; ++i) {
        int u = i * TT + tid;
        int ka = u >> 7, x = u & 127;
        float2* M = F + x * LS;
        float2 g[16];
        #pragma unroll
        for (int t = 0; t < 16; ++t) g[t] = M[(16 * ka + t) * ES];
        fft16<-1>(g);
        #pragma unroll
        for (int kb = 0; kb < 16; ++kb) M[(16 * ka + kb) * ES] = g[kb];
    }
}

__device__ __forceinline__ void fwdB_col_capture(const float2* __restrict__ F, int tid,
                                                 float2* __restrict__ uh) {
    #pragma unroll
    for (int i = 0; i < 2; ++i) {
        int u = i * TT + tid;
        int ka = u >> 7, c = u & 127;
        float2 g[16];
        #pragma unroll
        for (int t = 0; t < 16; ++t) g[t] = F[(16 * ka + t) * SS + c];
        fft16<-1>(g);
        #pragma unroll
        for (int kb = 0; kb < 16; ++kb) uh[i * 16 + kb] = g[kb];
    }
}

template<int ES, int LS>
__device__ __forceinline__ void invA(float2* __restrict__ F,
                                     const float2* __restrict__ tw, int tid) {
    #pragma unroll
    for (int i = 0; i < 2; ++i) {
        int u = i * TT + tid;
        int ka = u >> 7, x = u & 127;
        float2* M = F + x * LS;
        float2 g[16];
        #pragma unroll
        for (int kb = 0; kb < 16; ++kb) g[kb] = M[(16 * ka + kb) * ES];
        fft16<1>(g);
        #pragma unroll
        for (int t = 0; t < 16; ++t)
            M[(16 * ka + t) * ES] = cmul(g[t], tw[t * ka]);
    }
}

template<int ES, int LS>
__device__ __forceinline__ void invB(float2* __restrict__ F, int tid) {
    #pragma unroll
    for (int i = 0; i < 4; ++i) {
        int u = i * TT + tid;
        int t = u >> 7, x = u & 127;
        float2* M = F + x * LS;
        float2 f[8];
        #pragma unroll
        for (int ka = 0; ka < 8; ++ka) f[ka] = M[(16 * ka + t) * ES];
        fft8<1>(f);
        #pragma unroll
        for (int nh = 0; nh < 8; ++nh) M[(t + 16 * nh) * ES] = f[nh];
    }
}

// FUSED: inverse row stepB -> |.| (raw, acc) -> forward row stepA (same cells).
__device__ __forceinline__ void invBmag_fwdA_row(float2* __restrict__ F,
                                                 const float2* __restrict__ tw,
                                                 int tid, float& acc) {
    #pragma unroll
    for (int i = 0; i < 4; ++i) {
        int u = i * TT + tid;
        int t = u >> 7, x = u & 127;
        float2* M = F + x * SS;
        float2 f[8];
        #pragma unroll
        for (int ka = 0; ka < 8; ++ka) f[ka] = M[16 * ka + t];
        fft8<1>(f);
        #pragma unroll
        for (int nh = 0; nh < 8; ++nh) {
            float m = sqrtf(f[nh].x * f[nh].x + f[nh].y * f[nh].y);
            acc += m;
            f[nh] = make_float2(m, 0.f);
        }
        fft8<-1>(f);
        #pragma unroll
        for (int ka = 0; ka < 8; ++ka)
            M[t + 16 * ka] = cmulc(f[ka], tw[t * ka]);
    }
}

// ---------- K_pre1 (R19): row-strip forward FFT along c + filters + zero ----------
// blocks 0..255: (b = blk>>2, q = blk&3) rows [32q, 32q+32) of image b.
// blocks 256..271: filter bank. block 272: zero ALL coeffs (s0 written by pre2).
__global__ __attribute__((amdgpu_flat_work_group_size(TT, TT), amdgpu_waves_per_eu(2, 2)))
void k_pre1(const float* __restrict__ img,
            float* __restrict__ psi,
            float2* __restrict__ interm,
            float* __restrict__ coeffs) {
    __shared__ __align__(16) float2 F[32 * SS];
    __shared__ float2 tw[128];
    int blk = blockIdx.x, tid = threadIdx.x;
    if (blk >= 256) {
        if (blk == 272) {
            for (int i = tid; i < 64 * 11; i += TT) coeffs[i] = 0.f;
            return;
        }
        int f = blk - 256;
        int j = f >> 2, l = f & 3;
        float k0    = 2.35619449019234493f / (float)(1 << j);
        float sigma = 0.8f * (float)(1 << j);
        float s2    = sigma * sigma;
        float theta = 0.78539816339744831f * (float)l;
        float k0x = k0 * cosf(theta);
        float k0y = k0 * sinf(theta);
        float beta = expf(-0.5f * s2 * k0 * k0);
        const float FSTEP = 0.04908738521234052f;
        float* dst = psi + (size_t)f * NPIX;
        for (int i = tid; i < NPIX; i += TT) {
            int pr = i >> 7, pc = i & 127;
            int kr = (pr >> 4) + 8 * (pr & 15);
            int kc = (pc >> 4) + 8 * (pc & 15);
            float fr = (float)(kr < 64 ? kr : kr - 128) * FSTEP;
            float fc = (float)(kc < 64 ? kc : kc - 128) * FSTEP;
            float dx = fr - k0x, dy = fc - k0y;
            float g1 = expf(-0.5f * s2 * (dx * dx + dy * dy));
            float g0 = expf(-0.5f * s2 * (fr * fr + fc * fc));
            dst[i] = g1 - beta * g0;
        }
        return;
    }
    int b = blk >> 2, q = blk & 3;
    buildTw(tw, tid);
    const float* im = img + (size_t)b * NPIX + (size_t)q * 32 * NN;
    #pragma unroll
    for (int k = 0; k < 8; ++k) {
        int e = k * TT + tid;                      // 0..4095
        F[(e >> 7) * SS + (e & 127)] = make_float2(im[e], 0.f);
    }
    __syncthreads();
    {   // stepA along c (fft8): 32 rows x 16 t = 512
        int x = tid & 31, t = tid >> 5;
        float2* M = F + x * SS;
        float2 f[8];
        #pragma unroll
        for (int n1 = 0; n1 < 8; ++n1) f[n1] = M[t + 16 * n1];
        fft8<-1>(f);
        #pragma unroll
        for (int ka = 0; ka < 8; ++ka)
            M[t + 16 * ka] = cmulc(f[ka], tw[t * ka]);
    }
    __syncthreads();
    if (tid < 256) {   // stepB along c (fft16): 32 rows x 8 ka
        int x = tid & 31, ka = tid >> 5;
        float2* M = F + x * SS + 16 * ka;
        float2 g[16];
        #pragma unroll
        for (int t = 0; t < 16; ++t) g[t] = M[t];
        fft16<-1>(g);
        #pragma unroll
        for (int kb = 0; kb < 16; ++kb) M[kb] = g[kb];
    }
    __syncthreads();
    float2* dst = interm + (size_t)b * NPIX + (size_t)q * 32 * NN;
    #pragma unroll
    for (int k = 0; k < 8; ++k) {
        int e = k * TT + tid;
        dst[e] = F[(e >> 7) * SS + (e & 127)];
    }
}

// ---------- K_pre2 (R19): col-strip forward FFT along r + capture + s0 ----------
// blocks 0..255: (b = blk>>2, q = blk&3) cols [32q, 32q+32) of image b.
// interm ALIASES ihat: strip fully loaded to LDS before any global write.
__global__ __attribute__((amdgpu_flat_work_group_size(TT, TT), amdgpu_waves_per_eu(2, 2)))
void k_pre2(float2* __restrict__ ihat,
            float* __restrict__ coeffs) {
    __shared__ __align__(16) float2 F[128 * 33];
    __shared__ float2 tw[128];
    int blk = blockIdx.x, tid = threadIdx.x;
    int b = blk >> 2, q = blk & 3;
    buildTw(tw, tid);
    float2* base = ihat + (size_t)b * NPIX + q * 32;
    #pragma unroll
    for (int k = 0; k < 8; ++k) {
        int e = k * TT + tid;                      // 0..4095
        int r = e >> 5, cl = e & 31;
        F[r * 33 + cl] = base[r * NN + cl];
    }
    __syncthreads();
    {   // stepA along r (fft8): 32 cols x 16 t = 512
        int cl = tid & 31, t = tid >> 5;
        float2 f[8];
        #pragma unroll
        for (int n1 = 0; n1 < 8; ++n1) f[n1] = F[(t + 16 * n1) * 33 + cl];
        fft8<-1>(f);
        #pragma unroll
        for (int ka = 0; ka < 8; ++ka)
            F[(t + 16 * ka) * 33 + cl] = cmulc(f[ka], tw[t * ka]);
    }
    __syncthreads();
    if (tid < 256) {   // stepB along r (fft16) + store + s0
        int cl = tid & 31, ka = tid >> 5;
        float2 g[16];
        #pragma unroll
        for (int t = 0; t < 16; ++t) g[t] = F[(16 * ka + t) * 33 + cl];
        fft16<-1>(g);
        float2* dst = base + cl;
        #pragma unroll
        for (int kb = 0; kb < 16; ++kb)
            dst[(16 * ka + kb) * NN] = g[kb];
        if (q == 0 && cl == 0 && ka == 0)
            coeffs[b * 11 + 0] = g[0].x * (1.f / 16384.f);
    }
}

// ---------- K_scat_big: j1 = 0 ONLY (grid 256 = one round; R4-proven form) ----------
__global__ __attribute__((amdgpu_flat_work_group_size(TT, TT), amdgpu_waves_per_eu(2, 2)))
void k_scat_big(const float2* __restrict__ ihat,
                const float* __restrict__ psi,
                float* __restrict__ coeffs) {
    // F: 16640 float2 = 133,120 B.
    //   128-grid phases: F[0..16512) stride SS.
    //   j2=1 one-pass: G2a..G2d = F + {0,4160,8320,12480}  (4x 64x65 float2)
    //   j2=2 pass:     G4a = (float4*)F, G4b = (float4*)(F+8320) (2x 64x65 float4)
    //   j2=3 pass:     P4a/P4b = two 32x33 float4 grids at F[0..4224)  (R17)
    __shared__ __align__(16) float2 F[16640];
    __shared__ float2 tw[128];
    float4* G4a = (float4*)F;
    float4* G4b = (float4*)(F + 8320);
    float2* G2a = F;
    float2* G2b = F + 4160;
    float2* G2c = F + 8320;
    float2* G2d = F + 12480;
    float4* P4a = (float4*)F;
    float4* P4b = (float4*)F + 1056;
    int tid = threadIdx.x;
    int x = blockIdx.x;
    int b = x & 63, l1 = x >> 6;                       // j1 == 0
    const float2* ih = ihat + (size_t)b * NPIX;
    const float*  p1 = psi + (size_t)l1 * NPIX;
    buildTw(tw, tid);

    const float S1_128 = 9.3132257461547852e-10f;   // 2^-30
    const float S2TR   = 5.6843418860808015e-14f;   // 2^-44
    const float S2_03  = 2.2737367544323206e-13f;   // 2^-42 = 4*S2TR (32-grid)

    int kalo = tid >> 7, c = tid & 127;
    {
        #pragma unroll
        for (int i = 0; i < 2; ++i) {
            int ka = kalo + 4 * i;
            float2 g[16];
            #pragma unroll
            for (int kb = 0; kb < 16; ++kb) {
                int e = (16 * ka + kb) * NN + c;
                float2 z = ih[e];
                float  p = p1[e];
                g[kb] = make_float2(z.x * p, z.y * p);
            }
            fft16<1>(g);
            #pragma unroll
            for (int t = 0; t < 16; ++t)
                F[(16 * ka + t) * SS + c] = cmul(g[t], tw[t * ka]);
        }
    }
    __syncthreads();
    invB<SS, 1>(F, tid);      __syncthreads();
    invA<1, SS>(F, tw, tid);  __syncthreads();
    float acc = 0.f;
    invBmag_fwdA_row(F, tw, tid, acc);
    float ws1 = waveReduceSum(acc);
    if ((tid & 63) == 0) atomicAdd(&coeffs[b * 11 + 1], ws1 * S1_128);
    __syncthreads();
    fwdB<1, SS>(F, tid);      __syncthreads();
    fwdA<SS, 1>(F, tw, tid);  __syncthreads();
    float2 uh[32];
    fwdB_col_capture(F, tid, uh);
    __syncthreads();   // capture done -> F reusable (grids alias it)

    // trunc-staging column perm (central +-32 window), for j2=2
    int m = c & 15;
    bool colKeep = (m < 4) || (m >= 12);
    int pc64 = 8 * (c >> 4) + ((m < 4) ? m : (m - 8));
    int fc = (c >> 4) + 8 * (c & 15);

    {
        // ===== (j1=0, j2=1): ONE pass, 4 off-center 64-windows (R14 mapping) =====
        const int ORW[4] = {21, 15, 0, -15};
        const int OCW[4] = { 0, 15, 21,  15};
        bool ckw[4]; int pcw[4];
        #pragma unroll
        for (int w = 0; w < 4; ++w) {
            int dc = (fc - OCW[w]) & 127;
            ckw[w] = (dc < 32) || (dc >= 96);
            int uc = (dc < 32) ? dc : (dc - 64);
            pcw[w] = 8 * (uc & 7) + (uc >> 3);
        }
        #pragma unroll
        for (int i = 0; i < 2; ++i) {
            int ka = kalo + 4 * i;
            #pragma unroll
            for (int kb = 0; kb < 16; ++kb) {
                int fr = ka + 8 * kb;
                float2 z = uh[i * 16 + kb];
                int e = (16 * ka + kb) * NN + c;
                #pragma unroll
                for (int w = 0; w < 4; ++w) {
                    if (ckw[w]) {
                        int dr = (fr - ORW[w]) & 127;
                        if (dr < 32 || dr >= 96) {
                            int ur = (dr < 32) ? dr : (dr - 64);
                            int pr = 8 * (ur & 7) + (ur >> 3);
                            float pv = psi[(size_t)(4 + w) * NPIX + e];
                            float2* G = (w == 0) ? G2a : (w == 1) ? G2b
                                       : (w == 2) ? G2c : G2d;
                            G[pr * SG + pcw[w]] = make_float2(z.x * pv, z.y * pv);
                        }
                    }
                }
            }
        }
        __syncthreads();
        {   // col stepA (4 grids, full width)
            int col = tid & 63, k8 = tid >> 6;
            float2 f0[8], f1[8], f2[8], f3[8];
            #pragma unroll
            for (int kb = 0; kb < 8; ++kb) {
                int o = (8 * k8 + kb) * SG + col;
                f0[kb] = G2a[o]; f1[kb] = G2b[o]; f2[kb] = G2c[o]; f3[kb] = G2d[o];
            }
            fft8<1>(f0); fft8<1>(f1); fft8<1>(f2); fft8<1>(f3);
            #pragma unroll
            for (int q = 0; q < 8; ++q) {
                float2 w = tw[2 * q * k8];
                int o = (8 * k8 + q) * SG + col;
                G2a[o] = cmul(f0[q], w); G2b[o] = cmul(f1[q], w);
                G2c[o] = cmul(f2[q], w); G2d[o] = cmul(f3[q], w);
            }
        }
        __syncthreads();
        {   // col stepB
            int col = tid & 63, q = tid >> 6;
            float2 f0[8], f1[8], f2[8], f3[8];
            #pragma unroll
            for (int k8 = 0; k8 < 8; ++k8) {
                int o = (8 * k8 + q) * SG + col;
                f0[k8] = G2a[o]; f1[k8] = G2b[o]; f2[k8] = G2c[o]; f3[k8] = G2d[o];
            }
            fft8<1>(f0); fft8<1>(f1); fft8<1>(f2); fft8<1>(f3);
            #pragma unroll
            for (int n1 = 0; n1 < 8; ++n1) {
                int o = (8 * n1 + q) * SG + col;
                G2a[o] = f0[n1]; G2b[o] = f1[n1]; G2c[o] = f2[n1]; G2d[o] = f3[n1];
            }
        }
        __syncthreads();
        {   // row stepA
            int row = tid & 63, k8 = tid >> 6;
            int base = row * SG + 8 * k8;
            float2 f0[8], f1[8], f2[8], f3[8];
            #pragma unroll
            for (int kb = 0; kb < 8; ++kb) {
                f0[kb] = G2a[base + kb]; f1[kb] = G2b[base + kb];
                f2[kb] = G2c[base + kb]; f3[kb] = G2d[base + kb];
            }
            fft8<1>(f0); fft8<1>(f1); fft8<1>(f2); fft8<1>(f3);
            #pragma unroll
            for (int q = 0; q < 8; ++q) {
                float2 w = tw[2 * q * k8];
                G2a[base + q] = cmul(f0[q], w); G2b[base + q] = cmul(f1[q], w);
                G2c[base + q] = cmul(f2[q], w); G2d[base + q] = cmul(f3[q], w);
            }
        }
        __syncthreads();
        float a2 = 0.f;
        {   // row stepB + mag (all 4 -> same coeff)
            int row = tid & 63, q = tid >> 6;
            int base = row * SG + q;
            float2 f0[8], f1[8], f2[8], f3[8];
            #pragma unroll
            for (int k8 = 0; k8 < 8; ++k8) {
                int o = base + 8 * k8;
                f0[k8] = G2a[o]; f1[k8] = G2b[o]; f2[k8] = G2c[o]; f3[k8] = G2d[o];
            }
            fft8<1>(f0); fft8<1>(f1); fft8<1>(f2); fft8<1>(f3);
            #pragma unroll
            for (int n1 = 0; n1 < 8; ++n1) {
                a2 += sqrtf(f0[n1].x * f0[n1].x + f0[n1].y * f0[n1].y);
                a2 += sqrtf(f1[n1].x * f1[n1].x + f1[n1].y * f1[n1].y);
                a2 += sqrtf(f2[n1].x * f2[n1].x + f2[n1].y * f2[n1].y);
                a2 += sqrtf(f3[n1].x * f3[n1].x + f3[n1].y * f3[n1].y);
            }
        }
        float ws2 = waveReduceSum(a2);
        if ((tid & 63) == 0) atomicAdd(&coeffs[b * 11 + 5 + 0], ws2 * S2TR);
        __syncthreads();
    }

    {   // ===== (0,2): ONE pass, 4 filters, central +-32 64-grid (R4-proven) =====
        const float* p0 = psi + (size_t)8 * NPIX;
        const float* pq1 = p0 + NPIX;
        const float* pq2 = pq1 + NPIX;
        const float* pq3 = pq2 + NPIX;
        if (colKeep) {
            #pragma unroll
            for (int i = 0; i < 2; ++i) {
                int ka = kalo + 4 * i;
                #pragma unroll
                for (int kb = 0; kb < 16; ++kb) {
                    if (kb < 4 || kb >= 12) {
                        int pr64 = 8 * ka + ((kb < 4) ? kb : (kb - 8));
                        float2 z = uh[i * 16 + kb];
                        int e = (16 * ka + kb) * NN + c;
                        float a0 = p0[e], a1 = pq1[e], a2f = pq2[e], a3 = pq3[e];
                        G4a[pr64 * SG + pc64] =
                            make_float4(z.x * a0, z.y * a0, z.x * a1, z.y * a1);
                        G4b[pr64 * SG + pc64] =
                            make_float4(z.x * a2f, z.y * a2f, z.x * a3, z.y * a3);
                    }
                }
            }
        }
        __syncthreads();
        {   // col stepA (two packed grids = 4 filters, full width)
            int col = tid & 63, k8 = tid >> 6;
            float2 f0[8], f1[8], f2[8], f3[8];
            #pragma unroll
            for (int kb = 0; kb < 8; ++kb) {
                int o = (8 * k8 + kb) * SG + col;
                float4 v = G4a[o];
                f0[kb] = make_float2(v.x, v.y); f1[kb] = make_float2(v.z, v.w);
                float4 u = G4b[o];
                f2[kb] = make_float2(u.x, u.y); f3[kb] = make_float2(u.z, u.w);
            }
            fft8<1>(f0); fft8<1>(f1); fft8<1>(f2); fft8<1>(f3);
            #pragma unroll
            for (int q = 0; q < 8; ++q) {
                float2 w = tw[2 * q * k8];
                int o = (8 * k8 + q) * SG + col;
                float2 a = cmul(f0[q], w), d = cmul(f1[q], w);
                G4a[o] = make_float4(a.x, a.y, d.x, d.y);
                float2 a2c = cmul(f2[q], w), d2 = cmul(f3[q], w);
                G4b[o] = make_float4(a2c.x, a2c.y, d2.x, d2.y);
            }
        }
        __syncthreads();
        {   // col stepB
            int col = tid & 63, q = tid >> 6;
            float2 f0[8], f1[8], f2[8], f3[8];
            #pragma unroll
            for (int k8 = 0; k8 < 8; ++k8) {
                int o = (8 * k8 + q) * SG + col;
                float4 v = G4a[o];
                f0[k8] = make_float2(v.x, v.y); f1[k8] = make_float2(v.z, v.w);
                float4 u = G4b[o];
                f2[k8] = make_float2(u.x, u.y); f3[k8] = make_float2(u.z, u.w);
            }
            fft8<1>(f0); fft8<1>(f1); fft8<1>(f2); fft8<1>(f3);
            #pragma unroll
            for (int n1 = 0; n1 < 8; ++n1) {
                int o = (8 * n1 + q) * SG + col;
                G4a[o] = make_float4(f0[n1].x, f0[n1].y, f1[n1].x, f1[n1].y);
                G4b[o] = make_float4(f2[n1].x, f2[n1].y, f3[n1].x, f3[n1].y);
            }
        }
        __syncthreads();
        {   // row stepA
            int row = tid & 63, k8 = tid >> 6;
            int base = row * SG + 8 * k8;
            float2 f0[8], f1[8], f2[8], f3[8];
            #pragma unroll
            for (int kb = 0; kb < 8; ++kb) {
                float4 v = G4a[base + kb];
                f0[kb] = make_float2(v.x, v.y); f1[kb] = make_float2(v.z, v.w);
                float4 u = G4b[base + kb];
                f2[kb] = make_float2(u.x, u.y); f3[kb] = make_float2(u.z, u.w);
            }
            fft8<1>(f0); fft8<1>(f1); fft8<1>(f2); fft8<1>(f3);
            #pragma unroll
            for (int q = 0; q < 8; ++q) {
                float2 w = tw[2 * q * k8];
                float2 a = cmul(f0[q], w), d = cmul(f1[q], w);
                G4a[base + q] = make_float4(a.x, a.y, d.x, d.y);
                float2 a2c = cmul(f2[q], w), d2 = cmul(f3[q], w);
                G4b[base + q] = make_float4(a2c.x, a2c.y, d2.x, d2.y);
            }
        }
        __syncthreads();
        float a2 = 0.f;
        {   // row stepB + mag
            int row = tid & 63, q = tid >> 6;
            int base = row * SG + q;
            float2 f0[8], f1[8], f2[8], f3[8];
            #pragma unroll
            for (int k8 = 0; k8 < 8; ++k8) {
                float4 v = G4a[base + 8 * k8];
                f0[k8] = make_float2(v.x, v.y); f1[k8] = make_float2(v.z, v.w);
                float4 u = G4b[base + 8 * k8];
                f2[k8] = make_float2(u.x, u.y); f3[k8] = make_float2(u.z, u.w);
            }
            fft8<1>(f0); fft8<1>(f1); fft8<1>(f2); fft8<1>(f3);
            #pragma unroll
            for (int n1 = 0; n1 < 8; ++n1) {
                a2 += sqrtf(f0[n1].x * f0[n1].x + f0[n1].y * f0[n1].y);
                a2 += sqrtf(f1[n1].x * f1[n1].x + f1[n1].y * f1[n1].y);
                a2 += sqrtf(f2[n1].x * f2[n1].x + f2[n1].y * f2[n1].y);
                a2 += sqrtf(f3[n1].x * f3[n1].x + f3[n1].y * f3[n1].y);
            }
        }
        float ws2 = waveReduceSum(a2);
        if ((tid & 63) == 0) atomicAdd(&coeffs[b * 11 + 5 + 1], ws2 * S2TR);
        __syncthreads();
    }

    {   // ===== (0,3): 32-grid 4-filter pass (R17-proven; central +-16 of uh) =====
        bool ck32 = (m < 2) || (m >= 14);
        int pc32 = 4 * (c >> 4) + ((m < 2) ? m : (m - 12));
        const float* p0 = psi + (size_t)12 * NPIX;
        const float* pq1 = p0 + NPIX;
        const float* pq2 = pq1 + NPIX;
        const float* pq3 = pq2 + NPIX;
        if (ck32) {
            #pragma unroll
            for (int i = 0; i < 2; ++i) {
                int ka = kalo + 4 * i;
                #pragma unroll
                for (int kb = 0; kb < 16; ++kb) {
                    if (kb < 2 || kb >= 14) {
                        int pr32 = 4 * ka + ((kb < 2) ? kb : (kb - 12));
                        float2 z = uh[i * 16 + kb];
                        int e = (16 * ka + kb) * NN + c;
                        float a0 = p0[e], a1 = pq1[e], a2f = pq2[e], a3 = pq3[e];
                        P4a[pr32 * SG32 + pc32] =
                            make_float4(z.x * a0, z.y * a0, z.x * a1, z.y * a1);
                        P4b[pr32 * SG32 + pc32] =
                            make_float4(z.x * a2f, z.y * a2f, z.x * a3, z.y * a3);
                    }
                }
            }
        }
        float a2 = pass32x4(P4a, P4b, tw, tid);
        float ws2 = waveReduceSum(a2);
        if ((tid & 63) == 0) atomicAdd(&coeffs[b * 11 + 5 + 2], ws2 * S2_03);
    }
}

// ---------- K_scat_small: j1 in {1,2,3} -- 67.6 KB LDS => 2 blocks/CU ----------
__global__ __attribute__((amdgpu_flat_work_group_size(TT, TT), amdgpu_waves_per_eu(4, 4)))
void k_scat_small(const float2* __restrict__ ihat,
                  const float* __restrict__ psi,
                  float* __restrict__ coeffs) {
    // S: 8448 float2 = 67,584 B.
    //   G2 (64x65 float2) = S[0..4160); H32 = S[6144..7168) (j1=2 path);
    //   j1=2 (2,3): P4a=(float4*)S [0..2112), P4b=+1056 [2112..4224) (R17);
    //   j1=1 combo: Qs0..Qs3 = S+{0,1056,2112,3168}; Psa=(float4*)(S+4224),
    //               Psb=(float4*)(S+6336)  (R18);
    //   G32 (32x33 float2) aliases S[0..) (j1=3 first order).
    __shared__ __align__(16) float2 S[8448];
    __shared__ float2 tw[128];
    float2* G2  = S;
    float2* G32 = S;
    float4* P4a = (float4*)S;
    float4* P4b = (float4*)S + 1056;
    float2* Qs0 = S;
    float2* Qs1 = S + 1056;
    float2* Qs2 = S + 2112;
    float2* Qs3 = S + 3168;
    float4* Psa = (float4*)(S + 4224);
    float4* Psb = (float4*)(S + 6336);
    float2* H32 = S + 6144;
    int tid = threadIdx.x;
    int x = blockIdx.x;
    int b = x & 63, l1 = (x >> 6) & 3;
    int t0 = x >> 8;                          // 0 -> j1=1 (heavy, first), 1 -> j1=2, 2 -> j1=3
    int j1 = (t0 == 0) ? 1 : (t0 + 1);
    const float2* ih = ihat + (size_t)b * NPIX;
    const float*  p1 = psi + (size_t)(j1 * 4 + l1) * NPIX;
    buildTw(tw, tid);

    const float S1_64 = 3.7252902984619141e-9f;    // 2^-28
    const float S1_32 = 1.4901161193847656e-8f;    // 2^-26
    const float S2_32 = 9.0949470177292824e-13f;   // 2^-40 (32-grid from V)

    int kalo = tid >> 7, c = tid & 127;

    if (t0 == 0) {
        // =========== j1 = 1 on off-center 64-window (R16) ===========
        const int OR1[4] = {21, 15, 0, -15};
        const int OC1[4] = { 0, 15, 21,  15};
        int fc = (c >> 4) + 8 * (c & 15);
        int dc = (fc - OC1[l1]) & 127;
        bool ck = (dc < 32) || (dc >= 96);
        int ucw = (dc < 32) ? dc : (dc - 64);
        int pcd = 8 * (ucw & 7) + (ucw >> 3);
        if (ck) {
            #pragma unroll
            for (int i = 0; i < 2; ++i) {
                int ka = kalo + 4 * i;
                #pragma unroll
                for (int kb = 0; kb < 16; ++kb) {
                    int fr = ka + 8 * kb;
                    int dr = (fr - OR1[l1]) & 127;
                    if (dr < 32 || dr >= 96) {
                        int ur = (dr < 32) ? dr : (dr - 64);
                        int pr = 8 * (ur & 7) + (ur >> 3);
                        int e = (16 * ka + kb) * NN + c;
                        float2 z = ih[e];
                        float  p = p1[e];
                        G2[pr * SG + pcd] = make_float2(z.x * p, z.y * p);
                    }
                }
            }
        }
        __syncthreads();
        {   // col stepA (inverse)
            int col = tid & 63, k8 = tid >> 6;
            float2 f[8];
            #pragma unroll
            for (int kb = 0; kb < 8; ++kb) f[kb] = G2[(8 * k8 + kb) * SG + col];
            fft8<1>(f);
            #pragma unroll
            for (int q = 0; q < 8; ++q)
                G2[(8 * k8 + q) * SG + col] = cmul(f[q], tw[2 * q * k8]);
        }
        __syncthreads();
        {   // col stepB
            int col = tid & 63, q = tid >> 6;
            float2 f[8];
            #pragma unroll
            for (int k8 = 0; k8 < 8; ++k8) f[k8] = G2[(8 * k8 + q) * SG + col];
            fft8<1>(f);
            #pragma unroll
            for (int n1 = 0; n1 < 8; ++n1) G2[(8 * n1 + q) * SG + col] = f[n1];
        }
        __syncthreads();
        {   // row stepA (inverse)
            int row = tid & 63, k8 = tid >> 6;
            float2* R = G2 + row * SG + 8 * k8;
            float2 f[8];
            #pragma unroll
            for (int kb = 0; kb < 8; ++kb) f[kb] = R[kb];
            fft8<1>(f);
            #pragma unroll
            for (int q = 0; q < 8; ++q) R[q] = cmul(f[q], tw[2 * q * k8]);
        }
        __syncthreads();
        float acc = 0.f;
        {   // FUSED64: row stepB inv -> |.| -> row stepA fwd
            int row = tid & 63, q = tid >> 6;
            float2* R = G2 + row * SG + q;
            float2 f[8];
            #pragma unroll
            for (int k8 = 0; k8 < 8; ++k8) f[k8] = R[8 * k8];
            fft8<1>(f);
            #pragma unroll
            for (int n1 = 0; n1 < 8; ++n1) {
                float mg = sqrtf(f[n1].x * f[n1].x + f[n1].y * f[n1].y);
                acc += mg;
                f[n1] = make_float2(mg, 0.f);
            }
            fft8<-1>(f);
            #pragma unroll
            for (int ka = 0; ka < 8; ++ka)
                R[8 * ka] = cmulc(f[ka], tw[2 * q * ka]);
        }
        float ws1 = waveReduceSum(acc);
        if ((tid & 63) == 0) atomicAdd(&coeffs[b * 11 + 2], ws1 * S1_64);
        __syncthreads();
        {   // row stepB (forward)
            int row2 = tid & 63, ka = tid >> 6;
            float2* R2 = G2 + row2 * SG + 8 * ka;
            float2 g[8];
            #pragma unroll
            for (int t = 0; t < 8; ++t) g[t] = R2[t];
            fft8<-1>(g);
            #pragma unroll
            for (int kb = 0; kb < 8; ++kb) R2[kb] = g[kb];
        }
        __syncthreads();
        {   // col stepA (forward)
            int col = tid & 63, t = tid >> 6;
            float2 g[8];
            #pragma unroll
            for (int n1 = 0; n1 < 8; ++n1) g[n1] = G2[(t + 8 * n1) * SG + col];
            fft8<-1>(g);
            #pragma unroll
            for (int ka = 0; ka < 8; ++ka)
                G2[(t + 8 * ka) * SG + col] = cmulc(g[ka], tw[2 * t * ka]);
        }
        __syncthreads();
        float2 vh[8];
        int c6 = tid & 63, ka8 = tid >> 6;
        {   // col stepB (forward) -> V = u1hat_64 captured to registers
            float2 g[8];
            #pragma unroll
            for (int t = 0; t < 8; ++t) g[t] = G2[(8 * ka8 + t) * SG + c6];
            fft8<-1>(g);
            #pragma unroll
            for (int kb = 0; kb < 8; ++kb) vh[kb] = g[kb];
        }
        __syncthreads();   // G2 reads done -> combo grids (aliases) safe to write

        // psi gather indices: 64-grid storage p <-> freq u = 8*(p&7)+(p>>3);
        // 128-freq f128 = u<32 ? u : u+64; storage s = 16*(f128&7)+(f128>>3)
        int uc64 = 8 * (c6 & 7) + (c6 >> 3);
        int fc128 = (uc64 < 32) ? uc64 : (uc64 + 64);
        int scI = 16 * (fc128 & 7) + (fc128 >> 3);
        int se[8];
        #pragma unroll
        for (int kb = 0; kb < 8; ++kb) {
            int ur = 8 * kb + ka8;
            int fr128 = (ur < 32) ? ur : (ur + 64);
            se[kb] = (16 * (fr128 & 7) + (fr128 >> 3)) * NN + scI;
        }

        {   // ===== (1,2)+(1,3): fused 32-grid combo pass (R18) =====
            const int OR2[4] = {9, 6, 0, -6};
            const int OC2[4] = {0, 6, 9,  6};
            bool ckq[4]; int pcq[4];
            #pragma unroll
            for (int w = 0; w < 4; ++w) {
                int dcw = (uc64 - OC2[w]) & 63;
                ckq[w] = (dcw < 16) || (dcw >= 48);
                int f32c = (dcw < 16) ? dcw : (dcw - 32);
                pcq[w] = 4 * (f32c & 7) + (f32c >> 3);
            }
            int m6 = c6 & 7;
            bool ckV = (m6 < 2) || (m6 >= 6);
            int p32c = 4 * (c6 >> 3) + ((m6 < 2) ? m6 : (m6 - 4));
            const float* p30 = psi + (size_t)12 * NPIX;
            #pragma unroll
            for (int kb = 0; kb < 8; ++kb) {
                int ur = 8 * kb + ka8;
                float2 z = vh[kb];
                int e = se[kb];
                #pragma unroll
                for (int w = 0; w < 4; ++w) {
                    if (ckq[w]) {
                        int dr = (ur - OR2[w]) & 63;
                        if (dr < 16 || dr >= 48) {
                            int f32r = (dr < 16) ? dr : (dr - 32);
                            int pr = 4 * (f32r & 7) + (f32r >> 3);
                            float pv = psi[(size_t)(8 + w) * NPIX + e];
                            float2* Q = (w == 0) ? Qs0 : (w == 1) ? Qs1
                                       : (w == 2) ? Qs2 : Qs3;
                            Q[pr * SG32 + pcq[w]] = make_float2(z.x * pv, z.y * pv);
                        }
                    }
                }
                if (ckV && (kb < 2 || kb >= 6)) {
                    int pr32 = 4 * ka8 + (kb & 3);
                    float a0 = p30[e], a1 = p30[NPIX + e];
                    float a2f = p30[2 * NPIX + e], a3 = p30[3 * NPIX + e];
                    Psa[pr32 * SG32 + p32c] =
                        make_float4(z.x * a0, z.y * a0, z.x * a1, z.y * a1);
                    Psb[pr32 * SG32 + p32c] =
                        make_float4(z.x * a2f, z.y * a2f, z.x * a3, z.y * a3);
                }
            }
            float aq, ap;
            pass32combo(Qs0, Qs1, Qs2, Qs3, Psa, Psb, tw, tid, aq, ap);
            float wsq = waveReduceSum(aq);
            float wsp = waveReduceSum(ap);
            if ((tid & 63) == 0) {
                atomicAdd(&coeffs[b * 11 + 5 + 3], wsq * S2_32);
                atomicAdd(&coeffs[b * 11 + 5 + 4], wsp * S2_32);
            }
        }
        return;
    }

    if (t0 == 2) {
        // ===== j1=3: 32-grid first order (psi_{j1=3} support +-16) =====
        int m = c & 15;
        bool ck32 = (m < 2) || (m >= 14);
        int pc32 = 4 * (c >> 4) + ((m < 2) ? m : (m - 12));
        if (ck32) {
            #pragma unroll
            for (int i = 0; i < 2; ++i) {
                int ka = kalo + 4 * i;
                #pragma unroll
                for (int kb = 0; kb < 16; ++kb) {
                    if (kb < 2 || kb >= 14) {
                        int e = (16 * ka + kb) * NN + c;
                        float2 z = ih[e];
                        float  p = p1[e];
                        int pr32 = 4 * ka + ((kb < 2) ? kb : (kb - 12));
                        G32[pr32 * SG32 + pc32] = make_float2(z.x * p, z.y * p);
                    }
                }
            }
        }
        __syncthreads();
        if (tid < 256) {   // col stepA: fft4 over b per a (32 lines x 8 a)
            int line = tid & 31, a = tid >> 5;
            float2 f[4];
            #pragma unroll
            for (int kb = 0; kb < 4; ++kb) f[kb] = G32[(4 * a + kb) * SG32 + line];
            fft4<1>(f);
            #pragma unroll
            for (int t = 0; t < 4; ++t)
                G32[(4 * a + t) * SG32 + line] = cmul(f[t], tw[4 * t * a]);
        }
        __syncthreads();
        if (tid < 128) {   // col stepB: fft8 over a per t (32 lines x 4 t)
            int line = tid & 31, t = tid >> 5;
            float2 f[8];
            #pragma unroll
            for (int a = 0; a < 8; ++a) f[a] = G32[(4 * a + t) * SG32 + line];
            fft8<1>(f);
            #pragma unroll
            for (int n1 = 0; n1 < 8; ++n1) G32[(4 * n1 + t) * SG32 + line] = f[n1];
        }
        __syncthreads();
        if (tid < 256) {   // row stepA
            int row = tid & 31, a = tid >> 5;
            float2* R = G32 + row * SG32 + 4 * a;
            float2 f[4];
            #pragma unroll
            for (int kb = 0; kb < 4; ++kb) f[kb] = R[kb];
            fft4<1>(f);
            #pragma unroll
            for (int t = 0; t < 4; ++t) R[t] = cmul(f[t], tw[4 * t * a]);
        }
        __syncthreads();
        float acc = 0.f;
        if (tid < 128) {   // row stepB + mag
            int row = tid & 31, t = tid >> 5;
            float2* R = G32 + row * SG32 + t;
            float2 f[8];
            #pragma unroll
            for (int a = 0; a < 8; ++a) f[a] = R[4 * a];
            fft8<1>(f);
            #pragma unroll
            for (int n1 = 0; n1 < 8; ++n1)
                acc += sqrtf(f[n1].x * f[n1].x + f[n1].y * f[n1].y);
        }
        float ws1 = waveReduceSum(acc);
        if ((tid & 63) == 0 && tid < 128) atomicAdd(&coeffs[b * 11 + 4], ws1 * S1_32);
        return;
    }

    // ===================== j1 == 2: 64-grid first order (R13-proven) ==============
    int m = c & 15;
    bool colKeep = (m < 4) || (m >= 12);
    if (colKeep) {
        #pragma unroll
        for (int i = 0; i < 2; ++i) {
            int ka = kalo + 4 * i;
            #pragma unroll
            for (int kb = 0; kb < 16; ++kb) {
                if (kb < 4 || kb >= 12) {
                    int e = (16 * ka + kb) * NN + c;
                    float2 z = ih[e];
                    float  p = p1[e];
                    int pr64 = 8 * ka + ((kb < 4) ? kb : (kb - 8));
                    int pc64 = 8 * (c >> 4) + ((m < 4) ? m : (m - 8));
                    G2[pr64 * SG + pc64] = make_float2(z.x * p, z.y * p);
                }
            }
        }
    }
    __syncthreads();
    {   // col stepA (inverse)
        int col = tid & 63, k8 = tid >> 6;
        float2 f[8];
        #pragma unroll
        for (int kb = 0; kb < 8; ++kb) f[kb] = G2[(8 * k8 + kb) * SG + col];
        fft8<1>(f);
        #pragma unroll
        for (int q = 0; q < 8; ++q)
            G2[(8 * k8 + q) * SG + col] = cmul(f[q], tw[2 * q * k8]);
    }
    __syncthreads();
    {   // col stepB
        int col = tid & 63, q = tid >> 6;
        float2 f[8];
        #pragma unroll
        for (int k8 = 0; k8 < 8; ++k8) f[k8] = G2[(8 * k8 + q) * SG + col];
        fft8<1>(f);
        #pragma unroll
        for (int n1 = 0; n1 < 8; ++n1) G2[(8 * n1 + q) * SG + col] = f[n1];
    }
    __syncthreads();
    {   // row stepA (inverse)
        int row = tid & 63, k8 = tid >> 6;
        float2* R = G2 + row * SG + 8 * k8;
        float2 f[8];
        #pragma unroll
        for (int kb = 0; kb < 8; ++kb) f[kb] = R[kb];
        fft8<1>(f);
        #pragma unroll
        for (int q = 0; q < 8; ++q) R[q] = cmul(f[q], tw[2 * q * k8]);
    }
    __syncthreads();
    float acc = 0.f;
    {   // FUSED64: row stepB inv -> |.| (raw) -> row stepA fwd (same cells)
        int row = tid & 63, q = tid >> 6;
        float2* R = G2 + row * SG + q;
        float2 f[8];
        #pragma unroll
        for (int k8 = 0; k8 < 8; ++k8) f[k8] = R[8 * k8];
        fft8<1>(f);
        #pragma unroll
        for (int n1 = 0; n1 < 8; ++n1) {
            float mg = sqrtf(f[n1].x * f[n1].x + f[n1].y * f[n1].y);
            acc += mg;
            f[n1] = make_float2(mg, 0.f);
        }
        fft8<-1>(f);
        #pragma unroll
        for (int ka = 0; ka < 8; ++ka)
            R[8 * ka] = cmulc(f[ka], tw[2 * q * ka]);
    }
    float ws1 = waveReduceSum(acc);
    if ((tid & 63) == 0) atomicAdd(&coeffs[b * 11 + 3], ws1 * S1_64);
    __syncthreads();
    {   // row stepB (forward)
        int row2 = tid & 63, ka = tid >> 6;
        float2* R2 = G2 + row2 * SG + 8 * ka;
        float2 g[8];
        #pragma unroll
        for (int t = 0; t < 8; ++t) g[t] = R2[t];
        fft8<-1>(g);
        #pragma unroll
        for (int kb = 0; kb < 8; ++kb) R2[kb] = g[kb];
    }
    __syncthreads();
    {   // col stepA (forward)
        int col = tid & 63, t = tid >> 6;
        float2 g[8];
        #pragma unroll
        for (int n1 = 0; n1 < 8; ++n1) g[n1] = G2[(t + 8 * n1) * SG + col];
        fft8<-1>(g);
        #pragma unroll
        for (int ka = 0; ka < 8; ++ka)
            G2[(t + 8 * ka) * SG + col] = cmulc(g[ka], tw[2 * t * ka]);
    }
    __syncthreads();
    {   // col stepB (forward) -> H32: central +-16 of V only (perm32 layout)
        int col = tid & 63, ka = tid >> 6;
        float2 g[8];
        #pragma unroll
        for (int t = 0; t < 8; ++t) g[t] = G2[(8 * ka + t) * SG + col];
        fft8<-1>(g);
        int br = col & 7, ar = col >> 3;
        if (br < 2 || br >= 6) {
            int p32row = 4 * ar + (br & 3);
            #pragma unroll
            for (int kb = 0; kb < 8; ++kb) {
                if (kb < 2 || kb >= 6)
                    H32[(4 * ka + (kb & 3)) * 32 + p32row] = g[kb];
            }
        }
    }
    __syncthreads();

    {   // ===== (2,3): ONE 32-grid 4-filter pass (R17 proven) =====
        bool ck32 = (m < 2) || (m >= 14);
        int pc32 = 4 * (c >> 4) + ((m < 2) ? m : (m - 12));
        const float* p0 = psi + (size_t)12 * NPIX;
        const float* pq1 = p0 + NPIX;
        const float* pq2 = pq1 + NPIX;
        const float* pq3 = pq2 + NPIX;
        if (ck32) {
            #pragma unroll
            for (int i = 0; i < 2; ++i) {
                int ka = kalo + 4 * i;
                #pragma unroll
                for (int kb = 0; kb < 16; ++kb) {
                    if (kb < 2 || kb >= 14) {
                        int pr32 = 4 * ka + ((kb < 2) ? kb : (kb - 12));
                        float2 z = H32[pr32 * 32 + pc32];
                        int e = (16 * ka + kb) * NN + c;
                        float a0 = p0[e], a1 = pq1[e], a2f = pq2[e], a3 = pq3[e];
                        P4a[pr32 * SG32 + pc32] =
                            make_float4(z.x * a0, z.y * a0, z.x * a1, z.y * a1);
                        P4b[pr32 * SG32 + pc32] =
                            make_float4(z.x * a2f, z.y * a2f, z.x * a3, z.y * a3);
                    }
                }
            }
        }
        float a2 = pass32x4(P4a, P4b, tw, tid);
        float ws2 = waveReduceSum(a2);
        if ((tid & 63) == 0) atomicAdd(&coeffs[b * 11 + 5 + 5], ws2 * S2_32);
    }
}

// ---------- K_mlp: tiny MLP head (separate launch -- R12 lesson) ----------
__global__ void k_mlp(const float* __restrict__ coeffs,
                      const float* __restrict__ w1, const float* __restrict__ b1,
                      const float* __restrict__ w2, const float* __restrict__ b2,
                      float* __restrict__ out) {
    int b = threadIdx.x;
    if (b >= 64) return;
    float c[11];
    #pragma unroll
    for (int i = 0; i < 11; ++i) c[i] = coeffs[b * 11 + i];
    float h[4];
    #pragma unroll
    for (int k = 0; k < 4; ++k) {
        float s = b1[k];
        #pragma unroll
        for (int i = 0; i < 11; ++i) s += w1[k * 11 + i] * c[i];
        h[k] = fmaxf(s, 0.f);
    }
    #pragma unroll
    for (int o = 0; o < 10; ++o) {
        float s = b2[o];
        #pragma unroll
        for (int k = 0; k < 4; ++k) s += w2[o * 4 + k] * h[k];
        out[b * 10 + o] = 1.f / (1.f + expf(-s));
    }
}

extern "C" void kernel_launch(void* const* d_in, const int* in_sizes, int n_in,
                              void* d_out, int out_size, void* d_ws, size_t ws_size,
                              hipStream_t stream) {
    const float* img = (const float*)d_in[0];
    const float* w1  = (const float*)d_in[1];
    const float* b1  = (const float*)d_in[2];
    const float* w2  = (const float*)d_in[3];
    const float* b2  = (const float*)d_in[4];
    float* out = (float*)d_out;

    float*  ws     = (float*)d_ws;
    float*  psi    = ws;
    float2* ihat   = (float2*)(ws + 16 * NPIX);
    float*  coeffs = ws + 16 * NPIX + 2 * 64 * NPIX;

    // R19: pre split. ihat doubles as the row-FFT intermediate (pre2 aliasing-safe).
    hipLaunchKernelGGL(k_pre1,       dim3(273), dim3(TT), 0, stream, img, psi, ihat, coeffs);
    hipLaunchKernelGGL(k_pre2,       dim3(256), dim3(TT), 0, stream, ihat, coeffs);
    hipLaunchKernelGGL(k_scat_big,   dim3(256), dim3(TT), 0, stream, ihat, psi, coeffs);
    hipLaunchKernelGGL(k_scat_small, dim3(768), dim3(TT), 0, stream, ihat, psi, coeffs);
    hipLaunchKernelGGL(k_mlp,        dim3(1),   dim3(64), 0, stream, coeffs, w1, b1, w2, b2, out);
}

// Round 7
// 168.893 us; speedup vs baseline: 1.4435x; 1.0495x over previous
//
#include <hip/hip_runtime.h>
#include <math.h>

#define NN   128
#define SS   129          // LDS row stride in float2 (ODD -> conflict-free lane stride)
#define TT   512          // PROVEN: TT=512 no-spill; TT=1024 ALWAYS spills. Never 1024.
#define NPIX 16384        // 128*128
#define EPT  32           // NPIX / TT
#define SG   65           // 64-grid row stride (float2 or float4 units)
#define SG32 33           // 32-grid row stride

// R12 lesson: NO __threadfence() tail / in-kernel MLP fold (cost ~115 us).
// R14: (j1=0,j2=1) on OFF-CENTER 64x64 frequency windows. Proven absmax 0.0.
// R15: H eliminated; full-width packed passes.
// R16: j1=1 retired from the 128-grid (off-center 64-window; V = uh/4).
// R17: all j2=3 pairs on the 32-grid (pass32x4; scales per ladder).
// R18: j2=2 pairs on off-center 32-windows (combo kept in SMALL j1=1 only;
//      R5 measured big's fused scatter staging as a regression at 1 block/CU).
// R19: k_pre split into pre1 (row strips) + pre2 (col strips).
// R20 (this round):
//   (a) pre1/pre2 waves_per_eu(2,2)->(4,4) [was pinning 1 block/CU!] and
//       filter bank split 16 -> 128 blocks (expf tail was serialized).
//   (b) j1=2 branch ENTIRELY on off-center 32-windows: first order uses R18's
//       proven window family (same filter scale), S1_32 scale; (2,3) staged
//       from V32 at the SAME storage slot (same perm), scale 2^-38 = ladder
//       2^-44 * 4^(u1 halvings=2) * 4^(pass halvings=1). V32 alias tails ==
//       tails the proven (2,3) truncation discarded.

__device__ __forceinline__ float2 cmul(float2 a, float2 w) {
    return make_float2(a.x * w.x - a.y * w.y, a.x * w.y + a.y * w.x);
}
__device__ __forceinline__ float2 cmulc(float2 a, float2 w) {   // a * conj(w)
    return make_float2(a.x * w.x + a.y * w.y, a.y * w.x - a.x * w.y);
}

// ---------- register FFT codelets (fft4/fft8/fft16 verified R2-R19) ----------
template<int SGN>
__device__ __forceinline__ void fft4(float2* f) {
    float2 t0 = make_float2(f[0].x + f[2].x, f[0].y + f[2].y);
    float2 t1 = make_float2(f[0].x - f[2].x, f[0].y - f[2].y);
    float2 t2 = make_float2(f[1].x + f[3].x, f[1].y + f[3].y);
    float2 t3 = make_float2(f[1].x - f[3].x, f[1].y - f[3].y);
    float2 t3i = (SGN > 0) ? make_float2(-t3.y, t3.x) : make_float2(t3.y, -t3.x);
    f[0] = make_float2(t0.x + t2.x, t0.y + t2.y);
    f[1] = make_float2(t1.x + t3i.x, t1.y + t3i.y);
    f[2] = make_float2(t0.x - t2.x, t0.y - t2.y);
    f[3] = make_float2(t1.x - t3i.x, t1.y - t3i.y);
}

template<int SGN>
__device__ __forceinline__ void fft8(float2* f) {
    const float R = 0.70710678118654752f;
    const float WC[4] = {1.f, R, 0.f, -R};
    const float WS[4] = {0.f, R, 1.f, R};
    #pragma unroll
    for (int stage = 0; stage < 3; ++stage) {
        const int L = 8 >> stage, half = L >> 1, step = 1 << stage;
        #pragma unroll
        for (int base = 0; base < 8; base += L) {
            #pragma unroll
            for (int j = 0; j < half; ++j) {
                float2 u = f[base + j], v = f[base + half + j];
                f[base + j] = make_float2(u.x + v.x, u.y + v.y);
                float dx = u.x - v.x, dy = u.y - v.y;
                const int t = j * step;
                const float wr = WC[t];
                const float wi = (SGN > 0) ? WS[t] : -WS[t];
                f[base + half + j] = make_float2(dx * wr - dy * wi, dx * wi + dy * wr);
            }
        }
    }
    float2 tmp;
    tmp = f[1]; f[1] = f[4]; f[4] = tmp;
    tmp = f[3]; f[3] = f[6]; f[6] = tmp;
}

template<int SGN>
__device__ __forceinline__ void fft16(float2* f) {
    const float WC[8] = {1.f, 0.92387953251f, 0.70710678119f, 0.38268343236f,
                         0.f, -0.38268343236f, -0.70710678119f, -0.92387953251f};
    const float WS[8] = {0.f, 0.38268343236f, 0.70710678119f, 0.92387953251f,
                         1.f, 0.92387953251f, 0.70710678119f, 0.38268343236f};
    #pragma unroll
    for (int stage = 0; stage < 4; ++stage) {
        const int L = 16 >> stage, half = L >> 1, step = 1 << stage;
        #pragma unroll
        for (int base = 0; base < 16; base += L) {
            #pragma unroll
            for (int j = 0; j < half; ++j) {
                float2 u = f[base + j], v = f[base + half + j];
                f[base + j] = make_float2(u.x + v.x, u.y + v.y);
                float dx = u.x - v.x, dy = u.y - v.y;
                const int t = j * step;
                const float wr = WC[t];
                const float wi = (SGN > 0) ? WS[t] : -WS[t];
                f[base + half + j] = make_float2(dx * wr - dy * wi, dx * wi + dy * wr);
            }
        }
    }
    float2 tmp;
    tmp = f[1];  f[1]  = f[8];  f[8]  = tmp;
    tmp = f[2];  f[2]  = f[4];  f[4]  = tmp;
    tmp = f[3];  f[3]  = f[12]; f[12] = tmp;
    tmp = f[5];  f[5]  = f[10]; f[10] = tmp;
    tmp = f[7];  f[7]  = f[14]; f[14] = tmp;
    tmp = f[11]; f[11] = f[13]; f[13] = tmp;
}

__device__ __forceinline__ float waveReduceSum(float v) {
    #pragma unroll
    for (int off = 32; off > 0; off >>= 1) v += __shfl_down(v, off, 64);
    return v;
}

__device__ __forceinline__ void buildTw(float2* tw, int tid) {
    if (tid < 128) {
        float s, c;
        __sincosf((float)tid * 0.04908738521234052f, &s, &c);   // 2*pi/128
        tw[tid] = make_float2(c, s);
    }
}

// ======== 32-grid 4-filter inverse pass (R17 proven) ========
__device__ __forceinline__ float pass32x4(float4* __restrict__ P4a,
                                          float4* __restrict__ P4b,
                                          const float2* __restrict__ tw, int tid) {
    __syncthreads();
    {   // col stepA
        float4* P = (tid & 256) ? P4b : P4a;
        int line = tid & 31, a = (tid >> 5) & 7;
        float2 f0[4], f1[4];
        #pragma unroll
        for (int kb = 0; kb < 4; ++kb) {
            float4 v = P[(4 * a + kb) * SG32 + line];
            f0[kb] = make_float2(v.x, v.y); f1[kb] = make_float2(v.z, v.w);
        }
        fft4<1>(f0); fft4<1>(f1);
        #pragma unroll
        for (int t = 0; t < 4; ++t) {
            float2 w = tw[4 * t * a];
            float2 aa = cmul(f0[t], w), d = cmul(f1[t], w);
            P[(4 * a + t) * SG32 + line] = make_float4(aa.x, aa.y, d.x, d.y);
        }
    }
    __syncthreads();
    if (tid < 256) {   // col stepB
        float4* P = (tid & 128) ? P4b : P4a;
        int line = tid & 31, t = (tid >> 5) & 3;
        float2 f0[8], f1[8];
        #pragma unroll
        for (int a = 0; a < 8; ++a) {
            float4 v = P[(4 * a + t) * SG32 + line];
            f0[a] = make_float2(v.x, v.y); f1[a] = make_float2(v.z, v.w);
        }
        fft8<1>(f0); fft8<1>(f1);
        #pragma unroll
        for (int n1 = 0; n1 < 8; ++n1)
            P[(4 * n1 + t) * SG32 + line] =
                make_float4(f0[n1].x, f0[n1].y, f1[n1].x, f1[n1].y);
    }
    __syncthreads();
    {   // row stepA
        float4* P = (tid & 256) ? P4b : P4a;
        int row = tid & 31, a = (tid >> 5) & 7;
        float4* R = P + row * SG32 + 4 * a;
        float2 f0[4], f1[4];
        #pragma unroll
        for (int kb = 0; kb < 4; ++kb) {
            float4 v = R[kb];
            f0[kb] = make_float2(v.x, v.y); f1[kb] = make_float2(v.z, v.w);
        }
        fft4<1>(f0); fft4<1>(f1);
        #pragma unroll
        for (int t = 0; t < 4; ++t) {
            float2 w = tw[4 * t * a];
            float2 aa = cmul(f0[t], w), d = cmul(f1[t], w);
            R[t] = make_float4(aa.x, aa.y, d.x, d.y);
        }
    }
    __syncthreads();
    float a2 = 0.f;
    if (tid < 256) {   // row stepB + mag
        float4* P = (tid & 128) ? P4b : P4a;
        int row = tid & 31, t = (tid >> 5) & 3;
        float4* R = P + row * SG32 + t;
        float2 f0[8], f1[8];
        #pragma unroll
        for (int a = 0; a < 8; ++a) {
            float4 v = R[4 * a];
            f0[a] = make_float2(v.x, v.y); f1[a] = make_float2(v.z, v.w);
        }
        fft8<1>(f0); fft8<1>(f1);
        #pragma unroll
        for (int n1 = 0; n1 < 8; ++n1) {
            a2 += sqrtf(f0[n1].x * f0[n1].x + f0[n1].y * f0[n1].y);
            a2 += sqrtf(f1[n1].x * f1[n1].x + f1[n1].y * f1[n1].y);
        }
    }
    return a2;
}

// ======== R18: fused 8-filter 32-grid pass (SMALL j1=1 only) ========
__device__ __forceinline__ void pass32combo(float2* __restrict__ Q0, float2* __restrict__ Q1,
                                            float2* __restrict__ Q2, float2* __restrict__ Q3,
                                            float4* __restrict__ Pa, float4* __restrict__ Pb,
                                            const float2* __restrict__ tw, int tid,
                                            float& aq, float& ap) {
    __syncthreads();
    {   // col stepA: threads 0-255 {Q0,Q1,Pa}; 256-511 {Q2,Q3,Pb}
        float2* Qx = (tid & 256) ? Q2 : Q0;
        float2* Qy = (tid & 256) ? Q3 : Q1;
        float4* P  = (tid & 256) ? Pb : Pa;
        int line = tid & 31, a = (tid >> 5) & 7;
        float2 q0[4], q1[4], f0[4], f1[4];
        #pragma unroll
        for (int kb = 0; kb < 4; ++kb) {
            int o = (4 * a + kb) * SG32 + line;
            q0[kb] = Qx[o]; q1[kb] = Qy[o];
            float4 v = P[o];
            f0[kb] = make_float2(v.x, v.y); f1[kb] = make_float2(v.z, v.w);
        }
        fft4<1>(q0); fft4<1>(q1); fft4<1>(f0); fft4<1>(f1);
        #pragma unroll
        for (int t = 0; t < 4; ++t) {
            float2 w = tw[4 * t * a];
            int o = (4 * a + t) * SG32 + line;
            Qx[o] = cmul(q0[t], w); Qy[o] = cmul(q1[t], w);
            float2 aa = cmul(f0[t], w), d = cmul(f1[t], w);
            P[o] = make_float4(aa.x, aa.y, d.x, d.y);
        }
    }
    __syncthreads();
    if (tid < 256) {   // col stepB
        float2* Qx = (tid & 128) ? Q2 : Q0;
        float2* Qy = (tid & 128) ? Q3 : Q1;
        float4* P  = (tid & 128) ? Pb : Pa;
        int line = tid & 31, t = (tid >> 5) & 3;
        float2 q0[8], q1[8], f0[8], f1[8];
        #pragma unroll
        for (int a = 0; a < 8; ++a) {
            int o = (4 * a + t) * SG32 + line;
            q0[a] = Qx[o]; q1[a] = Qy[o];
            float4 v = P[o];
            f0[a] = make_float2(v.x, v.y); f1[a] = make_float2(v.z, v.w);
        }
        fft8<1>(q0); fft8<1>(q1); fft8<1>(f0); fft8<1>(f1);
        #pragma unroll
        for (int n1 = 0; n1 < 8; ++n1) {
            int o = (4 * n1 + t) * SG32 + line;
            Qx[o] = q0[n1]; Qy[o] = q1[n1];
            P[o] = make_float4(f0[n1].x, f0[n1].y, f1[n1].x, f1[n1].y);
        }
    }
    __syncthreads();
    {   // row stepA
        float2* Qx = (tid & 256) ? Q2 : Q0;
        float2* Qy = (tid & 256) ? Q3 : Q1;
        float4* P  = (tid & 256) ? Pb : Pa;
        int row = tid & 31, a = (tid >> 5) & 7;
        int base = row * SG32 + 4 * a;
        float2 q0[4], q1[4], f0[4], f1[4];
        #pragma unroll
        for (int kb = 0; kb < 4; ++kb) {
            q0[kb] = Qx[base + kb]; q1[kb] = Qy[base + kb];
            float4 v = P[base + kb];
            f0[kb] = make_float2(v.x, v.y); f1[kb] = make_float2(v.z, v.w);
        }
        fft4<1>(q0); fft4<1>(q1); fft4<1>(f0); fft4<1>(f1);
        #pragma unroll
        for (int t = 0; t < 4; ++t) {
            float2 w = tw[4 * t * a];
            Qx[base + t] = cmul(q0[t], w); Qy[base + t] = cmul(q1[t], w);
            float2 aa = cmul(f0[t], w), d = cmul(f1[t], w);
            P[base + t] = make_float4(aa.x, aa.y, d.x, d.y);
        }
    }
    __syncthreads();
    aq = 0.f; ap = 0.f;
    if (tid < 256) {   // row stepB + mag (split accumulators)
        float2* Qx = (tid & 128) ? Q2 : Q0;
        float2* Qy = (tid & 128) ? Q3 : Q1;
        float4* P  = (tid & 128) ? Pb : Pa;
        int row = tid & 31, t = (tid >> 5) & 3;
        int base = row * SG32 + t;
        float2 q0[8], q1[8], f0[8], f1[8];
        #pragma unroll
        for (int a = 0; a < 8; ++a) {
            int o = base + 4 * a;
            q0[a] = Qx[o]; q1[a] = Qy[o];
            float4 v = P[o];
            f0[a] = make_float2(v.x, v.y); f1[a] = make_float2(v.z, v.w);
        }
        fft8<1>(q0); fft8<1>(q1); fft8<1>(f0); fft8<1>(f1);
        #pragma unroll
        for (int n1 = 0; n1 < 8; ++n1) {
            aq += sqrtf(q0[n1].x * q0[n1].x + q0[n1].y * q0[n1].y);
            aq += sqrtf(q1[n1].x * q1[n1].x + q1[n1].y * q1[n1].y);
            ap += sqrtf(f0[n1].x * f0[n1].x + f0[n1].y * f0[n1].y);
            ap += sqrtf(f1[n1].x * f1[n1].x + f1[n1].y * f1[n1].y);
        }
    }
}

// ======== 128-grid sweep phases (R6-R13 proven, TT=512) ========
template<int ES, int LS>
__device__ __forceinline__ void fwdA(float2* __restrict__ F,
                                     const float2* __restrict__ tw, int tid) {
    #pragma unroll
    for (int i = 0; i < 4; ++i) {
        int u = i * TT + tid;
        int t = u >> 7, x = u & 127;
        float2* M = F + x * LS;
        float2 f[8];
        #pragma unroll
        for (int n1 = 0; n1 < 8; ++n1) f[n1] = M[(t + 16 * n1) * ES];
        fft8<-1>(f);
        #pragma unroll
        for (int ka = 0; ka < 8; ++ka)
            M[(t + 16 * ka) * ES] = cmulc(f[ka], tw[t * ka]);
    }
}

template<int ES, int LS>
__device__ __forceinline__ void fwdB(float2* __restrict__ F, int tid) {
    #pragma unroll
    for (int i = 0; i < 2; ++i) {
        int u = i * TT + tid;
        int ka = u >> 7, x = u & 127;
        float2* M = F + x * LS;
        float2 g[16];
        #pragma unroll
        for (int t = 0; t < 16; ++t) g[t] = M[(16 * ka + t) * ES];
        fft16<-1>(g);
        #pragma unroll
        for (int kb = 0; kb < 16; ++kb) M[(16 * ka + kb) * ES] = g[kb];
    }
}

__device__ __forceinline__ void fwdB_col_capture(const float2* __restrict__ F, int tid,
                                                 float2* __restrict__ uh) {
    #pragma unroll
    for (int i = 0; i < 2; ++i) {
        int u = i * TT + tid;
        int ka = u >> 7, c = u & 127;
        float2 g[16];
        #pragma unroll
        for (int t = 0; t < 16; ++t) g[t] = F[(16 * ka + t) * SS + c];
        fft16<-1>(g);
        #pragma unroll
        for (int kb = 0; kb < 16; ++kb) uh[i * 16 + kb] = g[kb];
    }
}

template<int ES, int LS>
__device__ __forceinline__ void invA(float2* __restrict__ F,
                                     const float2* __restrict__ tw, int tid) {
    #pragma unroll
    for (int i = 0; i < 2; ++i) {
        int u = i * TT + tid;
        int ka = u >> 7, x = u & 127;
        float2* M = F + x * LS;
        float2 g[16];
        #pragma unroll
        for (int kb = 0; kb < 16; ++kb) g[kb] = M[(16 * ka + kb) * ES];
        fft16<1>(g);
        #pragma unroll
        for (int t = 0; t < 16; ++t)
            M[(16 * ka + t) * ES] = cmul(g[t], tw[t * ka]);
    }
}

template<int ES, int LS>
__device__ __forceinline__ void invB(float2* __restrict__ F, int tid) {
    #pragma unroll
    for (int i = 0; i < 4; ++i) {
        int u = i * TT + tid;
        int t = u >> 7, x = u & 127;
        float2* M = F + x * LS;
        float2 f[8];
        #pragma unroll
        for (int ka = 0; ka < 8; ++ka) f[ka] = M[(16 * ka + t) * ES];
        fft8<1>(f);
        #pragma unroll
        for (int nh = 0; nh < 8; ++nh) M[(t + 16 * nh) * ES] = f[nh];
    }
}

// FUSED: inverse row stepB -> |.| (raw, acc) -> forward row stepA (same cells).
__device__ __forceinline__ void invBmag_fwdA_row(float2* __restrict__ F,
                                                 const float2* __restrict__ tw,
                                                 int tid, float& acc) {
    #pragma unroll
    for (int i = 0; i < 4; ++i) {
        int u = i * TT + tid;
        int t = u >> 7, x = u & 127;
        float2* M = F + x * SS;
        float2 f[8];
        #pragma unroll
        for (int ka = 0; ka < 8; ++ka) f[ka] = M[16 * ka + t];
        fft8<1>(f);
        #pragma unroll
        for (int nh = 0; nh < 8; ++nh) {
            float m = sqrtf(f[nh].x * f[nh].x + f[nh].y * f[nh].y);
            acc += m;
            f[nh] = make_float2(m, 0.f);
        }
        fft8<-1>(f);
        #pragma unroll
        for (int ka = 0; ka < 8; ++ka)
            M[t + 16 * ka] = cmulc(f[ka], tw[t * ka]);
    }
}

// ---------- K_pre1 (R19/R20): row-strip FFT along c + filters + zero ----------
// blocks 0..255: (b = blk>>2, q = blk&3) rows [32q, 32q+32) of image b.
// blocks 256..383: filter bank, 16 filters x 8 chunks. block 384: zero coeffs.
__global__ __attribute__((amdgpu_flat_work_group_size(TT, TT), amdgpu_waves_per_eu(4, 4)))
void k_pre1(const float* __restrict__ img,
            float* __restrict__ psi,
            float2* __restrict__ interm,
            float* __restrict__ coeffs) {
    __shared__ __align__(16) float2 F[32 * SS];
    __shared__ float2 tw[128];
    int blk = blockIdx.x, tid = threadIdx.x;
    if (blk >= 256) {
        if (blk == 384) {
            for (int i = tid; i < 64 * 11; i += TT) coeffs[i] = 0.f;
            return;
        }
        int fb = blk - 256;
        int f = fb >> 3, chunk = fb & 7;          // 16 filters x 8 chunks
        int j = f >> 2, l = f & 3;
        float k0    = 2.35619449019234493f / (float)(1 << j);
        float sigma = 0.8f * (float)(1 << j);
        float s2    = sigma * sigma;
        float theta = 0.78539816339744831f * (float)l;
        float k0x = k0 * cosf(theta);
        float k0y = k0 * sinf(theta);
        float beta = expf(-0.5f * s2 * k0 * k0);
        const float FSTEP = 0.04908738521234052f;
        float* dst = psi + (size_t)f * NPIX;
        int i0 = chunk * 2048, i1 = i0 + 2048;
        for (int i = i0 + tid; i < i1; i += TT) {
            int pr = i >> 7, pc = i & 127;
            int kr = (pr >> 4) + 8 * (pr & 15);
            int kc = (pc >> 4) + 8 * (pc & 15);
            float fr = (float)(kr < 64 ? kr : kr - 128) * FSTEP;
            float fc = (float)(kc < 64 ? kc : kc - 128) * FSTEP;
            float dx = fr - k0x, dy = fc - k0y;
            float g1 = expf(-0.5f * s2 * (dx * dx + dy * dy));
            float g0 = expf(-0.5f * s2 * (fr * fr + fc * fc));
            dst[i] = g1 - beta * g0;
        }
        return;
    }
    int b = blk >> 2, q = blk & 3;
    buildTw(tw, tid);
    const float* im = img + (size_t)b * NPIX + (size_t)q * 32 * NN;
    #pragma unroll
    for (int k = 0; k < 8; ++k) {
        int e = k * TT + tid;                      // 0..4095
        F[(e >> 7) * SS + (e & 127)] = make_float2(im[e], 0.f);
    }
    __syncthreads();
    {   // stepA along c (fft8): 32 rows x 16 t = 512
        int x = tid & 31, t = tid >> 5;
        float2* M = F + x * SS;
        float2 f[8];
        #pragma unroll
        for (int n1 = 0; n1 < 8; ++n1) f[n1] = M[t + 16 * n1];
        fft8<-1>(f);
        #pragma unroll
        for (int ka = 0; ka < 8; ++ka)
            M[t + 16 * ka] = cmulc(f[ka], tw[t * ka]);
    }
    __syncthreads();
    if (tid < 256) {   // stepB along c (fft16): 32 rows x 8 ka
        int x = tid & 31, ka = tid >> 5;
        float2* M = F + x * SS + 16 * ka;
        float2 g[16];
        #pragma unroll
        for (int t = 0; t < 16; ++t) g[t] = M[t];
        fft16<-1>(g);
        #pragma unroll
        for (int kb = 0; kb < 16; ++kb) M[kb] = g[kb];
    }
    __syncthreads();
    float2* dst = interm + (size_t)b * NPIX + (size_t)q * 32 * NN;
    #pragma unroll
    for (int k = 0; k < 8; ++k) {
        int e = k * TT + tid;
        dst[e] = F[(e >> 7) * SS + (e & 127)];
    }
}

// ---------- K_pre2 (R19/R20): col-strip FFT along r + capture + s0 ----------
__global__ __attribute__((amdgpu_flat_work_group_size(TT, TT), amdgpu_waves_per_eu(4, 4)))
void k_pre2(float2* __restrict__ ihat,
            float* __restrict__ coeffs) {
    __shared__ __align__(16) float2 F[128 * 33];
    __shared__ float2 tw[128];
    int blk = blockIdx.x, tid = threadIdx.x;
    int b = blk >> 2, q = blk & 3;
    buildTw(tw, tid);
    float2* base = ihat + (size_t)b * NPIX + q * 32;
    #pragma unroll
    for (int k = 0; k < 8; ++k) {
        int e = k * TT + tid;                      // 0..4095
        int r = e >> 5, cl = e & 31;
        F[r * 33 + cl] = base[r * NN + cl];
    }
    __syncthreads();
    {   // stepA along r (fft8): 32 cols x 16 t = 512
        int cl = tid & 31, t = tid >> 5;
        float2 f[8];
        #pragma unroll
        for (int n1 = 0; n1 < 8; ++n1) f[n1] = F[(t + 16 * n1) * 33 + cl];
        fft8<-1>(f);
        #pragma unroll
        for (int ka = 0; ka < 8; ++ka)
            F[(t + 16 * ka) * 33 + cl] = cmulc(f[ka], tw[t * ka]);
    }
    __syncthreads();
    if (tid < 256) {   // stepB along r (fft16) + store + s0
        int cl = tid & 31, ka = tid >> 5;
        float2 g[16];
        #pragma unroll
        for (int t = 0; t < 16; ++t) g[t] = F[(16 * ka + t) * 33 + cl];
        fft16<-1>(g);
        float2* dst = base + cl;
        #pragma unroll
        for (int kb = 0; kb < 16; ++kb)
            dst[(16 * ka + kb) * NN] = g[kb];
        if (q == 0 && cl == 0 && ka == 0)
            coeffs[b * 11 + 0] = g[0].x * (1.f / 16384.f);
    }
}

// ---------- K_scat_big: j1 = 0 ONLY (grid 256 = one round; R4-proven form) ----------
__global__ __attribute__((amdgpu_flat_work_group_size(TT, TT), amdgpu_waves_per_eu(2, 2)))
void k_scat_big(const float2* __restrict__ ihat,
                const float* __restrict__ psi,
                float* __restrict__ coeffs) {
    // F: 16640 float2 = 133,120 B.
    //   128-grid phases: F[0..16512) stride SS.
    //   j2=1 one-pass: G2a..G2d = F + {0,4160,8320,12480}  (4x 64x65 float2)
    //   j2=2 pass:     G4a = (float4*)F, G4b = (float4*)(F+8320) (2x 64x65 float4)
    //   j2=3 pass:     P4a/P4b = two 32x33 float4 grids at F[0..4224)  (R17)
    __shared__ __align__(16) float2 F[16640];
    __shared__ float2 tw[128];
    float4* G4a = (float4*)F;
    float4* G4b = (float4*)(F + 8320);
    float2* G2a = F;
    float2* G2b = F + 4160;
    float2* G2c = F + 8320;
    float2* G2d = F + 12480;
    float4* P4a = (float4*)F;
    float4* P4b = (float4*)F + 1056;
    int tid = threadIdx.x;
    int x = blockIdx.x;
    int b = x & 63, l1 = x >> 6;                       // j1 == 0
    const float2* ih = ihat + (size_t)b * NPIX;
    const float*  p1 = psi + (size_t)l1 * NPIX;
    buildTw(tw, tid);

    const float S1_128 = 9.3132257461547852e-10f;   // 2^-30
    const float S2TR   = 5.6843418860808015e-14f;   // 2^-44
    const float S2_03  = 2.2737367544323206e-13f;   // 2^-42 = 4*S2TR (32-grid)

    int kalo = tid >> 7, c = tid & 127;
    {
        #pragma unroll
        for (int i = 0; i < 2; ++i) {
            int ka = kalo + 4 * i;
            float2 g[16];
            #pragma unroll
            for (int kb = 0; kb < 16; ++kb) {
                int e = (16 * ka + kb) * NN + c;
                float2 z = ih[e];
                float  p = p1[e];
                g[kb] = make_float2(z.x * p, z.y * p);
            }
            fft16<1>(g);
            #pragma unroll
            for (int t = 0; t < 16; ++t)
                F[(16 * ka + t) * SS + c] = cmul(g[t], tw[t * ka]);
        }
    }
    __syncthreads();
    invB<SS, 1>(F, tid);      __syncthreads();
    invA<1, SS>(F, tw, tid);  __syncthreads();
    float acc = 0.f;
    invBmag_fwdA_row(F, tw, tid, acc);
    float ws1 = waveReduceSum(acc);
    if ((tid & 63) == 0) atomicAdd(&coeffs[b * 11 + 1], ws1 * S1_128);
    __syncthreads();
    fwdB<1, SS>(F, tid);      __syncthreads();
    fwdA<SS, 1>(F, tw, tid);  __syncthreads();
    float2 uh[32];
    fwdB_col_capture(F, tid, uh);
    __syncthreads();   // capture done -> F reusable (grids alias it)

    // trunc-staging column perm (central +-32 window), for j2=2
    int m = c & 15;
    bool colKeep = (m < 4) || (m >= 12);
    int pc64 = 8 * (c >> 4) + ((m < 4) ? m : (m - 8));
    int fc = (c >> 4) + 8 * (c & 15);

    {
        // ===== (j1=0, j2=1): ONE pass, 4 off-center 64-windows (R14 mapping) =====
        const int ORW[4] = {21, 15, 0, -15};
        const int OCW[4] = { 0, 15, 21,  15};
        bool ckw[4]; int pcw[4];
        #pragma unroll
        for (int w = 0; w < 4; ++w) {
            int dc = (fc - OCW[w]) & 127;
            ckw[w] = (dc < 32) || (dc >= 96);
            int uc = (dc < 32) ? dc : (dc - 64);
            pcw[w] = 8 * (uc & 7) + (uc >> 3);
        }
        #pragma unroll
        for (int i = 0; i < 2; ++i) {
            int ka = kalo + 4 * i;
            #pragma unroll
            for (int kb = 0; kb < 16; ++kb) {
                int fr = ka + 8 * kb;
                float2 z = uh[i * 16 + kb];
                int e = (16 * ka + kb) * NN + c;
                #pragma unroll
                for (int w = 0; w < 4; ++w) {
                    if (ckw[w]) {
                        int dr = (fr - ORW[w]) & 127;
                        if (dr < 32 || dr >= 96) {
                            int ur = (dr < 32) ? dr : (dr - 64);
                            int pr = 8 * (ur & 7) + (ur >> 3);
                            float pv = psi[(size_t)(4 + w) * NPIX + e];
                            float2* G = (w == 0) ? G2a : (w == 1) ? G2b
                                       : (w == 2) ? G2c : G2d;
                            G[pr * SG + pcw[w]] = make_float2(z.x * pv, z.y * pv);
                        }
                    }
                }
            }
        }
        __syncthreads();
        {   // col stepA (4 grids, full width)
            int col = tid & 63, k8 = tid >> 6;
            float2 f0[8], f1[8], f2[8], f3[8];
            #pragma unroll
            for (int kb = 0; kb < 8; ++kb) {
                int o = (8 * k8 + kb) * SG + col;
                f0[kb] = G2a[o]; f1[kb] = G2b[o]; f2[kb] = G2c[o]; f3[kb] = G2d[o];
            }
            fft8<1>(f0); fft8<1>(f1); fft8<1>(f2); fft8<1>(f3);
            #pragma unroll
            for (int q = 0; q < 8; ++q) {
                float2 w = tw[2 * q * k8];
                int o = (8 * k8 + q) * SG + col;
                G2a[o] = cmul(f0[q], w); G2b[o] = cmul(f1[q], w);
                G2c[o] = cmul(f2[q], w); G2d[o] = cmul(f3[q], w);
            }
        }
        __syncthreads();
        {   // col stepB
            int col = tid & 63, q = tid >> 6;
            float2 f0[8], f1[8], f2[8], f3[8];
            #pragma unroll
            for (int k8 = 0; k8 < 8; ++k8) {
                int o = (8 * k8 + q) * SG + col;
                f0[k8] = G2a[o]; f1[k8] = G2b[o]; f2[k8] = G2c[o]; f3[k8] = G2d[o];
            }
            fft8<1>(f0); fft8<1>(f1); fft8<1>(f2); fft8<1>(f3);
            #pragma unroll
            for (int n1 = 0; n1 < 8; ++n1) {
                int o = (8 * n1 + q) * SG + col;
                G2a[o] = f0[n1]; G2b[o] = f1[n1]; G2c[o] = f2[n1]; G2d[o] = f3[n1];
            }
        }
        __syncthreads();
        {   // row stepA
            int row = tid & 63, k8 = tid >> 6;
            int base = row * SG + 8 * k8;
            float2 f0[8], f1[8], f2[8], f3[8];
            #pragma unroll
            for (int kb = 0; kb < 8; ++kb) {
                f0[kb] = G2a[base + kb]; f1[kb] = G2b[base + kb];
                f2[kb] = G2c[base + kb]; f3[kb] = G2d[base + kb];
            }
            fft8<1>(f0); fft8<1>(f1); fft8<1>(f2); fft8<1>(f3);
            #pragma unroll
            for (int q = 0; q < 8; ++q) {
                float2 w = tw[2 * q * k8];
                G2a[base + q] = cmul(f0[q], w); G2b[base + q] = cmul(f1[q], w);
                G2c[base + q] = cmul(f2[q], w); G2d[base + q] = cmul(f3[q], w);
            }
        }
        __syncthreads();
        float a2 = 0.f;
        {   // row stepB + mag (all 4 -> same coeff)
            int row = tid & 63, q = tid >> 6;
            int base = row * SG + q;
            float2 f0[8], f1[8], f2[8], f3[8];
            #pragma unroll
            for (int k8 = 0; k8 < 8; ++k8) {
                int o = base + 8 * k8;
                f0[k8] = G2a[o]; f1[k8] = G2b[o]; f2[k8] = G2c[o]; f3[k8] = G2d[o];
            }
            fft8<1>(f0); fft8<1>(f1); fft8<1>(f2); fft8<1>(f3);
            #pragma unroll
            for (int n1 = 0; n1 < 8; ++n1) {
                a2 += sqrtf(f0[n1].x * f0[n1].x + f0[n1].y * f0[n1].y);
                a2 += sqrtf(f1[n1].x * f1[n1].x + f1[n1].y * f1[n1].y);
                a2 += sqrtf(f2[n1].x * f2[n1].x + f2[n1].y * f2[n1].y);
                a2 += sqrtf(f3[n1].x * f3[n1].x + f3[n1].y * f3[n1].y);
            }
        }
        float ws2 = waveReduceSum(a2);
        if ((tid & 63) == 0) atomicAdd(&coeffs[b * 11 + 5 + 0], ws2 * S2TR);
        __syncthreads();
    }

    {   // ===== (0,2): ONE pass, 4 filters, central +-32 64-grid (R4-proven) =====
        const float* p0 = psi + (size_t)8 * NPIX;
        const float* pq1 = p0 + NPIX;
        const float* pq2 = pq1 + NPIX;
        const float* pq3 = pq2 + NPIX;
        if (colKeep) {
            #pragma unroll
            for (int i = 0; i < 2; ++i) {
                int ka = kalo + 4 * i;
                #pragma unroll
                for (int kb = 0; kb < 16; ++kb) {
                    if (kb < 4 || kb >= 12) {
                        int pr64 = 8 * ka + ((kb < 4) ? kb : (kb - 8));
                        float2 z = uh[i * 16 + kb];
                        int e = (16 * ka + kb) * NN + c;
                        float a0 = p0[e], a1 = pq1[e], a2f = pq2[e], a3 = pq3[e];
                        G4a[pr64 * SG + pc64] =
                            make_float4(z.x * a0, z.y * a0, z.x * a1, z.y * a1);
                        G4b[pr64 * SG + pc64] =
                            make_float4(z.x * a2f, z.y * a2f, z.x * a3, z.y * a3);
                    }
                }
            }
        }
        __syncthreads();
        {   // col stepA (two packed grids = 4 filters, full width)
            int col = tid & 63, k8 = tid >> 6;
            float2 f0[8], f1[8], f2[8], f3[8];
            #pragma unroll
            for (int kb = 0; kb < 8; ++kb) {
                int o = (8 * k8 + kb) * SG + col;
                float4 v = G4a[o];
                f0[kb] = make_float2(v.x, v.y); f1[kb] = make_float2(v.z, v.w);
                float4 u = G4b[o];
                f2[kb] = make_float2(u.x, u.y); f3[kb] = make_float2(u.z, u.w);
            }
            fft8<1>(f0); fft8<1>(f1); fft8<1>(f2); fft8<1>(f3);
            #pragma unroll
            for (int q = 0; q < 8; ++q) {
                float2 w = tw[2 * q * k8];
                int o = (8 * k8 + q) * SG + col;
                float2 a = cmul(f0[q], w), d = cmul(f1[q], w);
                G4a[o] = make_float4(a.x, a.y, d.x, d.y);
                float2 a2c = cmul(f2[q], w), d2 = cmul(f3[q], w);
                G4b[o] = make_float4(a2c.x, a2c.y, d2.x, d2.y);
            }
        }
        __syncthreads();
        {   // col stepB
            int col = tid & 63, q = tid >> 6;
            float2 f0[8], f1[8], f2[8], f3[8];
            #pragma unroll
            for (int k8 = 0; k8 < 8; ++k8) {
                int o = (8 * k8 + q) * SG + col;
                float4 v = G4a[o];
                f0[k8] = make_float2(v.x, v.y); f1[k8] = make_float2(v.z, v.w);
                float4 u = G4b[o];
                f2[k8] = make_float2(u.x, u.y); f3[k8] = make_float2(u.z, u.w);
            }
            fft8<1>(f0); fft8<1>(f1); fft8<1>(f2); fft8<1>(f3);
            #pragma unroll
            for (int n1 = 0; n1 < 8; ++n1) {
                int o = (8 * n1 + q) * SG + col;
                G4a[o] = make_float4(f0[n1].x, f0[n1].y, f1[n1].x, f1[n1].y);
                G4b[o] = make_float4(f2[n1].x, f2[n1].y, f3[n1].x, f3[n1].y);
            }
        }
        __syncthreads();
        {   // row stepA
            int row = tid & 63, k8 = tid >> 6;
            int base = row * SG + 8 * k8;
            float2 f0[8], f1[8], f2[8], f3[8];
            #pragma unroll
            for (int kb = 0; kb < 8; ++kb) {
                float4 v = G4a[base + kb];
                f0[kb] = make_float2(v.x, v.y); f1[kb] = make_float2(v.z, v.w);
                float4 u = G4b[base + kb];
                f2[kb] = make_float2(u.x, u.y); f3[kb] = make_float2(u.z, u.w);
            }
            fft8<1>(f0); fft8<1>(f1); fft8<1>(f2); fft8<1>(f3);
            #pragma unroll
            for (int q = 0; q < 8; ++q) {
                float2 w = tw[2 * q * k8];
                float2 a = cmul(f0[q], w), d = cmul(f1[q], w);
                G4a[base + q] = make_float4(a.x, a.y, d.x, d.y);
                float2 a2c = cmul(f2[q], w), d2 = cmul(f3[q], w);
                G4b[base + q] = make_float4(a2c.x, a2c.y, d2.x, d2.y);
            }
        }
        __syncthreads();
        float a2 = 0.f;
        {   // row stepB + mag
            int row = tid & 63, q = tid >> 6;
            int base = row * SG + q;
            float2 f0[8], f1[8], f2[8], f3[8];
            #pragma unroll
            for (int k8 = 0; k8 < 8; ++k8) {
                float4 v = G4a[base + 8 * k8];
                f0[k8] = make_float2(v.x, v.y); f1[k8] = make_float2(v.z, v.w);
                float4 u = G4b[base + 8 * k8];
                f2[k8] = make_float2(u.x, u.y); f3[k8] = make_float2(u.z, u.w);
            }
            fft8<1>(f0); fft8<1>(f1); fft8<1>(f2); fft8<1>(f3);
            #pragma unroll
            for (int n1 = 0; n1 < 8; ++n1) {
                a2 += sqrtf(f0[n1].x * f0[n1].x + f0[n1].y * f0[n1].y);
                a2 += sqrtf(f1[n1].x * f1[n1].x + f1[n1].y * f1[n1].y);
                a2 += sqrtf(f2[n1].x * f2[n1].x + f2[n1].y * f2[n1].y);
                a2 += sqrtf(f3[n1].x * f3[n1].x + f3[n1].y * f3[n1].y);
            }
        }
        float ws2 = waveReduceSum(a2);
        if ((tid & 63) == 0) atomicAdd(&coeffs[b * 11 + 5 + 1], ws2 * S2TR);
        __syncthreads();
    }

    {   // ===== (0,3): 32-grid 4-filter pass (R17-proven; central +-16 of uh) =====
        bool ck32 = (m < 2) || (m >= 14);
        int pc32 = 4 * (c >> 4) + ((m < 2) ? m : (m - 12));
        const float* p0 = psi + (size_t)12 * NPIX;
        const float* pq1 = p0 + NPIX;
        const float* pq2 = pq1 + NPIX;
        const float* pq3 = pq2 + NPIX;
        if (ck32) {
            #pragma unroll
            for (int i = 0; i < 2; ++i) {
                int ka = kalo + 4 * i;
                #pragma unroll
                for (int kb = 0; kb < 16; ++kb) {
                    if (kb < 2 || kb >= 14) {
                        int pr32 = 4 * ka + ((kb < 2) ? kb : (kb - 12));
                        float2 z = uh[i * 16 + kb];
                        int e = (16 * ka + kb) * NN + c;
                        float a0 = p0[e], a1 = pq1[e], a2f = pq2[e], a3 = pq3[e];
                        P4a[pr32 * SG32 + pc32] =
                            make_float4(z.x * a0, z.y * a0, z.x * a1, z.y * a1);
                        P4b[pr32 * SG32 + pc32] =
                            make_float4(z.x * a2f, z.y * a2f, z.x * a3, z.y * a3);
                    }
                }
            }
        }
        float a2 = pass32x4(P4a, P4b, tw, tid);
        float ws2 = waveReduceSum(a2);
        if ((tid & 63) == 0) atomicAdd(&coeffs[b * 11 + 5 + 2], ws2 * S2_03);
    }
}

// ---------- K_scat_small: j1 in {1,2,3} -- 67.6 KB LDS => 2 blocks/CU ----------
__global__ __attribute__((amdgpu_flat_work_group_size(TT, TT), amdgpu_waves_per_eu(4, 4)))
void k_scat_small(const float2* __restrict__ ihat,
                  const float* __restrict__ psi,
                  float* __restrict__ coeffs) {
    // S: 8448 float2 = 67,584 B.
    //   j1=1: G2 (64x65) = S[0..4160); combo Qs0..Qs3 = S+{0,1056,2112,3168};
    //         Psa=(float4*)(S+4224), Psb=(float4*)(S+6336)  (R18);
    //   j1=2 (R20): G32n = S[0..1056); P32a=(float4*)(S+1088) [S 1088..3200);
    //         P32b=(float4*)(S+3200) [S 3200..5312)  -- disjoint regions;
    //   j1=3: G32 aliases S[0..).
    __shared__ __align__(16) float2 S[8448];
    __shared__ float2 tw[128];
    float2* G2  = S;
    float2* G32 = S;
    float2* Qs0 = S;
    float2* Qs1 = S + 1056;
    float2* Qs2 = S + 2112;
    float2* Qs3 = S + 3168;
    float4* Psa = (float4*)(S + 4224);
    float4* Psb = (float4*)(S + 6336);
    int tid = threadIdx.x;
    int x = blockIdx.x;
    int b = x & 63, l1 = (x >> 6) & 3;
    int t0 = x >> 8;                          // 0 -> j1=1 (heavy, first), 1 -> j1=2, 2 -> j1=3
    const float2* ih = ihat + (size_t)b * NPIX;
    const float*  p1 = psi + (size_t)(((t0 == 0) ? 1 : (t0 + 1)) * 4 + l1) * NPIX;
    buildTw(tw, tid);

    const float S1_64 = 3.7252902984619141e-9f;    // 2^-28
    const float S1_32 = 1.4901161193847656e-8f;    // 2^-26
    const float S2_32 = 9.0949470177292824e-13f;   // 2^-40 (32-grid from V64)

    int kalo = tid >> 7, c = tid & 127;

    if (t0 == 0) {
        // =========== j1 = 1 on off-center 64-window (R16) ===========
        const int OR1[4] = {21, 15, 0, -15};
        const int OC1[4] = { 0, 15, 21,  15};
        int fc = (c >> 4) + 8 * (c & 15);
        int dc = (fc - OC1[l1]) & 127;
        bool ck = (dc < 32) || (dc >= 96);
        int ucw = (dc < 32) ? dc : (dc - 64);
        int pcd = 8 * (ucw & 7) + (ucw >> 3);
        if (ck) {
            #pragma unroll
            for (int i = 0; i < 2; ++i) {
                int ka = kalo + 4 * i;
                #pragma unroll
                for (int kb = 0; kb < 16; ++kb) {
                    int fr = ka + 8 * kb;
                    int dr = (fr - OR1[l1]) & 127;
                    if (dr < 32 || dr >= 96) {
                        int ur = (dr < 32) ? dr : (dr - 64);
                        int pr = 8 * (ur & 7) + (ur >> 3);
                        int e = (16 * ka + kb) * NN + c;
                        float2 z = ih[e];
                        float  p = p1[e];
                        G2[pr * SG + pcd] = make_float2(z.x * p, z.y * p);
                    }
                }
            }
        }
        __syncthreads();
        {   // col stepA (inverse)
            int col = tid & 63, k8 = tid >> 6;
            float2 f[8];
            #pragma unroll
            for (int kb = 0; kb < 8; ++kb) f[kb] = G2[(8 * k8 + kb) * SG + col];
            fft8<1>(f);
            #pragma unroll
            for (int q = 0; q < 8; ++q)
                G2[(8 * k8 + q) * SG + col] = cmul(f[q], tw[2 * q * k8]);
        }
        __syncthreads();
        {   // col stepB
            int col = tid & 63, q = tid >> 6;
            float2 f[8];
            #pragma unroll
            for (int k8 = 0; k8 < 8; ++k8) f[k8] = G2[(8 * k8 + q) * SG + col];
            fft8<1>(f);
            #pragma unroll
            for (int n1 = 0; n1 < 8; ++n1) G2[(8 * n1 + q) * SG + col] = f[n1];
        }
        __syncthreads();
        {   // row stepA (inverse)
            int row = tid & 63, k8 = tid >> 6;
            float2* R = G2 + row * SG + 8 * k8;
            float2 f[8];
            #pragma unroll
            for (int kb = 0; kb < 8; ++kb) f[kb] = R[kb];
            fft8<1>(f);
            #pragma unroll
            for (int q = 0; q < 8; ++q) R[q] = cmul(f[q], tw[2 * q * k8]);
        }
        __syncthreads();
        float acc = 0.f;
        {   // FUSED64: row stepB inv -> |.| -> row stepA fwd
            int row = tid & 63, q = tid >> 6;
            float2* R = G2 + row * SG + q;
            float2 f[8];
            #pragma unroll
            for (int k8 = 0; k8 < 8; ++k8) f[k8] = R[8 * k8];
            fft8<1>(f);
            #pragma unroll
            for (int n1 = 0; n1 < 8; ++n1) {
                float mg = sqrtf(f[n1].x * f[n1].x + f[n1].y * f[n1].y);
                acc += mg;
                f[n1] = make_float2(mg, 0.f);
            }
            fft8<-1>(f);
            #pragma unroll
            for (int ka = 0; ka < 8; ++ka)
                R[8 * ka] = cmulc(f[ka], tw[2 * q * ka]);
        }
        float ws1 = waveReduceSum(acc);
        if ((tid & 63) == 0) atomicAdd(&coeffs[b * 11 + 2], ws1 * S1_64);
        __syncthreads();
        {   // row stepB (forward)
            int row2 = tid & 63, ka = tid >> 6;
            float2* R2 = G2 + row2 * SG + 8 * ka;
            float2 g[8];
            #pragma unroll
            for (int t = 0; t < 8; ++t) g[t] = R2[t];
            fft8<-1>(g);
            #pragma unroll
            for (int kb = 0; kb < 8; ++kb) R2[kb] = g[kb];
        }
        __syncthreads();
        {   // col stepA (forward)
            int col = tid & 63, t = tid >> 6;
            float2 g[8];
            #pragma unroll
            for (int n1 = 0; n1 < 8; ++n1) g[n1] = G2[(t + 8 * n1) * SG + col];
            fft8<-1>(g);
            #pragma unroll
            for (int ka = 0; ka < 8; ++ka)
                G2[(t + 8 * ka) * SG + col] = cmulc(g[ka], tw[2 * t * ka]);
        }
        __syncthreads();
        float2 vh[8];
        int c6 = tid & 63, ka8 = tid >> 6;
        {   // col stepB (forward) -> V = u1hat_64 captured to registers
            float2 g[8];
            #pragma unroll
            for (int t = 0; t < 8; ++t) g[t] = G2[(8 * ka8 + t) * SG + c6];
            fft8<-1>(g);
            #pragma unroll
            for (int kb = 0; kb < 8; ++kb) vh[kb] = g[kb];
        }
        __syncthreads();   // G2 reads done -> combo grids (aliases) safe to write

        // psi gather indices: 64-grid storage p <-> freq u = 8*(p&7)+(p>>3);
        // 128-freq f128 = u<32 ? u : u+64; storage s = 16*(f128&7)+(f128>>3)
        int uc64 = 8 * (c6 & 7) + (c6 >> 3);
        int fc128 = (uc64 < 32) ? uc64 : (uc64 + 64);
        int scI = 16 * (fc128 & 7) + (fc128 >> 3);
        int se[8];
        #pragma unroll
        for (int kb = 0; kb < 8; ++kb) {
            int ur = 8 * kb + ka8;
            int fr128 = (ur < 32) ? ur : (ur + 64);
            se[kb] = (16 * (fr128 & 7) + (fr128 >> 3)) * NN + scI;
        }

        {   // ===== (1,2)+(1,3): fused 32-grid combo pass (R18) =====
            const int OR2[4] = {9, 6, 0, -6};
            const int OC2[4] = {0, 6, 9,  6};
            bool ckq[4]; int pcq[4];
            #pragma unroll
            for (int w = 0; w < 4; ++w) {
                int dcw = (uc64 - OC2[w]) & 63;
                ckq[w] = (dcw < 16) || (dcw >= 48);
                int f32c = (dcw < 16) ? dcw : (dcw - 32);
                pcq[w] = 4 * (f32c & 7) + (f32c >> 3);
            }
            int m6 = c6 & 7;
            bool ckV = (m6 < 2) || (m6 >= 6);
            int p32c = 4 * (c6 >> 3) + ((m6 < 2) ? m6 : (m6 - 4));
            const float* p30 = psi + (size_t)12 * NPIX;
            #pragma unroll
            for (int kb = 0; kb < 8; ++kb) {
                int ur = 8 * kb + ka8;
                float2 z = vh[kb];
                int e = se[kb];
                #pragma unroll
                for (int w = 0; w < 4; ++w) {
                    if (ckq[w]) {
                        int dr = (ur - OR2[w]) & 63;
                        if (dr < 16 || dr >= 48) {
                            int f32r = (dr < 16) ? dr : (dr - 32);
                            int pr = 4 * (f32r & 7) + (f32r >> 3);
                            float pv = psi[(size_t)(8 + w) * NPIX + e];
                            float2* Q = (w == 0) ? Qs0 : (w == 1) ? Qs1
                                       : (w == 2) ? Qs2 : Qs3;
                            Q[pr * SG32 + pcq[w]] = make_float2(z.x * pv, z.y * pv);
                        }
                    }
                }
                if (ckV && (kb < 2 || kb >= 6)) {
                    int pr32 = 4 * ka8 + (kb & 3);
                    float a0 = p30[e], a1 = p30[NPIX + e];
                    float a2f = p30[2 * NPIX + e], a3 = p30[3 * NPIX + e];
                    Psa[pr32 * SG32 + p32c] =
                        make_float4(z.x * a0, z.y * a0, z.x * a1, z.y * a1);
                    Psb[pr32 * SG32 + p32c] =
                        make_float4(z.x * a2f, z.y * a2f, z.x * a3, z.y * a3);
                }
            }
            float aq, ap;
            pass32combo(Qs0, Qs1, Qs2, Qs3, Psa, Psb, tw, tid, aq, ap);
            float wsq = waveReduceSum(aq);
            float wsp = waveReduceSum(ap);
            if ((tid & 63) == 0) {
                atomicAdd(&coeffs[b * 11 + 5 + 3], wsq * S2_32);
                atomicAdd(&coeffs[b * 11 + 5 + 4], wsp * S2_32);
            }
        }
        return;
    }

    if (t0 == 2) {
        // ===== j1=3: 32-grid first order (psi_{j1=3} support +-16) =====
        int m = c & 15;
        bool ck32 = (m < 2) || (m >= 14);
        int pc32 = 4 * (c >> 4) + ((m < 2) ? m : (m - 12));
        if (ck32) {
            #pragma unroll
            for (int i = 0; i < 2; ++i) {
                int ka = kalo + 4 * i;
                #pragma unroll
                for (int kb = 0; kb < 16; ++kb) {
                    if (kb < 2 || kb >= 14) {
                        int e = (16 * ka + kb) * NN + c;
                        float2 z = ih[e];
                        float  p = p1[e];
                        int pr32 = 4 * ka + ((kb < 2) ? kb : (kb - 12));
                        G32[pr32 * SG32 + pc32] = make_float2(z.x * p, z.y * p);
                    }
                }
            }
        }
        __syncthreads();
        if (tid < 256) {   // col stepA: fft4 over b per a (32 lines x 8 a)
            int line = tid & 31, a = tid >> 5;
            float2 f[4];
            #pragma unroll
            for (int kb = 0; kb < 4; ++kb) f[kb] = G32[(4 * a + kb) * SG32 + line];
            fft4<1>(f);
            #pragma unroll
            for (int t = 0; t < 4; ++t)
                G32[(4 * a + t) * SG32 + line] = cmul(f[t], tw[4 * t * a]);
        }
        __syncthreads();
        if (tid < 128) {   // col stepB: fft8 over a per t (32 lines x 4 t)
            int line = tid & 31, t = tid >> 5;
            float2 f[8];
            #pragma unroll
            for (int a = 0; a < 8; ++a) f[a] = G32[(4 * a + t) * SG32 + line];
            fft8<1>(f);
            #pragma unroll
            for (int n1 = 0; n1 < 8; ++n1) G32[(4 * n1 + t) * SG32 + line] = f[n1];
        }
        __syncthreads();
        if (tid < 256) {   // row stepA
            int row = tid & 31, a = tid >> 5;
            float2* R = G32 + row * SG32 + 4 * a;
            float2 f[4];
            #pragma unroll
            for (int kb = 0; kb < 4; ++kb) f[kb] = R[kb];
            fft4<1>(f);
            #pragma unroll
            for (int t = 0; t < 4; ++t) R[t] = cmul(f[t], tw[4 * t * a]);
        }
        __syncthreads();
        float acc = 0.f;
        if (tid < 128) {   // row stepB + mag
            int row = tid & 31, t = tid >> 5;
            float2* R = G32 + row * SG32 + t;
            float2 f[8];
            #pragma unroll
            for (int a = 0; a < 8; ++a) f[a] = R[4 * a];
            fft8<1>(f);
            #pragma unroll
            for (int n1 = 0; n1 < 8; ++n1)
                acc += sqrtf(f[n1].x * f[n1].x + f[n1].y * f[n1].y);
        }
        float ws1 = waveReduceSum(acc);
        if ((tid & 63) == 0 && tid < 128) atomicAdd(&coeffs[b * 11 + 4], ws1 * S1_32);
        return;
    }

    // ===== j1 == 2 (R20): ENTIRE branch on off-center 32-windows =====
    // First order: R18's proven window family (same psi_{j=2} filters; center
    // bin 12, sigma_f 6.37; o biased 3 to DC). S1 scale = S1_32 (proven 32-grid
    // first order; off-center invariance proven R16). (2,3): V32 = FFT32(u1_32);
    // alias tails == tails the proven (2,3) truncation discarded. Scale:
    // 2^-44 * 4^(u1 halvings=2) * 4^(pass halvings=1) = 2^-38.
    {
        const float S2_23 = 3.6379788070917130e-12f;   // 2^-38
        const int OR1[4] = {9, 6, 0, -6};
        const int OC1[4] = {0, 6, 9,  6};
        float2* G = S;                                  // 32x33 float2
        float4* Pa = (float4*)(S + 1088);               // S[1088..3200)
        float4* Pb = (float4*)(S + 3200);               // S[3200..5312)
        int fc = (c >> 4) + 8 * (c & 15);
        int dc = (fc - OC1[l1]) & 127;
        bool ck = (dc < 16) || (dc >= 112);
        int f32c = (dc < 16) ? dc : (dc - 96);
        int pcd = 4 * (f32c & 7) + (f32c >> 3);
        if (ck) {
            #pragma unroll
            for (int i = 0; i < 2; ++i) {
                int ka = kalo + 4 * i;
                #pragma unroll
                for (int kb = 0; kb < 16; ++kb) {
                    int fr = ka + 8 * kb;
                    int dr = (fr - OR1[l1]) & 127;
                    if (dr < 16 || dr >= 112) {
                        int f32r = (dr < 16) ? dr : (dr - 96);
                        int pr = 4 * (f32r & 7) + (f32r >> 3);
                        int e = (16 * ka + kb) * NN + c;
                        float2 z = ih[e];
                        float  p = p1[e];
                        G[pr * SG32 + pcd] = make_float2(z.x * p, z.y * p);
                    }
                }
            }
        }
        __syncthreads();
        if (tid < 256) {   // col stepA (inverse)
            int line = tid & 31, a = tid >> 5;
            float2 f[4];
            #pragma unroll
            for (int kb = 0; kb < 4; ++kb) f[kb] = G[(4 * a + kb) * SG32 + line];
            fft4<1>(f);
            #pragma unroll
            for (int t = 0; t < 4; ++t)
                G[(4 * a + t) * SG32 + line] = cmul(f[t], tw[4 * t * a]);
        }
        __syncthreads();
        if (tid < 128) {   // col stepB (inverse)
            int line = tid & 31, t = tid >> 5;
            float2 f[8];
            #pragma unroll
            for (int a = 0; a < 8; ++a) f[a] = G[(4 * a + t) * SG32 + line];
            fft8<1>(f);
            #pragma unroll
            for (int n1 = 0; n1 < 8; ++n1) G[(4 * n1 + t) * SG32 + line] = f[n1];
        }
        __syncthreads();
        if (tid < 256) {   // row stepA (inverse)
            int row = tid & 31, a = tid >> 5;
            float2* R = G + row * SG32 + 4 * a;
            float2 f[4];
            #pragma unroll
            for (int kb = 0; kb < 4; ++kb) f[kb] = R[kb];
            fft4<1>(f);
            #pragma unroll
            for (int t = 0; t < 4; ++t) R[t] = cmul(f[t], tw[4 * t * a]);
        }
        __syncthreads();
        float acc = 0.f;
        if (tid < 128) {   // row stepB (inverse) + mag + writeback (m,0)
            int row = tid & 31, t = tid >> 5;
            float2* R = G + row * SG32 + t;
            float2 f[8];
            #pragma unroll
            for (int a = 0; a < 8; ++a) f[a] = R[4 * a];
            fft8<1>(f);
            #pragma unroll
            for (int n1 = 0; n1 < 8; ++n1) {
                float mg = sqrtf(f[n1].x * f[n1].x + f[n1].y * f[n1].y);
                acc += mg;
                R[4 * n1] = make_float2(mg, 0.f);
            }
        }
        float ws1 = waveReduceSum(acc);
        if ((tid & 63) == 0 && tid < 128) atomicAdd(&coeffs[b * 11 + 3], ws1 * S1_32);
        __syncthreads();
        if (tid < 256) {   // row stepA (forward)
            int row = tid & 31, a = tid >> 5;
            float2* R = G + row * SG32 + 4 * a;
            float2 f[4];
            #pragma unroll
            for (int kb = 0; kb < 4; ++kb) f[kb] = R[kb];
            fft4<-1>(f);
            #pragma unroll
            for (int t = 0; t < 4; ++t) R[t] = cmulc(f[t], tw[4 * t * a]);
        }
        __syncthreads();
        if (tid < 128) {   // row stepB (forward)
            int row = tid & 31, t = tid >> 5;
            float2* R = G + row * SG32 + t;
            float2 f[8];
            #pragma unroll
            for (int a = 0; a < 8; ++a) f[a] = R[4 * a];
            fft8<-1>(f);
            #pragma unroll
            for (int n1 = 0; n1 < 8; ++n1) R[4 * n1] = f[n1];
        }
        __syncthreads();
        if (tid < 256) {   // col stepA (forward)
            int line = tid & 31, a = tid >> 5;
            float2 f[4];
            #pragma unroll
            for (int kb = 0; kb < 4; ++kb) f[kb] = G[(4 * a + kb) * SG32 + line];
            fft4<-1>(f);
            #pragma unroll
            for (int t = 0; t < 4; ++t)
                G[(4 * a + t) * SG32 + line] = cmulc(f[t], tw[4 * t * a]);
        }
        __syncthreads();
        if (tid < 128) {   // col stepB (forward) -> V32 in G (perm layout)
            int line = tid & 31, t = tid >> 5;
            float2 f[8];
            #pragma unroll
            for (int a = 0; a < 8; ++a) f[a] = G[(4 * a + t) * SG32 + line];
            fft8<-1>(f);
            #pragma unroll
            for (int n1 = 0; n1 < 8; ++n1) G[(4 * n1 + t) * SG32 + line] = f[n1];
        }
        __syncthreads();
        {   // (2,3) staging: dest slot == V32 slot (same perm); psi at slot freq
            const float* q0 = psi + (size_t)12 * NPIX;
            const float* q1 = q0 + NPIX;
            const float* q2 = q1 + NPIX;
            const float* q3 = q2 + NPIX;
            #pragma unroll
            for (int ii = 0; ii < 2; ++ii) {
                int s = ii * 512 + tid;
                int pr = s >> 5, pc = s & 31;
                int ur = (pr >> 2) + 8 * (pr & 3);
                int uc = (pc >> 2) + 8 * (pc & 3);
                int fr = (ur < 16) ? ur : (ur + 96);
                int fcc = (uc < 16) ? uc : (uc + 96);
                int e = (16 * (fr & 7) + (fr >> 3)) * NN
                      + 16 * (fcc & 7) + (fcc >> 3);
                float2 z = G[pr * SG32 + pc];
                float a0 = q0[e], a1 = q1[e], a2f = q2[e], a3 = q3[e];
                Pa[pr * SG32 + pc] = make_float4(z.x * a0, z.y * a0, z.x * a1, z.y * a1);
                Pb[pr * SG32 + pc] = make_float4(z.x * a2f, z.y * a2f, z.x * a3, z.y * a3);
            }
        }
        float a2 = pass32x4(Pa, Pb, tw, tid);
        float ws2 = waveReduceSum(a2);
        if ((tid & 63) == 0) atomicAdd(&coeffs[b * 11 + 5 + 5], ws2 * S2_23);
    }
}

// ---------- K_mlp: tiny MLP head (separate launch -- R12 lesson) ----------
__global__ void k_mlp(const float* __restrict__ coeffs,
                      const float* __restrict__ w1, const float* __restrict__ b1,
                      const float* __restrict__ w2, const float* __restrict__ b2,
                      float* __restrict__ out) {
    int b = threadIdx.x;
    if (b >= 64) return;
    float c[11];
    #pragma unroll
    for (int i = 0; i < 11; ++i) c[i] = coeffs[b * 11 + i];
    float h[4];
    #pragma unroll
    for (int k = 0; k < 4; ++k) {
        float s = b1[k];
        #pragma unroll
        for (int i = 0; i < 11; ++i) s += w1[k * 11 + i] * c[i];
        h[k] = fmaxf(s, 0.f);
    }
    #pragma unroll
    for (int o = 0; o < 10; ++o) {
        float s = b2[o];
        #pragma unroll
        for (int k = 0; k < 4; ++k) s += w2[o * 4 + k] * h[k];
        out[b * 10 + o] = 1.f / (1.f + expf(-s));
    }
}

extern "C" void kernel_launch(void* const* d_in, const int* in_sizes, int n_in,
                              void* d_out, int out_size, void* d_ws, size_t ws_size,
                              hipStream_t stream) {
    const float* img = (const float*)d_in[0];
    const float* w1  = (const float*)d_in[1];
    const float* b1  = (const float*)d_in[2];
    const float* w2  = (const float*)d_in[3];
    const float* b2  = (const float*)d_in[4];
    float* out = (float*)d_out;

    float*  ws     = (float*)d_ws;
    float*  psi    = ws;
    float2* ihat   = (float2*)(ws + 16 * NPIX);
    float*  coeffs = ws + 16 * NPIX + 2 * 64 * NPIX;

    // R19/R20: pre split; ihat doubles as the row-FFT intermediate.
    hipLaunchKernelGGL(k_pre1,       dim3(385), dim3(TT), 0, stream, img, psi, ihat, coeffs);
    hipLaunchKernelGGL(k_pre2,       dim3(256), dim3(TT), 0, stream, ihat, coeffs);
    hipLaunchKernelGGL(k_scat_big,   dim3(256), dim3(TT), 0, stream, ihat, psi, coeffs);
    hipLaunchKernelGGL(k_scat_small, dim3(768), dim3(TT), 0, stream, ihat, psi, coeffs);
    hipLaunchKernelGGL(k_mlp,        dim3(1),   dim3(64), 0, stream, coeffs, w1, b1, w2, b2, out);
}